// Round 1
// baseline (675.576 us; speedup 1.0000x reference)
//
#include <hip/hip_runtime.h>
#include <math.h>

#define B 4
#define L 2048
#define D 256
#define NS 4
#define PPK 4
#define SP 16
#define POSP 16
#define LTMP 16
#define T 64
#define C 32
#define F 72
#define PI_F 3.14159274101257324f
#define TWO_PI_D 6.283185307179586476925286766559

// ---------------- positional phasors (exact fp32 angle, double reduction) --------
__global__ __launch_bounds__(256) void pos_kernel(const float* __restrict__ pos_freqs,
                                                  float* __restrict__ posc,
                                                  float* __restrict__ poss) {
    int idx = blockIdx.x * 256 + threadIdx.x;
    if (idx >= L * POSP) return;
    int t = idx >> 4, p = idx & 15;
    float a = (float)t * pos_freqs[p];   // replicate numpy op order in fp32
    float th = (a * 2.0f) * PI_F;
    double r = fmod((double)th, TWO_PI_D);
    posc[idx] = (float)cos(r);
    poss[idx] = (float)sin(r);
}

// ---------------- featurize: projections, phasor features, V = x@w_value + b ----
__global__ __launch_bounds__(256) void featurize_kernel(
    const float* __restrict__ x, const float* __restrict__ key_proj,
    const float* __restrict__ query_proj, const float* __restrict__ w_value,
    const float* __restrict__ b_value, const float* __restrict__ set_weights,
    float* __restrict__ V, float* __restrict__ fk, float* __restrict__ fq) {
    int half = blockIdx.x;   // 2
    int c32  = blockIdx.y;   // 64 chunks of 32 positions
    int b    = blockIdx.z;   // 4
    int tid = threadIdx.x;
    int t0 = c32 * 32;
    __shared__ float xs[32][260];
    __shared__ float zbuf[32][33];
    for (int e = tid; e < 32 * 256; e += 256) {
        int t = e >> 8, j = e & 255;
        xs[t][j] = x[((size_t)(b * L + t0 + t)) * D + j];
    }
    __syncthreads();
    int tt = tid >> 3, cg = tid & 7;
    if (half == 0) {
        float sw0 = set_weights[0], sw1 = set_weights[1], sw2 = set_weights[2], sw3 = set_weights[3];
        float mx = fmaxf(fmaxf(sw0, sw1), fmaxf(sw2, sw3));
        float e0 = expf(sw0 - mx), e1 = expf(sw1 - mx), e2 = expf(sw2 - mx), e3 = expf(sw3 - mx);
        float esum = e0 + e1 + e2 + e3;
        float wsoft[4] = {e0 / esum, e1 / esum, e2 / esum, e3 / esum};
        for (int cc = 0; cc < 4; cc++) {
            int col = cg * 4 + cc;
            const float* W = (col < 16) ? key_proj : query_proj;
            int jw = col & 15;
            float acc = 0.f;
            for (int j = 0; j < 256; j++) acc += xs[tt][j] * W[j * 16 + jw];
            zbuf[tt][col] = tanhf(acc) * PI_F;
        }
        __syncthreads();
        size_t bt = (size_t)(b * L + t0 + tt);
        float* fkp = fk + bt * 40;
        float* fqp = fq + bt * 40;
        for (int cc = 0; cc < 4; cc++) {
            int col = cg * 4 + cc;
            float z = zbuf[tt][col];
            float s, co;
            sincosf(z, &s, &co);
            if (col < 16) { fkp[2 * col] = co; fkp[2 * col + 1] = s; }
            else {
                int j = col - 16;
                float sc = 0.1f * wsoft[j >> 2];   // 0.5 * w_s / (NSETS+1)
                fqp[2 * j] = sc * co; fqp[2 * j + 1] = sc * s;
            }
        }
        if (cg < 4) {   // joint key phasor = phase sum over sets
            int p = cg;
            float zs = zbuf[tt][p] + zbuf[tt][4 + p] + zbuf[tt][8 + p] + zbuf[tt][12 + p];
            float s, co; sincosf(zs, &s, &co);
            fkp[32 + 2 * p] = co; fkp[33 + 2 * p] = s;
        } else {
            int p = cg - 4;
            float zs = zbuf[tt][16 + p] + zbuf[tt][20 + p] + zbuf[tt][24 + p] + zbuf[tt][28 + p];
            float s, co; sincosf(zs, &s, &co);
            fqp[32 + 2 * p] = 0.1f * co; fqp[33 + 2 * p] = 0.1f * s;
        }
    }
    // V = x @ w_value + b_value (each half-block does 128 of 256 columns)
    int d0 = half * 128 + cg * 16;
    float acc[16];
#pragma unroll
    for (int k = 0; k < 16; k++) acc[k] = 0.f;
    for (int j = 0; j < 256; j++) {
        float xv = xs[tt][j];
        const float4* wrow = (const float4*)(w_value + (size_t)j * D + d0);
#pragma unroll
        for (int q4 = 0; q4 < 4; q4++) {
            float4 w = wrow[q4];
            acc[q4 * 4 + 0] += xv * w.x; acc[q4 * 4 + 1] += xv * w.y;
            acc[q4 * 4 + 2] += xv * w.z; acc[q4 * 4 + 3] += xv * w.w;
        }
    }
    float* Vp = V + ((size_t)(b * L + t0 + tt)) * D + d0;
#pragma unroll
    for (int k = 0; k < 16; k++) Vp[k] = acc[k] + b_value[d0 + k];
}

// ---------------- gate scan: exclusive cumsum of joint keys -> gate; gate fk ----
__global__ __launch_bounds__(256) void gate_scan_kernel(
    float* __restrict__ fk, const float* __restrict__ surprise_scale,
    const float* __restrict__ surprise_bias, const float* __restrict__ resonance_scale,
    const float* __restrict__ resonance_threshold) {
    int b = blockIdx.x;
    int tid = threadIdx.x;
    __shared__ float scan[256][8];
    float tot[8];
#pragma unroll
    for (int q = 0; q < 8; q++) tot[q] = 0.f;
    int t0 = tid * 8;
    for (int k = 0; k < 8; k++) {
        const float* fp = fk + ((size_t)(b * L + t0 + k)) * 40 + 32;
#pragma unroll
        for (int q = 0; q < 8; q++) tot[q] += fp[q];
    }
#pragma unroll
    for (int q = 0; q < 8; q++) scan[tid][q] = tot[q];
    __syncthreads();
    for (int off = 1; off < 256; off <<= 1) {
        float tmp[8];
        if (tid >= off) {
#pragma unroll
            for (int q = 0; q < 8; q++) tmp[q] = scan[tid - off][q];
        }
        __syncthreads();
        if (tid >= off) {
#pragma unroll
            for (int q = 0; q < 8; q++) scan[tid][q] += tmp[q];
        }
        __syncthreads();
    }
    float run[8];
#pragma unroll
    for (int q = 0; q < 8; q++) run[q] = scan[tid][q] - tot[q];   // exclusive prefix
    float ss = surprise_scale[0], sb = surprise_bias[0];
    float sc = fminf(fmaxf(resonance_scale[0], 1.f), 20.f);
    float th = fminf(fmaxf(resonance_threshold[0], 0.1f), 0.9f);
    for (int k = 0; k < 8; k++) {
        int t = t0 + k;
        float* fp = fk + ((size_t)(b * L + t)) * 40;
        float rmag = 0.25f * (sqrtf(run[0] * run[0] + run[1] * run[1]) +
                              sqrtf(run[2] * run[2] + run[3] * run[3]) +
                              sqrtf(run[4] * run[4] + run[5] * run[5]) +
                              sqrtf(run[6] * run[6] + run[7] * run[7]));
        float nres = rmag / sqrtf(fmaxf((float)t, 1.0f));
        float surprise = 0.5f * (1.0f - tanhf(sc * (nres - th)));
        float gate = 1.0f / (1.0f + expf(-(ss * (surprise - 0.5f) + sb)));
#pragma unroll
        for (int q = 0; q < 8; q++) run[q] += fp[32 + q];   // ungated jk BEFORE gating
#pragma unroll
        for (int q = 0; q < 40; q++) fp[q] *= gate;          // Vg folded into k-features
    }
}

// ---------------- chunk sums of x and x^2 (for LTM running stats) ---------------
__global__ __launch_bounds__(256) void chunk_sums_kernel(const float* __restrict__ x,
                                                         float* __restrict__ Sx,
                                                         float* __restrict__ Sxx) {
    int c = blockIdx.x, b = blockIdx.y;
    int d = threadIdx.x;
    float sx = 0.f, sxx = 0.f;
    for (int t = 0; t < T; t++) {
        float v = x[((size_t)(b * L + c * T + t)) * D + d];
        sx += v; sxx += v * v;
    }
    Sx[(b * C + c) * D + d] = sx;
    Sxx[(b * C + c) * D + d] = sxx;
}

// ---------------- LTM phasor angles: z = tanh([x,rm,rs]@W)*pi -> cos/sin --------
__global__ __launch_bounds__(256) void ltm_z_kernel(
    const float* __restrict__ x, const float* __restrict__ Sx,
    const float* __restrict__ Sxx, const float* __restrict__ W,
    float* __restrict__ czsz) {
    int c = blockIdx.x, b = blockIdx.y;
    int tid = threadIdx.x;
    __shared__ float xs[16][257], rms[16][257], rss[16][257];
    float runx = 0.f, runxx = 0.f;
    for (int cp = 0; cp < c; cp++) {
        runx += Sx[(b * C + cp) * D + tid];
        runxx += Sxx[(b * C + cp) * D + tid];
    }
    int tloc = tid >> 4, p = tid & 15;
    for (int tt0 = 0; tt0 < T; tt0 += 16) {
        for (int k = 0; k < 16; k++) {
            int tg = c * T + tt0 + k;
            float xv = x[((size_t)(b * L + tg)) * D + tid];
            runx += xv; runxx += xv * xv;
            float n = (float)(tg + 1);
            float rm = runx / n;
            float rv = runxx / n - rm * rm;
            xs[k][tid] = xv; rms[k][tid] = rm;
            rss[k][tid] = sqrtf(fmaxf(rv, 1e-8f));
        }
        __syncthreads();
        float u = 0.f;
        for (int j = 0; j < 256; j++) {
            u += xs[tloc][j] * W[j * LTMP + p];
            u += rms[tloc][j] * W[(256 + j) * LTMP + p];
            u += rss[tloc][j] * W[(512 + j) * LTMP + p];
        }
        float z = tanhf(u) * PI_F;
        float s, co; sincosf(z, &s, &co);
        int tg = c * T + tt0 + tloc;
        czsz[((size_t)(b * L + tg)) * 32 + p] = co;
        czsz[((size_t)(b * L + tg)) * 32 + 16 + p] = s;
        __syncthreads();
    }
}

// ---------------- per-chunk outer-product sums S[b,c,f,d] -----------------------
__global__ __launch_bounds__(256) void outer_sums_kernel(
    const float* __restrict__ V, const float* __restrict__ fk,
    const float* __restrict__ posc, const float* __restrict__ poss,
    float* __restrict__ S) {
    int g = blockIdx.x;   // 2 feature groups of 36
    int c = blockIdx.y;   // 32
    int b = blockIdx.z;   // 4
    int tid = threadIdx.x;
    __shared__ float Fk[T][40];
    int F0 = g * 36;
    {
        int t = tid >> 2, q = tid & 3;
        int tg = c * T + t;
        for (int e = 0; e < 9; e++) {
            int fl = q * 9 + e;
            int Fi = F0 + fl;
            float v;
            if (Fi < 40) v = fk[((size_t)(b * L + tg)) * 40 + Fi];
            else {
                int pf = Fi - 40;
                v = (pf & 1) ? poss[tg * POSP + (pf >> 1)] : posc[tg * POSP + (pf >> 1)];
            }
            Fk[t][fl] = v;
        }
    }
    __syncthreads();
    float acc[36];
#pragma unroll
    for (int f = 0; f < 36; f++) acc[f] = 0.f;
    for (int t = 0; t < T; t++) {
        float v = V[((size_t)(b * L + c * T + t)) * D + tid];
#pragma unroll
        for (int f = 0; f < 36; f++) acc[f] += Fk[t][f] * v;
    }
    for (int f = 0; f < 36; f++)
        S[(((size_t)(b * C + c)) * F + F0 + f) * D + tid] = acc[f];
}

// ---------------- in-place exclusive prefix of S over chunks --------------------
__global__ __launch_bounds__(256) void prefix_kernel(float* __restrict__ S) {
    int bf = blockIdx.x;
    int b = bf / F, f = bf % F;
    int d = threadIdx.x;
    float run = 0.f;
    for (int c = 0; c < C; c++) {
        size_t idx = (((size_t)(b * C + c)) * F + f) * D + d;
        float v = S[idx];
        S[idx] = run;
        run += v;
    }
}

// ---------------- intra-chunk causal attention + inter-chunk state --------------
__global__ __launch_bounds__(256) void intra_kernel(
    float* VR,   // V in, ret out (same buffer; per-thread column, read-before-write)
    const float* __restrict__ fk, const float* __restrict__ fq,
    const float* __restrict__ posc, const float* __restrict__ poss,
    const float* __restrict__ Mexc, const float* __restrict__ pos_weight) {
    int g = blockIdx.x;   // 4 d-groups of 64
    int c = blockIdx.y;   // 32
    int b = blockIdx.z;   // 4
    int tid = threadIdx.x;
    __shared__ float Fq[T][76], Fk[T][76], A[T][68];
    float posq = 0.5f / (1.0f + expf(-pos_weight[0]));
    {
        int t = tid >> 2, q = tid & 3;
        int tg = c * T + t;
        for (int e = 0; e < 18; e++) {
            int f = q * 18 + e;
            float vk, vq;
            if (f < 40) {
                vk = fk[((size_t)(b * L + tg)) * 40 + f];
                vq = fq[((size_t)(b * L + tg)) * 40 + f];
            } else {
                int pf = f - 40;
                float pv = (pf & 1) ? poss[tg * POSP + (pf >> 1)] : posc[tg * POSP + (pf >> 1)];
                vk = pv; vq = posq * pv;
            }
            Fk[t][f] = vk; Fq[t][f] = vq;
        }
    }
    __syncthreads();
    {
        int t = tid >> 2, kq = tid & 3;
        for (int kk = 0; kk < 16; kk++) {
            int k = kq * 16 + kk;
            float a = 0.f;
            if (k <= t) {
#pragma unroll
                for (int f = 0; f < F; f++) a += Fq[t][f] * Fk[k][f];
            }
            A[t][k] = a;
        }
    }
    __syncthreads();
    int lane = tid & 63, wv = tid >> 6;
    int d = g * 64 + lane;
    float vreg[T];
#pragma unroll
    for (int k = 0; k < T; k++) vreg[k] = VR[((size_t)(b * L + c * T + k)) * D + d];
    float mreg[F];
#pragma unroll
    for (int f = 0; f < F; f++) mreg[f] = Mexc[(((size_t)(b * C + c)) * F + f) * D + d];
    for (int tr = 0; tr < 16; tr++) {
        int t = wv * 16 + tr;
        float acc = 0.f;
#pragma unroll
        for (int f = 0; f < F; f++) acc += Fq[t][f] * mreg[f];
#pragma unroll
        for (int k = 0; k < T; k++) acc += A[t][k] * vreg[k];
        VR[((size_t)(b * L + c * T + t)) * D + d] = acc;
    }
}

// ---------------- final: +LTM, /nrm, LayerNorm, @w_out, +x ----------------------
__global__ __launch_bounds__(256) void final_kernel(
    const float* retp, const float* __restrict__ czsz,
    const float* __restrict__ ltm_mem, const float* __restrict__ ltm_count,
    const float* __restrict__ ltm_weight, const float* __restrict__ ln_gamma,
    const float* __restrict__ ln_beta, const float* __restrict__ w_out,
    const float* __restrict__ b_out, const float* __restrict__ x,
    float* __restrict__ out) {
    int half = blockIdx.x;  // 2
    int c = blockIdx.y;     // 32
    int b = blockIdx.z;     // 4
    int tid = threadIdx.x;
    __shared__ float hb[32][260];
    __shared__ float cs[32][32];
    __shared__ float part1[32][8], part2[32][8];
    __shared__ float mu[32], rsig[32];
    float lsig = 1.f / (1.f + expf(-ltm_weight[0]));
    float pnorm = sqrtf(fmaxf(ltm_count[0], 1.f) * (float)LTMP);
    float lcoef = lsig / pnorm;
    float Mre[16], Mim[16];
#pragma unroll
    for (int p = 0; p < 16; p++) {
        Mre[p] = ltm_mem[(p * D + tid) * 2];
        Mim[p] = ltm_mem[(p * D + tid) * 2 + 1];
    }
    float gam = ln_gamma[tid], bet = ln_beta[tid];
    for (int tt0 = 0; tt0 < T; tt0 += 32) {
        {
            int t = tid >> 3, q = tid & 7;
            int tg = c * T + tt0 + t;
            for (int e = 0; e < 4; e++)
                cs[t][q * 4 + e] = czsz[((size_t)(b * L + tg)) * 32 + q * 4 + e];
        }
        __syncthreads();
        for (int t = 0; t < 32; t++) {
            int tg = c * T + tt0 + t;
            float pers = 0.f;
#pragma unroll
            for (int p = 0; p < 16; p++) pers += Mre[p] * cs[t][p] + Mim[p] * cs[t][16 + p];
            float rv = retp[((size_t)(b * L + tg)) * D + tid];
            hb[t][tid] = (rv + lcoef * pers) / (2.0f * sqrtf((float)(tg + 1)));
        }
        __syncthreads();
        {
            int t = tid >> 3, q = tid & 7;
            float s1 = 0.f, s2 = 0.f;
            for (int k = 0; k < 32; k++) {
                float v = hb[t][q * 32 + k];
                s1 += v; s2 += v * v;
            }
            part1[t][q] = s1; part2[t][q] = s2;
        }
        __syncthreads();
        if (tid < 32) {
            float s1 = 0.f, s2 = 0.f;
            for (int q = 0; q < 8; q++) { s1 += part1[tid][q]; s2 += part2[tid][q]; }
            float m = s1 / 256.f;
            mu[tid] = m;
            rsig[tid] = rsqrtf(fmaxf(s2 / 256.f - m * m, 0.f) + 1e-5f);
        }
        __syncthreads();
        for (int t = 0; t < 32; t++)
            hb[t][tid] = (hb[t][tid] - mu[t]) * rsig[t] * gam + bet;
        __syncthreads();
        {
            int tr = tid >> 3, q = tid & 7;
            int tg = c * T + tt0 + tr;
            int d0 = half * 128 + q * 16;
            float acc[16];
#pragma unroll
            for (int k = 0; k < 16; k++) acc[k] = 0.f;
            for (int j = 0; j < 256; j++) {
                float hv = hb[tr][j];
                const float4* wr = (const float4*)(w_out + (size_t)j * D + d0);
#pragma unroll
                for (int q4 = 0; q4 < 4; q4++) {
                    float4 w = wr[q4];
                    acc[q4 * 4 + 0] += hv * w.x; acc[q4 * 4 + 1] += hv * w.y;
                    acc[q4 * 4 + 2] += hv * w.z; acc[q4 * 4 + 3] += hv * w.w;
                }
            }
            size_t o = ((size_t)(b * L + tg)) * D + d0;
#pragma unroll
            for (int k = 0; k < 16; k++) out[o + k] = x[o + k] + acc[k] + b_out[d0 + k];
        }
        __syncthreads();
    }
}

extern "C" void kernel_launch(void* const* d_in, const int* in_sizes, int n_in,
                              void* d_out, int out_size, void* d_ws, size_t ws_size,
                              hipStream_t stream) {
    (void)in_sizes; (void)n_in; (void)out_size; (void)ws_size;
    const float* x            = (const float*)d_in[0];
    const float* key_proj     = (const float*)d_in[1];
    const float* query_proj   = (const float*)d_in[2];
    const float* ltm_key_proj = (const float*)d_in[3];
    const float* pos_freqs    = (const float*)d_in[4];
    const float* w_value      = (const float*)d_in[5];
    const float* b_value      = (const float*)d_in[6];
    const float* ln_gamma     = (const float*)d_in[9];
    const float* ln_beta      = (const float*)d_in[10];
    const float* w_out        = (const float*)d_in[11];
    const float* b_out        = (const float*)d_in[12];
    const float* set_weights  = (const float*)d_in[13];
    const float* pos_weight   = (const float*)d_in[14];
    const float* surprise_scale      = (const float*)d_in[15];
    const float* surprise_bias       = (const float*)d_in[16];
    const float* resonance_scale     = (const float*)d_in[17];
    const float* resonance_threshold = (const float*)d_in[18];
    const float* ltm_weight   = (const float*)d_in[19];
    const float* ltm_mem      = (const float*)d_in[20];
    const float* ltm_count    = (const float*)d_in[21];
    float* out = (float*)d_out;

    float* ws = (float*)d_ws;
    size_t off = 0;
    float* V    = ws + off; off += (size_t)B * L * D;     // also reused as ret
    float* fk   = ws + off; off += (size_t)B * L * 40;
    float* fq   = ws + off; off += (size_t)B * L * 40;
    float* posc = ws + off; off += (size_t)L * POSP;
    float* poss = ws + off; off += (size_t)L * POSP;
    float* Sx   = ws + off; off += (size_t)B * C * D;
    float* Sxx  = ws + off; off += (size_t)B * C * D;
    float* czsz = ws + off; off += (size_t)B * L * 32;
    float* S    = ws + off; off += (size_t)B * C * F * D; // becomes exclusive prefix

    pos_kernel<<<dim3((L * POSP + 255) / 256), 256, 0, stream>>>(pos_freqs, posc, poss);
    featurize_kernel<<<dim3(2, 64, B), 256, 0, stream>>>(x, key_proj, query_proj, w_value,
                                                         b_value, set_weights, V, fk, fq);
    gate_scan_kernel<<<dim3(B), 256, 0, stream>>>(fk, surprise_scale, surprise_bias,
                                                  resonance_scale, resonance_threshold);
    chunk_sums_kernel<<<dim3(C, B), 256, 0, stream>>>(x, Sx, Sxx);
    ltm_z_kernel<<<dim3(C, B), 256, 0, stream>>>(x, Sx, Sxx, ltm_key_proj, czsz);
    outer_sums_kernel<<<dim3(2, C, B), 256, 0, stream>>>(V, fk, posc, poss, S);
    prefix_kernel<<<dim3(B * F), 256, 0, stream>>>(S);
    intra_kernel<<<dim3(4, C, B), 256, 0, stream>>>(V, fk, fq, posc, poss, S, pos_weight);
    final_kernel<<<dim3(2, C, B), 256, 0, stream>>>(V, czsz, ltm_mem, ltm_count, ltm_weight,
                                                    ln_gamma, ln_beta, w_out, b_out, x, out);
}

// Round 2
// 347.275 us; speedup vs baseline: 1.9454x; 1.9454x over previous
//
#include <hip/hip_runtime.h>
#include <math.h>

#define B 4
#define L 2048
#define D 256
#define NS 4
#define PPK 4
#define SP 16
#define POSP 16
#define LTMP 16
#define T 64
#define C 32
#define F 72
#define PI_F 3.14159274101257324f
#define TWO_PI_D 6.283185307179586476925286766559

// ---------------- positional phasors (exact fp32 angle, double reduction) --------
__global__ __launch_bounds__(256) void pos_kernel(const float* __restrict__ pos_freqs,
                                                  float* __restrict__ posc,
                                                  float* __restrict__ poss) {
    int idx = blockIdx.x * 256 + threadIdx.x;
    if (idx >= L * POSP) return;
    int t = idx >> 4, p = idx & 15;
    float a = (float)t * pos_freqs[p];   // replicate numpy op order in fp32
    float th = (a * 2.0f) * PI_F;
    double r = fmod((double)th, TWO_PI_D);
    posc[idx] = (float)cos(r);
    poss[idx] = (float)sin(r);
}

// ---------------- featurize: fused GEMM x @ [w_value | key_proj | query_proj] ---
// grid (64 row-chunks of 32, B); 256 threads; LDS-tiled, 4x8 micro-tile
__global__ __launch_bounds__(256) void featurize_kernel(
    const float* __restrict__ x, const float* __restrict__ key_proj,
    const float* __restrict__ query_proj, const float* __restrict__ w_value,
    const float* __restrict__ b_value, const float* __restrict__ set_weights,
    float* __restrict__ V, float* __restrict__ fk, float* __restrict__ fq) {
    int rc = blockIdx.x;
    int b  = blockIdx.y;
    int row0 = rc * 32;
    int tid = threadIdx.x;
    __shared__ float xs[32][36];     // 32 rows x 32-k chunk (pad 36 -> bank spread)
    __shared__ float ws[32][292];    // 32 k x 288 cols (256 w_value + 16 kp + 16 qp)
    __shared__ float zbuf[32][33];

    int rg = tid >> 5, cg = tid & 31;   // main GEMM: rows rg*4..+3, cols cg*8..+7
    int pr = tid >> 3, pc = tid & 7;    // proj GEMM: row pr, cols 256 + pc*4..+3
    float acc[4][8];
    float accp[4];
#pragma unroll
    for (int i = 0; i < 4; i++) {
#pragma unroll
        for (int e = 0; e < 8; e++) acc[i][e] = 0.f;
        accp[i] = 0.f;
    }

    for (int kc = 0; kc < 8; kc++) {
        int kb = kc * 32;
        // stage x chunk: 32 rows x 32 k
        {
            int r = tid >> 3, c4 = tid & 7;
            *(float4*)&xs[r][c4 * 4] =
                *(const float4*)(x + ((size_t)(b * L + row0 + r)) * D + kb + c4 * 4);
        }
        // stage weight chunk: 32 k x 288 cols = 2304 float4 (9 per thread)
        for (int e = 0; e < 9; e++) {
            int idx = e * 256 + tid;        // 0..2303
            int j = idx / 72;
            int c4 = idx - j * 72;
            const float* src;
            if (c4 < 64)      src = w_value + (size_t)(kb + j) * D + c4 * 4;
            else if (c4 < 68) src = key_proj + (size_t)(kb + j) * 16 + (c4 - 64) * 4;
            else              src = query_proj + (size_t)(kb + j) * 16 + (c4 - 68) * 4;
            *(float4*)&ws[j][c4 * 4] = *(const float4*)src;
        }
        __syncthreads();
#pragma unroll 4
        for (int j = 0; j < 32; j++) {
            float4 w0 = *(float4*)&ws[j][cg * 8];
            float4 w1 = *(float4*)&ws[j][cg * 8 + 4];
            float4 wp = *(float4*)&ws[j][256 + pc * 4];
            float xp = xs[pr][j];
#pragma unroll
            for (int i = 0; i < 4; i++) {
                float xv = xs[rg * 4 + i][j];
                acc[i][0] += xv * w0.x; acc[i][1] += xv * w0.y;
                acc[i][2] += xv * w0.z; acc[i][3] += xv * w0.w;
                acc[i][4] += xv * w1.x; acc[i][5] += xv * w1.y;
                acc[i][6] += xv * w1.z; acc[i][7] += xv * w1.w;
            }
            accp[0] += xp * wp.x; accp[1] += xp * wp.y;
            accp[2] += xp * wp.z; accp[3] += xp * wp.w;
        }
        __syncthreads();
    }

    // epilogue: V = acc + b_value
    {
        float4 bv0 = *(const float4*)(b_value + cg * 8);
        float4 bv1 = *(const float4*)(b_value + cg * 8 + 4);
#pragma unroll
        for (int i = 0; i < 4; i++) {
            size_t o = ((size_t)(b * L + row0 + rg * 4 + i)) * D + cg * 8;
            float4 r0 = make_float4(acc[i][0] + bv0.x, acc[i][1] + bv0.y,
                                    acc[i][2] + bv0.z, acc[i][3] + bv0.w);
            float4 r1 = make_float4(acc[i][4] + bv1.x, acc[i][5] + bv1.y,
                                    acc[i][6] + bv1.z, acc[i][7] + bv1.w);
            *(float4*)(V + o) = r0;
            *(float4*)(V + o + 4) = r1;
        }
    }
    // proj epilogue: z = tanh(proj)*pi into zbuf
#pragma unroll
    for (int e = 0; e < 4; e++) zbuf[pr][pc * 4 + e] = tanhf(accp[e]) * PI_F;
    __syncthreads();
    // phasor features (per-bank + joint) -> fk/fq
    {
        int tt = tid >> 3, cgf = tid & 7;
        float sw0 = set_weights[0], sw1 = set_weights[1], sw2 = set_weights[2], sw3 = set_weights[3];
        float mx = fmaxf(fmaxf(sw0, sw1), fmaxf(sw2, sw3));
        float e0 = expf(sw0 - mx), e1 = expf(sw1 - mx), e2 = expf(sw2 - mx), e3 = expf(sw3 - mx);
        float esum = e0 + e1 + e2 + e3;
        float wsoft[4] = {e0 / esum, e1 / esum, e2 / esum, e3 / esum};
        size_t bt = (size_t)(b * L + row0 + tt);
        float* fkp = fk + bt * 40;
        float* fqp = fq + bt * 40;
        for (int cc = 0; cc < 4; cc++) {
            int col = cgf * 4 + cc;
            float z = zbuf[tt][col];
            float s, co;
            sincosf(z, &s, &co);
            if (col < 16) { fkp[2 * col] = co; fkp[2 * col + 1] = s; }
            else {
                int j = col - 16;
                float sc = 0.1f * wsoft[j >> 2];   // 0.5 * w_s / (NSETS+1)
                fqp[2 * j] = sc * co; fqp[2 * j + 1] = sc * s;
            }
        }
        if (cgf < 4) {
            int p = cgf;
            float zs = zbuf[tt][p] + zbuf[tt][4 + p] + zbuf[tt][8 + p] + zbuf[tt][12 + p];
            float s, co; sincosf(zs, &s, &co);
            fkp[32 + 2 * p] = co; fkp[33 + 2 * p] = s;
        } else {
            int p = cgf - 4;
            float zs = zbuf[tt][16 + p] + zbuf[tt][20 + p] + zbuf[tt][24 + p] + zbuf[tt][28 + p];
            float s, co; sincosf(zs, &s, &co);
            fqp[32 + 2 * p] = 0.1f * co; fqp[33 + 2 * p] = 0.1f * s;
        }
    }
}

// ---------------- gate scan: exclusive cumsum of joint keys -> gate; gate fk ----
__global__ __launch_bounds__(1024) void gate_scan_kernel(
    float* __restrict__ fk, const float* __restrict__ surprise_scale,
    const float* __restrict__ surprise_bias, const float* __restrict__ resonance_scale,
    const float* __restrict__ resonance_threshold) {
    int b = blockIdx.x;
    int tid = threadIdx.x;
    __shared__ float scan[1024][8];
    float tot[8];
#pragma unroll
    for (int q = 0; q < 8; q++) tot[q] = 0.f;
    int t0 = tid * 2;
    for (int k = 0; k < 2; k++) {
        const float* fp = fk + ((size_t)(b * L + t0 + k)) * 40 + 32;
#pragma unroll
        for (int q = 0; q < 8; q++) tot[q] += fp[q];
    }
#pragma unroll
    for (int q = 0; q < 8; q++) scan[tid][q] = tot[q];
    __syncthreads();
    for (int off = 1; off < 1024; off <<= 1) {
        float tmp[8];
        if (tid >= off) {
#pragma unroll
            for (int q = 0; q < 8; q++) tmp[q] = scan[tid - off][q];
        }
        __syncthreads();
        if (tid >= off) {
#pragma unroll
            for (int q = 0; q < 8; q++) scan[tid][q] += tmp[q];
        }
        __syncthreads();
    }
    float run[8];
#pragma unroll
    for (int q = 0; q < 8; q++) run[q] = scan[tid][q] - tot[q];   // exclusive prefix
    float ss = surprise_scale[0], sb = surprise_bias[0];
    float sc = fminf(fmaxf(resonance_scale[0], 1.f), 20.f);
    float th = fminf(fmaxf(resonance_threshold[0], 0.1f), 0.9f);
    for (int k = 0; k < 2; k++) {
        int t = t0 + k;
        float* fp = fk + ((size_t)(b * L + t)) * 40;
        float rmag = 0.25f * (sqrtf(run[0] * run[0] + run[1] * run[1]) +
                              sqrtf(run[2] * run[2] + run[3] * run[3]) +
                              sqrtf(run[4] * run[4] + run[5] * run[5]) +
                              sqrtf(run[6] * run[6] + run[7] * run[7]));
        float nres = rmag / sqrtf(fmaxf((float)t, 1.0f));
        float surprise = 0.5f * (1.0f - tanhf(sc * (nres - th)));
        float gate = 1.0f / (1.0f + expf(-(ss * (surprise - 0.5f) + sb)));
#pragma unroll
        for (int q = 0; q < 8; q++) run[q] += fp[32 + q];   // ungated jk BEFORE gating
#pragma unroll
        for (int q = 0; q < 40; q++) fp[q] *= gate;          // Vg folded into k-features
    }
}

// ---------------- chunk sums of x and x^2 (for LTM running stats) ---------------
__global__ __launch_bounds__(256) void chunk_sums_kernel(const float* __restrict__ x,
                                                         float* __restrict__ Sx,
                                                         float* __restrict__ Sxx) {
    int c = blockIdx.x, b = blockIdx.y;
    int d = threadIdx.x;
    float sx = 0.f, sxx = 0.f;
    for (int t = 0; t < T; t++) {
        float v = x[((size_t)(b * L + c * T + t)) * D + d];
        sx += v; sxx += v * v;
    }
    Sx[(b * C + c) * D + d] = sx;
    Sxx[(b * C + c) * D + d] = sxx;
}

// ---------------- LTM phasor angles: z = tanh([x,rm,rs]@W)*pi -> cos/sin --------
// grid (2 half-chunks, C, B)
__global__ __launch_bounds__(256) void ltm_z_kernel(
    const float* __restrict__ x, const float* __restrict__ Sx,
    const float* __restrict__ Sxx, const float* __restrict__ W,
    float* __restrict__ czsz) {
    int h = blockIdx.x, c = blockIdx.y, b = blockIdx.z;
    int tid = threadIdx.x;
    __shared__ float xs[16][257], rms[16][257], rss[16][257];
    float runx = 0.f, runxx = 0.f;
    for (int cp = 0; cp < c; cp++) {
        runx += Sx[(b * C + cp) * D + tid];
        runxx += Sxx[(b * C + cp) * D + tid];
    }
    for (int t = 0; t < h * 32; t++) {   // catch up to this half-chunk
        float xv = x[((size_t)(b * L + c * T + t)) * D + tid];
        runx += xv; runxx += xv * xv;
    }
    int tloc = tid >> 4, p = tid & 15;
    const float* Wp = W + p;
    for (int tt0 = h * 32; tt0 < h * 32 + 32; tt0 += 16) {
        for (int k = 0; k < 16; k++) {
            int tg = c * T + tt0 + k;
            float xv = x[((size_t)(b * L + tg)) * D + tid];
            runx += xv; runxx += xv * xv;
            float n = (float)(tg + 1);
            float rm = runx / n;
            float rv = runxx / n - rm * rm;
            xs[k][tid] = xv; rms[k][tid] = rm;
            rss[k][tid] = sqrtf(fmaxf(rv, 1e-8f));
        }
        __syncthreads();
        float u0 = 0.f, u1 = 0.f, u2 = 0.f;
#pragma unroll 4
        for (int j = 0; j < 256; j++) {
            u0 += xs[tloc][j] * Wp[j * LTMP];
            u1 += rms[tloc][j] * Wp[(256 + j) * LTMP];
            u2 += rss[tloc][j] * Wp[(512 + j) * LTMP];
        }
        float z = tanhf(u0 + u1 + u2) * PI_F;
        float s, co; sincosf(z, &s, &co);
        int tg = c * T + tt0 + tloc;
        czsz[((size_t)(b * L + tg)) * 32 + p] = co;
        czsz[((size_t)(b * L + tg)) * 32 + 16 + p] = s;
        __syncthreads();
    }
}

// ---------------- per-chunk outer-product sums S[b,c,f,d] -----------------------
__global__ __launch_bounds__(256) void outer_sums_kernel(
    const float* __restrict__ V, const float* __restrict__ fk,
    const float* __restrict__ posc, const float* __restrict__ poss,
    float* __restrict__ S) {
    int g = blockIdx.x;   // 2 feature groups of 36
    int c = blockIdx.y;   // 32
    int b = blockIdx.z;   // 4
    int tid = threadIdx.x;
    __shared__ float Fk[T][40];
    int F0 = g * 36;
    {
        int t = tid >> 2, q = tid & 3;
        int tg = c * T + t;
        for (int e = 0; e < 9; e++) {
            int fl = q * 9 + e;
            int Fi = F0 + fl;
            float v;
            if (Fi < 40) v = fk[((size_t)(b * L + tg)) * 40 + Fi];
            else {
                int pf = Fi - 40;
                v = (pf & 1) ? poss[tg * POSP + (pf >> 1)] : posc[tg * POSP + (pf >> 1)];
            }
            Fk[t][fl] = v;
        }
    }
    __syncthreads();
    float acc[36];
#pragma unroll
    for (int f = 0; f < 36; f++) acc[f] = 0.f;
    for (int t = 0; t < T; t++) {
        float v = V[((size_t)(b * L + c * T + t)) * D + tid];
#pragma unroll
        for (int f = 0; f < 36; f++) acc[f] += Fk[t][f] * v;
    }
    for (int f = 0; f < 36; f++)
        S[(((size_t)(b * C + c)) * F + F0 + f) * D + tid] = acc[f];
}

// ---------------- in-place exclusive prefix of S over chunks --------------------
__global__ __launch_bounds__(256) void prefix_kernel(float* __restrict__ S) {
    int bf = blockIdx.x;
    int b = bf / F, f = bf % F;
    int d = threadIdx.x;
    float run = 0.f;
    for (int c = 0; c < C; c++) {
        size_t idx = (((size_t)(b * C + c)) * F + f) * D + d;
        float v = S[idx];
        S[idx] = run;
        run += v;
    }
}

// ---------------- intra-chunk causal attention + inter-chunk state --------------
__global__ __launch_bounds__(256) void intra_kernel(
    float* VR,   // V in, ret out (same buffer; per-thread column, read-before-write)
    const float* __restrict__ fk, const float* __restrict__ fq,
    const float* __restrict__ posc, const float* __restrict__ poss,
    const float* __restrict__ Mexc, const float* __restrict__ pos_weight) {
    int g = blockIdx.x;   // 4 d-groups of 64
    int c = blockIdx.y;   // 32
    int b = blockIdx.z;   // 4
    int tid = threadIdx.x;
    __shared__ float Fq[T][76], Fk[T][76], A[T][68];
    float posq = 0.5f / (1.0f + expf(-pos_weight[0]));
    {
        int t = tid >> 2, q = tid & 3;
        int tg = c * T + t;
        for (int e = 0; e < 18; e++) {
            int f = q * 18 + e;
            float vk, vq;
            if (f < 40) {
                vk = fk[((size_t)(b * L + tg)) * 40 + f];
                vq = fq[((size_t)(b * L + tg)) * 40 + f];
            } else {
                int pf = f - 40;
                float pv = (pf & 1) ? poss[tg * POSP + (pf >> 1)] : posc[tg * POSP + (pf >> 1)];
                vk = pv; vq = posq * pv;
            }
            Fk[t][f] = vk; Fq[t][f] = vq;
        }
    }
    __syncthreads();
    {
        int t = tid >> 2, kq = tid & 3;
        for (int kk = 0; kk < 16; kk++) {
            int k = kq * 16 + kk;
            float a = 0.f;
            if (k <= t) {
#pragma unroll
                for (int f = 0; f < F; f++) a += Fq[t][f] * Fk[k][f];
            }
            A[t][k] = a;
        }
    }
    __syncthreads();
    int lane = tid & 63, wv = tid >> 6;
    int d = g * 64 + lane;
    float vreg[T];
#pragma unroll
    for (int k = 0; k < T; k++) vreg[k] = VR[((size_t)(b * L + c * T + k)) * D + d];
    float mreg[F];
#pragma unroll
    for (int f = 0; f < F; f++) mreg[f] = Mexc[(((size_t)(b * C + c)) * F + f) * D + d];
    for (int tr = 0; tr < 16; tr++) {
        int t = wv * 16 + tr;
        float acc = 0.f;
#pragma unroll
        for (int f = 0; f < F; f++) acc += Fq[t][f] * mreg[f];
#pragma unroll
        for (int k = 0; k < T; k++) acc += A[t][k] * vreg[k];
        VR[((size_t)(b * L + c * T + t)) * D + d] = acc;
    }
}

// ---------------- final: +LTM, /nrm, LayerNorm, @w_out (LDS-tiled), +x ----------
// grid (64 row-chunks of 32, B); 256 threads
__global__ __launch_bounds__(256) void final_kernel(
    const float* __restrict__ retp, const float* __restrict__ czsz,
    const float* __restrict__ ltm_mem, const float* __restrict__ ltm_count,
    const float* __restrict__ ltm_weight, const float* __restrict__ ln_gamma,
    const float* __restrict__ ln_beta, const float* __restrict__ w_out,
    const float* __restrict__ b_out, const float* __restrict__ x,
    float* __restrict__ out) {
    int rc = blockIdx.x;
    int b  = blockIdx.y;
    int row0 = rc * 32;
    int tid = threadIdx.x;
    __shared__ float hb[32][257];
    __shared__ float ws2[16][260];
    __shared__ float cs[32][33];
    __shared__ float part1[32][8], part2[32][8];
    __shared__ float mu[32], rsig[32];
    float lsig = 1.f / (1.f + expf(-ltm_weight[0]));
    float pnorm = sqrtf(fmaxf(ltm_count[0], 1.f) * (float)LTMP);
    float lcoef = lsig / pnorm;
    float Mre[16], Mim[16];
#pragma unroll
    for (int p = 0; p < 16; p++) {
        Mre[p] = ltm_mem[(p * D + tid) * 2];
        Mim[p] = ltm_mem[(p * D + tid) * 2 + 1];
    }
    float gam = ln_gamma[tid], bet = ln_beta[tid];
    // stage czsz for these 32 rows
    {
        int t = tid >> 3, q = tid & 7;
        int tg = row0 + t;
        for (int e = 0; e < 4; e++)
            cs[t][q * 4 + e] = czsz[((size_t)(b * L + tg)) * 32 + q * 4 + e];
    }
    __syncthreads();
    // h = (ret + lcoef*pers) / nrm  (thread owns column tid)
    for (int t = 0; t < 32; t++) {
        int tg = row0 + t;
        float pers = 0.f;
#pragma unroll
        for (int p = 0; p < 16; p++) pers += Mre[p] * cs[t][p] + Mim[p] * cs[t][16 + p];
        float rv = retp[((size_t)(b * L + tg)) * D + tid];
        hb[t][tid] = (rv + lcoef * pers) / (2.0f * sqrtf((float)(tg + 1)));
    }
    __syncthreads();
    // LayerNorm stats
    {
        int t = tid >> 3, q = tid & 7;
        float s1 = 0.f, s2 = 0.f;
        for (int k = 0; k < 32; k++) {
            float v = hb[t][q * 32 + k];
            s1 += v; s2 += v * v;
        }
        part1[t][q] = s1; part2[t][q] = s2;
    }
    __syncthreads();
    if (tid < 32) {
        float s1 = 0.f, s2 = 0.f;
        for (int q = 0; q < 8; q++) { s1 += part1[tid][q]; s2 += part2[tid][q]; }
        float m = s1 / 256.f;
        mu[tid] = m;
        rsig[tid] = rsqrtf(fmaxf(s2 / 256.f - m * m, 0.f) + 1e-5f);
    }
    __syncthreads();
    for (int t = 0; t < 32; t++)
        hb[t][tid] = (hb[t][tid] - mu[t]) * rsig[t] * gam + bet;
    __syncthreads();
    // GEMM: hb[32][256] @ w_out -> 32x256, 4x8 micro-tile, 16-k chunks
    int rg = tid >> 5, cg = tid & 31;
    float acc[4][8];
#pragma unroll
    for (int i = 0; i < 4; i++)
#pragma unroll
        for (int e = 0; e < 8; e++) acc[i][e] = 0.f;
    for (int kc = 0; kc < 16; kc++) {
        int kb = kc * 16;
        for (int e = 0; e < 4; e++) {
            int idx = e * 256 + tid;     // 0..1023 float4s; 64 per k-row
            int j = idx >> 6, c4 = idx & 63;
            *(float4*)&ws2[j][c4 * 4] = *(const float4*)(w_out + (size_t)(kb + j) * D + c4 * 4);
        }
        __syncthreads();
#pragma unroll 4
        for (int j = 0; j < 16; j++) {
            float4 w0 = *(float4*)&ws2[j][cg * 8];
            float4 w1 = *(float4*)&ws2[j][cg * 8 + 4];
#pragma unroll
            for (int i = 0; i < 4; i++) {
                float xv = hb[rg * 4 + i][kb + j];
                acc[i][0] += xv * w0.x; acc[i][1] += xv * w0.y;
                acc[i][2] += xv * w0.z; acc[i][3] += xv * w0.w;
                acc[i][4] += xv * w1.x; acc[i][5] += xv * w1.y;
                acc[i][6] += xv * w1.z; acc[i][7] += xv * w1.w;
            }
        }
        __syncthreads();
    }
    // epilogue: out = x + acc + b_out
    {
        float4 bo0 = *(const float4*)(b_out + cg * 8);
        float4 bo1 = *(const float4*)(b_out + cg * 8 + 4);
#pragma unroll
        for (int i = 0; i < 4; i++) {
            size_t o = ((size_t)(b * L + row0 + rg * 4 + i)) * D + cg * 8;
            float4 x0 = *(const float4*)(x + o);
            float4 x1 = *(const float4*)(x + o + 4);
            float4 r0 = make_float4(x0.x + acc[i][0] + bo0.x, x0.y + acc[i][1] + bo0.y,
                                    x0.z + acc[i][2] + bo0.z, x0.w + acc[i][3] + bo0.w);
            float4 r1 = make_float4(x1.x + acc[i][4] + bo1.x, x1.y + acc[i][5] + bo1.y,
                                    x1.z + acc[i][6] + bo1.z, x1.w + acc[i][7] + bo1.w);
            *(float4*)(out + o) = r0;
            *(float4*)(out + o + 4) = r1;
        }
    }
}

extern "C" void kernel_launch(void* const* d_in, const int* in_sizes, int n_in,
                              void* d_out, int out_size, void* d_ws, size_t ws_size,
                              hipStream_t stream) {
    (void)in_sizes; (void)n_in; (void)out_size; (void)ws_size;
    const float* x            = (const float*)d_in[0];
    const float* key_proj     = (const float*)d_in[1];
    const float* query_proj   = (const float*)d_in[2];
    const float* ltm_key_proj = (const float*)d_in[3];
    const float* pos_freqs    = (const float*)d_in[4];
    const float* w_value      = (const float*)d_in[5];
    const float* b_value      = (const float*)d_in[6];
    const float* ln_gamma     = (const float*)d_in[9];
    const float* ln_beta      = (const float*)d_in[10];
    const float* w_out        = (const float*)d_in[11];
    const float* b_out        = (const float*)d_in[12];
    const float* set_weights  = (const float*)d_in[13];
    const float* pos_weight   = (const float*)d_in[14];
    const float* surprise_scale      = (const float*)d_in[15];
    const float* surprise_bias       = (const float*)d_in[16];
    const float* resonance_scale     = (const float*)d_in[17];
    const float* resonance_threshold = (const float*)d_in[18];
    const float* ltm_weight   = (const float*)d_in[19];
    const float* ltm_mem      = (const float*)d_in[20];
    const float* ltm_count    = (const float*)d_in[21];
    float* out = (float*)d_out;

    float* ws = (float*)d_ws;
    size_t off = 0;
    float* V    = ws + off; off += (size_t)B * L * D;     // also reused as ret
    float* fk   = ws + off; off += (size_t)B * L * 40;
    float* fq   = ws + off; off += (size_t)B * L * 40;
    float* posc = ws + off; off += (size_t)L * POSP;
    float* poss = ws + off; off += (size_t)L * POSP;
    float* Sx   = ws + off; off += (size_t)B * C * D;
    float* Sxx  = ws + off; off += (size_t)B * C * D;
    float* czsz = ws + off; off += (size_t)B * L * 32;
    float* S    = ws + off; off += (size_t)B * C * F * D; // becomes exclusive prefix

    pos_kernel<<<dim3((L * POSP + 255) / 256), 256, 0, stream>>>(pos_freqs, posc, poss);
    featurize_kernel<<<dim3(64, B), 256, 0, stream>>>(x, key_proj, query_proj, w_value,
                                                      b_value, set_weights, V, fk, fq);
    gate_scan_kernel<<<dim3(B), 1024, 0, stream>>>(fk, surprise_scale, surprise_bias,
                                                   resonance_scale, resonance_threshold);
    chunk_sums_kernel<<<dim3(C, B), 256, 0, stream>>>(x, Sx, Sxx);
    ltm_z_kernel<<<dim3(2, C, B), 256, 0, stream>>>(x, Sx, Sxx, ltm_key_proj, czsz);
    outer_sums_kernel<<<dim3(2, C, B), 256, 0, stream>>>(V, fk, posc, poss, S);
    prefix_kernel<<<dim3(B * F), 256, 0, stream>>>(S);
    intra_kernel<<<dim3(4, C, B), 256, 0, stream>>>(V, fk, fq, posc, poss, S, pos_weight);
    final_kernel<<<dim3(64, B), 256, 0, stream>>>(V, czsz, ltm_mem, ltm_count, ltm_weight,
                                                  ln_gamma, ln_beta, w_out, b_out, x, out);
}

// Round 3
// 330.038 us; speedup vs baseline: 2.0470x; 1.0522x over previous
//
#include <hip/hip_runtime.h>
#include <math.h>

#define B 4
#define L 2048
#define D 256
#define POSP 16
#define LTMP 16
#define T 64
#define C 32
#define F 72
#define PI_F 3.14159274101257324f
#define TWO_PI_D 6.283185307179586476925286766559

// ---------------- positional phasors (exact fp32 angle, double reduction) --------
__global__ __launch_bounds__(256) void pos_kernel(const float* __restrict__ pos_freqs,
                                                  float* __restrict__ posc,
                                                  float* __restrict__ poss) {
    int idx = blockIdx.x * 256 + threadIdx.x;
    if (idx >= L * POSP) return;
    int t = idx >> 4, p = idx & 15;
    float a = (float)t * pos_freqs[p];   // replicate numpy op order in fp32
    float th = (a * 2.0f) * PI_F;
    double r = fmod((double)th, TWO_PI_D);
    posc[idx] = (float)cos(r);
    poss[idx] = (float)sin(r);
}

// ---------------- featurize: fused GEMM x @ [w_value-half | proj] ---------------
// grid (2 col-groups, 64 row-chunks, B); g=0: V cols 0..127 + key_proj -> fk (+jk partials)
//                                        g=1: V cols 128..255 + query_proj -> fq
__global__ __launch_bounds__(256) void featurize_kernel(
    const float* __restrict__ x, const float* __restrict__ key_proj,
    const float* __restrict__ query_proj, const float* __restrict__ w_value,
    const float* __restrict__ b_value, const float* __restrict__ set_weights,
    float* __restrict__ V, float* __restrict__ fk, float* __restrict__ fq,
    float* __restrict__ partial) {
    int g  = blockIdx.x;
    int rc = blockIdx.y;
    int b  = blockIdx.z;
    int row0 = rc * 32;
    int tid = threadIdx.x;
    __shared__ float xs[32][36];
    __shared__ float ws[32][148];
    __shared__ float zbuf[32][18];
    __shared__ float jkv[32][9];
    const float* proj = g ? query_proj : key_proj;
    int rowg = tid >> 4, cg = tid & 15;   // rows {rowg, rowg+16}, cols cg*8..+7
    int pr = tid >> 3, pc = tid & 7;      // proj: row pr, cols pc*2, pc*2+1
    float acc0[8], acc1[8], accp[2];
#pragma unroll
    for (int e = 0; e < 8; e++) { acc0[e] = 0.f; acc1[e] = 0.f; }
    accp[0] = 0.f; accp[1] = 0.f;

    for (int kc = 0; kc < 8; kc++) {
        int kb = kc * 32;
        {
            int r = tid >> 3, c4 = tid & 7;
            *(float4*)&xs[r][c4 * 4] =
                *(const float4*)(x + ((size_t)(b * L + row0 + r)) * D + kb + c4 * 4);
        }
#pragma unroll
        for (int e = 0; e < 5; e++) {
            int idx = e * 256 + tid;
            if (idx < 1152) {
                int j = idx / 36, c4 = idx - j * 36;
                const float* src = (c4 < 32)
                    ? (w_value + (size_t)(kb + j) * D + g * 128 + c4 * 4)
                    : (proj + (size_t)(kb + j) * 16 + (c4 - 32) * 4);
                *(float4*)&ws[j][c4 * 4] = *(const float4*)src;
            }
        }
        __syncthreads();
#pragma unroll 4
        for (int j = 0; j < 32; j++) {
            float4 w0 = *(float4*)&ws[j][cg * 8];
            float4 w1 = *(float4*)&ws[j][cg * 8 + 4];
            float2 wp = *(float2*)&ws[j][128 + pc * 2];
            float x0 = xs[rowg][j], x1 = xs[rowg + 16][j];
            float xp = xs[pr][j];
            acc0[0] += x0 * w0.x; acc0[1] += x0 * w0.y; acc0[2] += x0 * w0.z; acc0[3] += x0 * w0.w;
            acc0[4] += x0 * w1.x; acc0[5] += x0 * w1.y; acc0[6] += x0 * w1.z; acc0[7] += x0 * w1.w;
            acc1[0] += x1 * w0.x; acc1[1] += x1 * w0.y; acc1[2] += x1 * w0.z; acc1[3] += x1 * w0.w;
            acc1[4] += x1 * w1.x; acc1[5] += x1 * w1.y; acc1[6] += x1 * w1.z; acc1[7] += x1 * w1.w;
            accp[0] += xp * wp.x; accp[1] += xp * wp.y;
        }
        __syncthreads();
    }
    // V epilogue
    {
        int d0 = g * 128 + cg * 8;
        float4 bv0 = *(const float4*)(b_value + d0);
        float4 bv1 = *(const float4*)(b_value + d0 + 4);
        size_t o0 = ((size_t)(b * L + row0 + rowg)) * D + d0;
        size_t o1 = ((size_t)(b * L + row0 + rowg + 16)) * D + d0;
        *(float4*)(V + o0)     = make_float4(acc0[0] + bv0.x, acc0[1] + bv0.y, acc0[2] + bv0.z, acc0[3] + bv0.w);
        *(float4*)(V + o0 + 4) = make_float4(acc0[4] + bv1.x, acc0[5] + bv1.y, acc0[6] + bv1.z, acc0[7] + bv1.w);
        *(float4*)(V + o1)     = make_float4(acc1[0] + bv0.x, acc1[1] + bv0.y, acc1[2] + bv0.z, acc1[3] + bv0.w);
        *(float4*)(V + o1 + 4) = make_float4(acc1[4] + bv1.x, acc1[5] + bv1.y, acc1[6] + bv1.z, acc1[7] + bv1.w);
    }
    zbuf[pr][pc * 2]     = tanhf(accp[0]) * PI_F;
    zbuf[pr][pc * 2 + 1] = tanhf(accp[1]) * PI_F;
    __syncthreads();
    // phasor epilogue
    {
        int tt = tid >> 3, c2 = tid & 7;
        size_t bt = (size_t)(b * L + row0 + tt);
        if (g == 0) {
            float* fp = fk + bt * 40;
#pragma unroll
            for (int e = 0; e < 2; e++) {
                int col = c2 * 2 + e;
                float si, co; sincosf(zbuf[tt][col], &si, &co);
                fp[2 * col] = co; fp[2 * col + 1] = si;
            }
            if (c2 < 4) {
                int p = c2;
                float zs = zbuf[tt][p] + zbuf[tt][4 + p] + zbuf[tt][8 + p] + zbuf[tt][12 + p];
                float si, co; sincosf(zs, &si, &co);
                fp[32 + 2 * p] = co; fp[33 + 2 * p] = si;
                jkv[tt][2 * p] = co; jkv[tt][2 * p + 1] = si;
            }
        } else {
            float sw0 = set_weights[0], sw1 = set_weights[1], sw2 = set_weights[2], sw3 = set_weights[3];
            float mx = fmaxf(fmaxf(sw0, sw1), fmaxf(sw2, sw3));
            float e0 = expf(sw0 - mx), e1 = expf(sw1 - mx), e2 = expf(sw2 - mx), e3 = expf(sw3 - mx);
            float esum = e0 + e1 + e2 + e3;
            float wsoft[4] = {e0 / esum, e1 / esum, e2 / esum, e3 / esum};
            float* fp = fq + bt * 40;
#pragma unroll
            for (int e = 0; e < 2; e++) {
                int col = c2 * 2 + e;
                float si, co; sincosf(zbuf[tt][col], &si, &co);
                float sc = 0.1f * wsoft[col >> 2];   // 0.5 * w_s / (NSETS+1)
                fp[2 * col] = sc * co; fp[2 * col + 1] = sc * si;
            }
            if (c2 < 4) {
                int p = c2;
                float zs = zbuf[tt][p] + zbuf[tt][4 + p] + zbuf[tt][8 + p] + zbuf[tt][12 + p];
                float si, co; sincosf(zs, &si, &co);
                fp[32 + 2 * p] = 0.1f * co; fp[33 + 2 * p] = 0.1f * si;
            }
        }
    }
    __syncthreads();
    if (g == 0) {   // reduce ungated jk over the 32 rows -> chunk partial
        int rr = tid >> 3, ch = tid & 7;
#pragma unroll
        for (int s2 = 16; s2 >= 1; s2 >>= 1) {
            if (rr < s2) jkv[rr][ch] += jkv[rr + s2][ch];
            __syncthreads();
        }
        if (rr == 0) partial[((size_t)(b * 64 + rc)) * 8 + ch] = jkv[0][ch];
    }
}

// ---------------- gate scan phase 2: exclusive scan of 64 chunk partials --------
__global__ __launch_bounds__(512) void gs_scan_kernel(const float* __restrict__ partial,
                                                      float* __restrict__ chunkoff) {
    int b = blockIdx.x;
    int tid = threadIdx.x;   // 512 = 64 chunks x 8 ch
    int c = tid >> 3, ch = tid & 7;
    __shared__ float sc_[64][9];
    float own = partial[((size_t)(b * 64 + c)) * 8 + ch];
    sc_[c][ch] = own;
    __syncthreads();
    for (int off = 1; off < 64; off <<= 1) {
        float v = 0.f;
        if (c >= off) v = sc_[c - off][ch];
        __syncthreads();
        if (c >= off) sc_[c][ch] += v;
        __syncthreads();
    }
    chunkoff[((size_t)(b * 64 + c)) * 8 + ch] = sc_[c][ch] - own;
}

// ---------------- gate scan phase 3: local scan, gate, scale fk -----------------
__global__ __launch_bounds__(256) void gs_apply_kernel(
    float* __restrict__ fk, const float* __restrict__ chunkoff,
    const float* __restrict__ surprise_scale, const float* __restrict__ surprise_bias,
    const float* __restrict__ resonance_scale, const float* __restrict__ resonance_threshold) {
    int rc = blockIdx.x, b = blockIdx.y;
    int tid = threadIdx.x;
    int t = tid >> 3, ch = tid & 7;
    __shared__ float sc_[32][9];
    __shared__ float gbuf[32];
    float* fp = fk + ((size_t)(b * L + rc * 32 + t)) * 40;
    float own = fp[32 + ch];
    sc_[t][ch] = own;
    __syncthreads();
    for (int off = 1; off < 32; off <<= 1) {
        float v = 0.f;
        if (t >= off) v = sc_[t - off][ch];
        __syncthreads();
        if (t >= off) sc_[t][ch] += v;
        __syncthreads();
    }
    float run = chunkoff[((size_t)(b * 64 + rc)) * 8 + ch] + sc_[t][ch] - own;
    __syncthreads();
    sc_[t][ch] = run;
    __syncthreads();
    if (tid < 32) {
        int tg = rc * 32 + tid;
        float r0 = sc_[tid][0], r1 = sc_[tid][1], r2 = sc_[tid][2], r3 = sc_[tid][3];
        float r4 = sc_[tid][4], r5 = sc_[tid][5], r6 = sc_[tid][6], r7 = sc_[tid][7];
        float rmag = 0.25f * (sqrtf(r0 * r0 + r1 * r1) + sqrtf(r2 * r2 + r3 * r3) +
                              sqrtf(r4 * r4 + r5 * r5) + sqrtf(r6 * r6 + r7 * r7));
        float scv = fminf(fmaxf(resonance_scale[0], 1.f), 20.f);
        float thv = fminf(fmaxf(resonance_threshold[0], 0.1f), 0.9f);
        float nres = rmag / sqrtf(fmaxf((float)tg, 1.0f));
        float surprise = 0.5f * (1.0f - tanhf(scv * (nres - thv)));
        gbuf[tid] = 1.0f / (1.0f + expf(-(surprise_scale[0] * (surprise - 0.5f) + surprise_bias[0])));
    }
    __syncthreads();
    float gv = gbuf[t];
#pragma unroll
    for (int e = 0; e < 5; e++) fp[ch * 5 + e] *= gv;
}

// ---------------- 16-row sub-chunk sums of x, x^2 (LTM stats) -------------------
__global__ __launch_bounds__(256) void stats16_kernel(const float* __restrict__ x,
                                                      float* __restrict__ Sx16,
                                                      float* __restrict__ Sxx16) {
    int s = blockIdx.x, b = blockIdx.y;
    int d = threadIdx.x;
    float sx = 0.f, sxx = 0.f;
#pragma unroll
    for (int k = 0; k < 16; k++) {
        float v = x[((size_t)(b * L + s * 16 + k)) * D + d];
        sx += v; sxx += v * v;
    }
    Sx16[((size_t)(b * 128 + s)) * D + d] = sx;
    Sxx16[((size_t)(b * 128 + s)) * D + d] = sxx;
}

// ---------------- LTM phasor angles, 16 rows per block --------------------------
__global__ __launch_bounds__(256) void ltm_z_kernel(
    const float* __restrict__ x, const float* __restrict__ Sx16,
    const float* __restrict__ Sxx16, const float* __restrict__ W,
    float* __restrict__ czsz) {
    int s = blockIdx.x, b = blockIdx.y;
    int tid = threadIdx.x;
    __shared__ float xs[16][257], rms[16][257], rss[16][257];
    float a0 = 0.f, a1 = 0.f, a2 = 0.f, a3 = 0.f;
    float c0 = 0.f, c1 = 0.f, c2 = 0.f, c3 = 0.f;
    int sp = 0;
    for (; sp + 4 <= s; sp += 4) {
        a0 += Sx16[((size_t)(b * 128 + sp)) * D + tid];
        a1 += Sx16[((size_t)(b * 128 + sp + 1)) * D + tid];
        a2 += Sx16[((size_t)(b * 128 + sp + 2)) * D + tid];
        a3 += Sx16[((size_t)(b * 128 + sp + 3)) * D + tid];
        c0 += Sxx16[((size_t)(b * 128 + sp)) * D + tid];
        c1 += Sxx16[((size_t)(b * 128 + sp + 1)) * D + tid];
        c2 += Sxx16[((size_t)(b * 128 + sp + 2)) * D + tid];
        c3 += Sxx16[((size_t)(b * 128 + sp + 3)) * D + tid];
    }
    for (; sp < s; sp++) {
        a0 += Sx16[((size_t)(b * 128 + sp)) * D + tid];
        c0 += Sxx16[((size_t)(b * 128 + sp)) * D + tid];
    }
    float runx = (a0 + a1) + (a2 + a3), runxx = (c0 + c1) + (c2 + c3);
    for (int k = 0; k < 16; k++) {
        int tg = s * 16 + k;
        float xv = x[((size_t)(b * L + tg)) * D + tid];
        runx += xv; runxx += xv * xv;
        float n = (float)(tg + 1);
        float rm = runx / n;
        float rv = runxx / n - rm * rm;
        xs[k][tid] = xv; rms[k][tid] = rm;
        rss[k][tid] = sqrtf(fmaxf(rv, 1e-8f));
    }
    __syncthreads();
    int tl = tid >> 4, p = tid & 15;
    const float* Wp = W + p;
    float u0 = 0.f, u1 = 0.f, u2 = 0.f;
#pragma unroll 4
    for (int j = 0; j < 256; j++) {
        u0 += xs[tl][j] * Wp[j * LTMP];
        u1 += rms[tl][j] * Wp[(256 + j) * LTMP];
        u2 += rss[tl][j] * Wp[(512 + j) * LTMP];
    }
    float z = tanhf(u0 + u1 + u2) * PI_F;
    float si, co; sincosf(z, &si, &co);
    int tg = s * 16 + tl;
    czsz[((size_t)(b * L + tg)) * 32 + p] = co;
    czsz[((size_t)(b * L + tg)) * 32 + 16 + p] = si;
}

// ---------------- per-chunk outer-product sums S[b,c,f,d] -----------------------
__global__ __launch_bounds__(256) void outer_sums_kernel(
    const float* __restrict__ V, const float* __restrict__ fk,
    const float* __restrict__ posc, const float* __restrict__ poss,
    float* __restrict__ S) {
    int g = blockIdx.x;   // 2 feature groups of 36
    int c = blockIdx.y;   // 32
    int b = blockIdx.z;   // 4
    int tid = threadIdx.x;
    __shared__ float Fk[T][40];
    int F0 = g * 36;
    {
        int t = tid >> 2, q = tid & 3;
        int tg = c * T + t;
        for (int e = 0; e < 9; e++) {
            int fl = q * 9 + e;
            int Fi = F0 + fl;
            float v;
            if (Fi < 40) v = fk[((size_t)(b * L + tg)) * 40 + Fi];
            else {
                int pf = Fi - 40;
                v = (pf & 1) ? poss[tg * POSP + (pf >> 1)] : posc[tg * POSP + (pf >> 1)];
            }
            Fk[t][fl] = v;
        }
    }
    __syncthreads();
    float acc[36];
#pragma unroll
    for (int f = 0; f < 36; f++) acc[f] = 0.f;
    for (int t = 0; t < T; t++) {
        float v = V[((size_t)(b * L + c * T + t)) * D + tid];
#pragma unroll
        for (int f = 0; f < 36; f++) acc[f] += Fk[t][f] * v;
    }
    for (int f = 0; f < 36; f++)
        S[(((size_t)(b * C + c)) * F + F0 + f) * D + tid] = acc[f];
}

// ---------------- in-place exclusive prefix of S over chunks --------------------
__global__ __launch_bounds__(256) void prefix_kernel(float* __restrict__ S) {
    int bf = blockIdx.x;
    int b = bf / F, f = bf % F;
    int d = threadIdx.x;
    float run = 0.f;
    for (int c = 0; c < C; c++) {
        size_t idx = (((size_t)(b * C + c)) * F + f) * D + d;
        float v = S[idx];
        S[idx] = run;
        run += v;
    }
}

// ---------------- score: A[t,k] = Fq[t]·Fk[k] (causal), per chunk ---------------
// grid (2 t-halves, 32 c, B)
__global__ __launch_bounds__(256) void score_kernel(
    const float* __restrict__ fk, const float* __restrict__ fq,
    const float* __restrict__ posc, const float* __restrict__ poss,
    const float* __restrict__ pos_weight, float* __restrict__ A) {
    int h = blockIdx.x, c = blockIdx.y, b = blockIdx.z;
    int tid = threadIdx.x;
    __shared__ float Fk[64][77];
    __shared__ float Fq[32][77];
    float posq = 0.5f / (1.0f + expf(-pos_weight[0]));
    for (int e = 0; e < 18; e++) {
        int idx = e * 256 + tid;   // 64*72 = 4608
        int r = idx / 72, f = idx - r * 72;
        int tg = c * T + r;
        float v;
        if (f < 40) v = fk[((size_t)(b * L + tg)) * 40 + f];
        else { int pf = f - 40; v = (pf & 1) ? poss[tg * POSP + (pf >> 1)] : posc[tg * POSP + (pf >> 1)]; }
        Fk[r][f] = v;
    }
    for (int e = 0; e < 9; e++) {
        int idx = e * 256 + tid;   // 32*72 = 2304
        int r = idx / 72, f = idx - r * 72;
        int tg = c * T + h * 32 + r;
        float v;
        if (f < 40) v = fq[((size_t)(b * L + tg)) * 40 + f];
        else { int pf = f - 40; v = posq * ((pf & 1) ? poss[tg * POSP + (pf >> 1)] : posc[tg * POSP + (pf >> 1)]); }
        Fq[r][f] = v;
    }
    __syncthreads();
    int tl = tid >> 3, k8 = tid & 7;
    int t = h * 32 + tl;
    float av[8];
#pragma unroll
    for (int j = 0; j < 8; j++) {
        int k = k8 * 8 + j;
        float a = 0.f;
        if (k <= t) {
#pragma unroll
            for (int f = 0; f < F; f++) a += Fq[tl][f] * Fk[k][f];
        }
        av[j] = a;
    }
    float* Ap = A + (((size_t)(b * 32 + c)) * 64 + t) * 64 + k8 * 8;
    *(float4*)Ap = make_float4(av[0], av[1], av[2], av[3]);
    *(float4*)(Ap + 4) = make_float4(av[4], av[5], av[6], av[7]);
}

// ---------------- intra: ret = Fq·M + A·V ---------------------------------------
// grid (4 d-groups, 32 c, B)
__global__ __launch_bounds__(256) void intra_kernel(
    float* VR,   // V in, ret out
    const float* __restrict__ fq, const float* __restrict__ posc,
    const float* __restrict__ poss, const float* __restrict__ Mexc,
    const float* __restrict__ A, const float* __restrict__ pos_weight) {
    int dg = blockIdx.x, c = blockIdx.y, b = blockIdx.z;
    int tid = threadIdx.x;
    __shared__ float Fq[64][77];
    __shared__ float As[64][68];
    float posq = 0.5f / (1.0f + expf(-pos_weight[0]));
    for (int e = 0; e < 18; e++) {
        int idx = e * 256 + tid;
        int r = idx / 72, f = idx - r * 72;
        int tg = c * T + r;
        float v;
        if (f < 40) v = fq[((size_t)(b * L + tg)) * 40 + f];
        else { int pf = f - 40; v = posq * ((pf & 1) ? poss[tg * POSP + (pf >> 1)] : posc[tg * POSP + (pf >> 1)]); }
        Fq[r][f] = v;
    }
#pragma unroll
    for (int e = 0; e < 4; e++) {
        int idx = e * 256 + tid;   // 1024 float4s
        int r = idx >> 4, c4 = idx & 15;
        *(float4*)&As[r][c4 * 4] =
            *(const float4*)(A + (((size_t)(b * 32 + c)) * 64 + r) * 64 + c4 * 4);
    }
    int lane = tid & 63, wv = tid >> 6;
    int d = dg * 64 + lane;
    float vreg[64];
#pragma unroll
    for (int k = 0; k < 64; k++) vreg[k] = VR[((size_t)(b * L + c * T + k)) * D + d];
    float mreg[F];
#pragma unroll
    for (int f = 0; f < F; f++) mreg[f] = Mexc[(((size_t)(b * C + c)) * F + f) * D + d];
    __syncthreads();   // all V reads done before any ret write (cross-wave safety)
    for (int tr = 0; tr < 16; tr++) {
        int t = wv * 16 + tr;
        float acc = 0.f;
#pragma unroll
        for (int f = 0; f < F; f++) acc += Fq[t][f] * mreg[f];
#pragma unroll 8
        for (int k = 0; k <= t; k++) acc += As[t][k] * vreg[k];
        VR[((size_t)(b * L + c * T + t)) * D + d] = acc;
    }
}

// ---------------- final: +LTM, /nrm, LayerNorm, @w_out-half, +x -----------------
// grid (2 col-halves, 64 row-chunks, B)
__global__ __launch_bounds__(256) void final_kernel(
    const float* __restrict__ retp, const float* __restrict__ czsz,
    const float* __restrict__ ltm_mem, const float* __restrict__ ltm_count,
    const float* __restrict__ ltm_weight, const float* __restrict__ ln_gamma,
    const float* __restrict__ ln_beta, const float* __restrict__ w_out,
    const float* __restrict__ b_out, const float* __restrict__ x,
    float* __restrict__ out) {
    int half = blockIdx.x;
    int rc = blockIdx.y;
    int b  = blockIdx.z;
    int row0 = rc * 32;
    int tid = threadIdx.x;
    __shared__ float hb[32][257];
    __shared__ float ws2[16][132];
    __shared__ float cs[32][33];
    __shared__ float part1[32][8], part2[32][8];
    __shared__ float mu[32], rsig[32];
    float lsig = 1.f / (1.f + expf(-ltm_weight[0]));
    float pnorm = sqrtf(fmaxf(ltm_count[0], 1.f) * (float)LTMP);
    float lcoef = lsig / pnorm;
    float Mre[16], Mim[16];
#pragma unroll
    for (int p = 0; p < 16; p++) {
        Mre[p] = ltm_mem[(p * D + tid) * 2];
        Mim[p] = ltm_mem[(p * D + tid) * 2 + 1];
    }
    float gam = ln_gamma[tid], bet = ln_beta[tid];
    {
        int t = tid >> 3, q = tid & 7;
        int tg = row0 + t;
        for (int e = 0; e < 4; e++)
            cs[t][q * 4 + e] = czsz[((size_t)(b * L + tg)) * 32 + q * 4 + e];
    }
    __syncthreads();
    for (int t = 0; t < 32; t++) {
        int tg = row0 + t;
        float pers = 0.f;
#pragma unroll
        for (int p = 0; p < 16; p++) pers += Mre[p] * cs[t][p] + Mim[p] * cs[t][16 + p];
        float rv = retp[((size_t)(b * L + tg)) * D + tid];
        hb[t][tid] = (rv + lcoef * pers) / (2.0f * sqrtf((float)(tg + 1)));
    }
    __syncthreads();
    {
        int t = tid >> 3, q = tid & 7;
        float s1 = 0.f, s2 = 0.f;
        for (int k = 0; k < 32; k++) {
            float v = hb[t][q * 32 + k];
            s1 += v; s2 += v * v;
        }
        part1[t][q] = s1; part2[t][q] = s2;
    }
    __syncthreads();
    if (tid < 32) {
        float s1 = 0.f, s2 = 0.f;
        for (int q = 0; q < 8; q++) { s1 += part1[tid][q]; s2 += part2[tid][q]; }
        float m = s1 / 256.f;
        mu[tid] = m;
        rsig[tid] = rsqrtf(fmaxf(s2 / 256.f - m * m, 0.f) + 1e-5f);
    }
    __syncthreads();
    for (int t = 0; t < 32; t++)
        hb[t][tid] = (hb[t][tid] - mu[t]) * rsig[t] * gam + bet;
    __syncthreads();
    // GEMM: hb[32][256] @ w_out[:, half*128 + 0..127]
    int rg = tid >> 4, cg = tid & 15;   // rows {rg, rg+16}, cols cg*8
    float acc0[8], acc1[8];
#pragma unroll
    for (int e = 0; e < 8; e++) { acc0[e] = 0.f; acc1[e] = 0.f; }
    for (int kc = 0; kc < 16; kc++) {
        int kb = kc * 16;
#pragma unroll
        for (int e = 0; e < 2; e++) {
            int idx = e * 256 + tid;     // 512 float4s (16 rows x 32 f4)
            int r = idx >> 5, c4 = idx & 31;
            *(float4*)&ws2[r][c4 * 4] =
                *(const float4*)(w_out + (size_t)(kb + r) * D + half * 128 + c4 * 4);
        }
        __syncthreads();
#pragma unroll 4
        for (int j = 0; j < 16; j++) {
            float4 w0 = *(float4*)&ws2[j][cg * 8];
            float4 w1 = *(float4*)&ws2[j][cg * 8 + 4];
            float x0 = hb[rg][kb + j], x1 = hb[rg + 16][kb + j];
            acc0[0] += x0 * w0.x; acc0[1] += x0 * w0.y; acc0[2] += x0 * w0.z; acc0[3] += x0 * w0.w;
            acc0[4] += x0 * w1.x; acc0[5] += x0 * w1.y; acc0[6] += x0 * w1.z; acc0[7] += x0 * w1.w;
            acc1[0] += x1 * w0.x; acc1[1] += x1 * w0.y; acc1[2] += x1 * w0.z; acc1[3] += x1 * w0.w;
            acc1[4] += x1 * w1.x; acc1[5] += x1 * w1.y; acc1[6] += x1 * w1.z; acc1[7] += x1 * w1.w;
        }
        __syncthreads();
    }
    {
        int d0 = half * 128 + cg * 8;
        float4 bo0 = *(const float4*)(b_out + d0);
        float4 bo1 = *(const float4*)(b_out + d0 + 4);
        size_t o0 = ((size_t)(b * L + row0 + rg)) * D + d0;
        size_t o1 = ((size_t)(b * L + row0 + rg + 16)) * D + d0;
        float4 xa = *(const float4*)(x + o0);
        float4 xb = *(const float4*)(x + o0 + 4);
        float4 xc = *(const float4*)(x + o1);
        float4 xd = *(const float4*)(x + o1 + 4);
        *(float4*)(out + o0)     = make_float4(xa.x + acc0[0] + bo0.x, xa.y + acc0[1] + bo0.y,
                                               xa.z + acc0[2] + bo0.z, xa.w + acc0[3] + bo0.w);
        *(float4*)(out + o0 + 4) = make_float4(xb.x + acc0[4] + bo1.x, xb.y + acc0[5] + bo1.y,
                                               xb.z + acc0[6] + bo1.z, xb.w + acc0[7] + bo1.w);
        *(float4*)(out + o1)     = make_float4(xc.x + acc1[0] + bo0.x, xc.y + acc1[1] + bo0.y,
                                               xc.z + acc1[2] + bo0.z, xc.w + acc1[3] + bo0.w);
        *(float4*)(out + o1 + 4) = make_float4(xd.x + acc1[4] + bo1.x, xd.y + acc1[5] + bo1.y,
                                               xd.z + acc1[6] + bo1.z, xd.w + acc1[7] + bo1.w);
    }
}

extern "C" void kernel_launch(void* const* d_in, const int* in_sizes, int n_in,
                              void* d_out, int out_size, void* d_ws, size_t ws_size,
                              hipStream_t stream) {
    (void)in_sizes; (void)n_in; (void)out_size; (void)ws_size;
    const float* x            = (const float*)d_in[0];
    const float* key_proj     = (const float*)d_in[1];
    const float* query_proj   = (const float*)d_in[2];
    const float* ltm_key_proj = (const float*)d_in[3];
    const float* pos_freqs    = (const float*)d_in[4];
    const float* w_value      = (const float*)d_in[5];
    const float* b_value      = (const float*)d_in[6];
    const float* ln_gamma     = (const float*)d_in[9];
    const float* ln_beta      = (const float*)d_in[10];
    const float* w_out        = (const float*)d_in[11];
    const float* b_out        = (const float*)d_in[12];
    const float* set_weights  = (const float*)d_in[13];
    const float* pos_weight   = (const float*)d_in[14];
    const float* surprise_scale      = (const float*)d_in[15];
    const float* surprise_bias       = (const float*)d_in[16];
    const float* resonance_scale     = (const float*)d_in[17];
    const float* resonance_threshold = (const float*)d_in[18];
    const float* ltm_weight   = (const float*)d_in[19];
    const float* ltm_mem      = (const float*)d_in[20];
    const float* ltm_count    = (const float*)d_in[21];
    float* out = (float*)d_out;

    float* ws = (float*)d_ws;
    size_t off = 0;
    float* V     = ws + off; off += (size_t)B * L * D;       // also reused as ret
    float* fk    = ws + off; off += (size_t)B * L * 40;
    float* fq    = ws + off; off += (size_t)B * L * 40;
    float* posc  = ws + off; off += (size_t)L * POSP;
    float* poss  = ws + off; off += (size_t)L * POSP;
    float* Sx16  = ws + off; off += (size_t)B * 128 * D;
    float* Sxx16 = ws + off; off += (size_t)B * 128 * D;
    float* czsz  = ws + off; off += (size_t)B * L * 32;
    float* S     = ws + off; off += (size_t)B * C * F * D;   // becomes exclusive prefix
    float* A     = ws + off; off += (size_t)B * C * T * T;
    float* partial  = ws + off; off += (size_t)B * 64 * 8;
    float* chunkoff = ws + off; off += (size_t)B * 64 * 8;

    pos_kernel<<<dim3(128), 256, 0, stream>>>(pos_freqs, posc, poss);
    featurize_kernel<<<dim3(2, 64, B), 256, 0, stream>>>(x, key_proj, query_proj, w_value,
                                                         b_value, set_weights, V, fk, fq, partial);
    gs_scan_kernel<<<dim3(B), 512, 0, stream>>>(partial, chunkoff);
    gs_apply_kernel<<<dim3(64, B), 256, 0, stream>>>(fk, chunkoff, surprise_scale, surprise_bias,
                                                     resonance_scale, resonance_threshold);
    stats16_kernel<<<dim3(128, B), 256, 0, stream>>>(x, Sx16, Sxx16);
    ltm_z_kernel<<<dim3(128, B), 256, 0, stream>>>(x, Sx16, Sxx16, ltm_key_proj, czsz);
    outer_sums_kernel<<<dim3(2, C, B), 256, 0, stream>>>(V, fk, posc, poss, S);
    prefix_kernel<<<dim3(B * F), 256, 0, stream>>>(S);
    score_kernel<<<dim3(2, C, B), 256, 0, stream>>>(fk, fq, posc, poss, pos_weight, A);
    intra_kernel<<<dim3(4, C, B), 256, 0, stream>>>(V, fq, posc, poss, S, A, pos_weight);
    final_kernel<<<dim3(2, 64, B), 256, 0, stream>>>(V, czsz, ltm_mem, ltm_count, ltm_weight,
                                                     ln_gamma, ln_beta, w_out, b_out, x, out);
}

// Round 4
// 299.967 us; speedup vs baseline: 2.2522x; 1.1002x over previous
//
#include <hip/hip_runtime.h>
#include <math.h>

#define B 4
#define L 2048
#define D 256
#define POSP 16
#define LTMP 16
#define T 64
#define C 32
#define F 72
#define PI_F 3.14159274101257324f
#define TWO_PI_D 6.283185307179586476925286766559

// ---------------- positional phasors (exact fp32 angle, double reduction) --------
__global__ __launch_bounds__(256) void pos_kernel(const float* __restrict__ pos_freqs,
                                                  float* __restrict__ posc,
                                                  float* __restrict__ poss) {
    int idx = blockIdx.x * 256 + threadIdx.x;
    if (idx >= L * POSP) return;
    int t = idx >> 4, p = idx & 15;
    float a = (float)t * pos_freqs[p];   // replicate numpy op order in fp32
    float th = (a * 2.0f) * PI_F;
    double r = fmod((double)th, TWO_PI_D);
    posc[idx] = (float)cos(r);
    poss[idx] = (float)sin(r);
}

// ---------------- featurize: fused GEMM x @ [w_value | key_proj | query_proj] ---
// grid (4 col-groups of 64, 64 row-chunks of 32, B); cg0 also does key_proj->fk,
// cg1 also does query_proj->fq. 8 indep FMA chains / thread.
__global__ __launch_bounds__(256) void featurize_kernel(
    const float* __restrict__ x, const float* __restrict__ key_proj,
    const float* __restrict__ query_proj, const float* __restrict__ w_value,
    const float* __restrict__ b_value, const float* __restrict__ set_weights,
    float* __restrict__ V, float* __restrict__ fk, float* __restrict__ fq,
    float* __restrict__ partial) {
    int cg = blockIdx.x;
    int rc = blockIdx.y;
    int b  = blockIdx.z;
    int row0 = rc * 32;
    int tid = threadIdx.x;
    __shared__ float xs[32][36];
    __shared__ float ws[32][84];    // 64 V-cols + 16 proj cols + pad
    __shared__ float zbuf[32][18];
    __shared__ float jkv[32][9];
    const bool has_proj = (cg < 2);
    const float* proj = (cg == 0) ? key_proj : query_proj;
    int rr = tid >> 3, c8 = tid & 7;   // row rr (0..31), cols c8*8..+7
    float acc[8], accp[2];
#pragma unroll
    for (int e = 0; e < 8; e++) acc[e] = 0.f;
    accp[0] = 0.f; accp[1] = 0.f;

    for (int kc = 0; kc < 8; kc++) {
        int kb = kc * 32;
        *(float4*)&xs[tid >> 3][(tid & 7) * 4] =
            *(const float4*)(x + ((size_t)(b * L + row0 + (tid >> 3))) * D + kb + (tid & 7) * 4);
#pragma unroll
        for (int e = 0; e < 3; e++) {
            int idx = e * 256 + tid;
            if (idx < 640) {
                int j = idx / 20, c4 = idx - j * 20;
                if (c4 < 16)
                    *(float4*)&ws[j][c4 * 4] =
                        *(const float4*)(w_value + (size_t)(kb + j) * D + cg * 64 + c4 * 4);
                else if (has_proj)
                    *(float4*)&ws[j][64 + (c4 - 16) * 4] =
                        *(const float4*)(proj + (size_t)(kb + j) * 16 + (c4 - 16) * 4);
            }
        }
        __syncthreads();
#pragma unroll 4
        for (int j = 0; j < 32; j++) {
            float xv = xs[rr][j];
            float4 w0 = *(float4*)&ws[j][c8 * 8];
            float4 w1 = *(float4*)&ws[j][c8 * 8 + 4];
            acc[0] += xv * w0.x; acc[1] += xv * w0.y; acc[2] += xv * w0.z; acc[3] += xv * w0.w;
            acc[4] += xv * w1.x; acc[5] += xv * w1.y; acc[6] += xv * w1.z; acc[7] += xv * w1.w;
            if (has_proj) {
                float2 wp = *(float2*)&ws[j][64 + c8 * 2];
                accp[0] += xv * wp.x; accp[1] += xv * wp.y;
            }
        }
        __syncthreads();
    }
    // V epilogue
    {
        int d0 = cg * 64 + c8 * 8;
        float4 bv0 = *(const float4*)(b_value + d0);
        float4 bv1 = *(const float4*)(b_value + d0 + 4);
        size_t o = ((size_t)(b * L + row0 + rr)) * D + d0;
        *(float4*)(V + o)     = make_float4(acc[0] + bv0.x, acc[1] + bv0.y, acc[2] + bv0.z, acc[3] + bv0.w);
        *(float4*)(V + o + 4) = make_float4(acc[4] + bv1.x, acc[5] + bv1.y, acc[6] + bv1.z, acc[7] + bv1.w);
    }
    if (!has_proj) return;
    zbuf[rr][c8 * 2]     = tanhf(accp[0]) * PI_F;
    zbuf[rr][c8 * 2 + 1] = tanhf(accp[1]) * PI_F;
    __syncthreads();
    // phasor epilogue
    {
        int tt = tid >> 3, c2 = tid & 7;
        size_t bt = (size_t)(b * L + row0 + tt);
        if (cg == 0) {
            float* fp = fk + bt * 40;
#pragma unroll
            for (int e = 0; e < 2; e++) {
                int col = c2 * 2 + e;
                float si, co; sincosf(zbuf[tt][col], &si, &co);
                fp[2 * col] = co; fp[2 * col + 1] = si;
            }
            if (c2 < 4) {
                int p = c2;
                float zs = zbuf[tt][p] + zbuf[tt][4 + p] + zbuf[tt][8 + p] + zbuf[tt][12 + p];
                float si, co; sincosf(zs, &si, &co);
                fp[32 + 2 * p] = co; fp[33 + 2 * p] = si;
                jkv[tt][2 * p] = co; jkv[tt][2 * p + 1] = si;
            }
        } else {
            float sw0 = set_weights[0], sw1 = set_weights[1], sw2 = set_weights[2], sw3 = set_weights[3];
            float mx = fmaxf(fmaxf(sw0, sw1), fmaxf(sw2, sw3));
            float e0 = expf(sw0 - mx), e1 = expf(sw1 - mx), e2 = expf(sw2 - mx), e3 = expf(sw3 - mx);
            float esum = e0 + e1 + e2 + e3;
            float wsoft[4] = {e0 / esum, e1 / esum, e2 / esum, e3 / esum};
            float* fp = fq + bt * 40;
#pragma unroll
            for (int e = 0; e < 2; e++) {
                int col = c2 * 2 + e;
                float si, co; sincosf(zbuf[tt][col], &si, &co);
                float sc = 0.1f * wsoft[col >> 2];   // 0.5 * w_s / (NSETS+1)
                fp[2 * col] = sc * co; fp[2 * col + 1] = sc * si;
            }
            if (c2 < 4) {
                int p = c2;
                float zs = zbuf[tt][p] + zbuf[tt][4 + p] + zbuf[tt][8 + p] + zbuf[tt][12 + p];
                float si, co; sincosf(zs, &si, &co);
                fp[32 + 2 * p] = 0.1f * co; fp[33 + 2 * p] = 0.1f * si;
            }
        }
    }
    __syncthreads();
    if (cg == 0) {   // reduce ungated jk over the 32 rows -> chunk partial
        int r2 = tid >> 3, ch = tid & 7;
#pragma unroll
        for (int s2 = 16; s2 >= 1; s2 >>= 1) {
            if (r2 < s2) jkv[r2][ch] += jkv[r2 + s2][ch];
            __syncthreads();
        }
        if (r2 == 0) partial[((size_t)(b * 64 + rc)) * 8 + ch] = jkv[0][ch];
    }
}

// ---------------- gate scan phase 2: exclusive scan of 64 chunk partials --------
__global__ __launch_bounds__(512) void gs_scan_kernel(const float* __restrict__ partial,
                                                      float* __restrict__ chunkoff) {
    int b = blockIdx.x;
    int tid = threadIdx.x;   // 512 = 64 chunks x 8 ch
    int c = tid >> 3, ch = tid & 7;
    __shared__ float sc_[64][9];
    float own = partial[((size_t)(b * 64 + c)) * 8 + ch];
    sc_[c][ch] = own;
    __syncthreads();
    for (int off = 1; off < 64; off <<= 1) {
        float v = 0.f;
        if (c >= off) v = sc_[c - off][ch];
        __syncthreads();
        if (c >= off) sc_[c][ch] += v;
        __syncthreads();
    }
    chunkoff[((size_t)(b * 64 + c)) * 8 + ch] = sc_[c][ch] - own;
}

// ---------------- gate scan phase 3: local scan, gate, scale fk -----------------
__global__ __launch_bounds__(256) void gs_apply_kernel(
    float* __restrict__ fk, const float* __restrict__ chunkoff,
    const float* __restrict__ surprise_scale, const float* __restrict__ surprise_bias,
    const float* __restrict__ resonance_scale, const float* __restrict__ resonance_threshold) {
    int rc = blockIdx.x, b = blockIdx.y;
    int tid = threadIdx.x;
    int t = tid >> 3, ch = tid & 7;
    __shared__ float sc_[32][9];
    __shared__ float gbuf[32];
    float* fp = fk + ((size_t)(b * L + rc * 32 + t)) * 40;
    float own = fp[32 + ch];
    sc_[t][ch] = own;
    __syncthreads();
    for (int off = 1; off < 32; off <<= 1) {
        float v = 0.f;
        if (t >= off) v = sc_[t - off][ch];
        __syncthreads();
        if (t >= off) sc_[t][ch] += v;
        __syncthreads();
    }
    float run = chunkoff[((size_t)(b * 64 + rc)) * 8 + ch] + sc_[t][ch] - own;
    __syncthreads();
    sc_[t][ch] = run;
    __syncthreads();
    if (tid < 32) {
        int tg = rc * 32 + tid;
        float r0 = sc_[tid][0], r1 = sc_[tid][1], r2 = sc_[tid][2], r3 = sc_[tid][3];
        float r4 = sc_[tid][4], r5 = sc_[tid][5], r6 = sc_[tid][6], r7 = sc_[tid][7];
        float rmag = 0.25f * (sqrtf(r0 * r0 + r1 * r1) + sqrtf(r2 * r2 + r3 * r3) +
                              sqrtf(r4 * r4 + r5 * r5) + sqrtf(r6 * r6 + r7 * r7));
        float scv = fminf(fmaxf(resonance_scale[0], 1.f), 20.f);
        float thv = fminf(fmaxf(resonance_threshold[0], 0.1f), 0.9f);
        float nres = rmag / sqrtf(fmaxf((float)tg, 1.0f));
        float surprise = 0.5f * (1.0f - tanhf(scv * (nres - thv)));
        gbuf[tid] = 1.0f / (1.0f + expf(-(surprise_scale[0] * (surprise - 0.5f) + surprise_bias[0])));
    }
    __syncthreads();
    float gv = gbuf[t];
#pragma unroll
    for (int e = 0; e < 5; e++) fp[ch * 5 + e] *= gv;
}

// ---------------- 16-row sub-chunk sums of x, x^2 (LTM stats) -------------------
__global__ __launch_bounds__(256) void stats16_kernel(const float* __restrict__ x,
                                                      float* __restrict__ Sx16,
                                                      float* __restrict__ Sxx16) {
    int s = blockIdx.x, b = blockIdx.y;
    int d = threadIdx.x;
    float sx = 0.f, sxx = 0.f;
#pragma unroll
    for (int k = 0; k < 16; k++) {
        float v = x[((size_t)(b * L + s * 16 + k)) * D + d];
        sx += v; sxx += v * v;
    }
    Sx16[((size_t)(b * 128 + s)) * D + d] = sx;
    Sxx16[((size_t)(b * 128 + s)) * D + d] = sxx;
}

// ---------------- LTM phasor angles, 16 rows per block --------------------------
__global__ __launch_bounds__(256) void ltm_z_kernel(
    const float* __restrict__ x, const float* __restrict__ Sx16,
    const float* __restrict__ Sxx16, const float* __restrict__ W,
    float* __restrict__ czsz) {
    int s = blockIdx.x, b = blockIdx.y;
    int tid = threadIdx.x;
    __shared__ float xs[16][257], rms[16][257], rss[16][257];
    float a0 = 0.f, a1 = 0.f, a2 = 0.f, a3 = 0.f;
    float c0 = 0.f, c1 = 0.f, c2 = 0.f, c3 = 0.f;
    int sp = 0;
    for (; sp + 4 <= s; sp += 4) {
        a0 += Sx16[((size_t)(b * 128 + sp)) * D + tid];
        a1 += Sx16[((size_t)(b * 128 + sp + 1)) * D + tid];
        a2 += Sx16[((size_t)(b * 128 + sp + 2)) * D + tid];
        a3 += Sx16[((size_t)(b * 128 + sp + 3)) * D + tid];
        c0 += Sxx16[((size_t)(b * 128 + sp)) * D + tid];
        c1 += Sxx16[((size_t)(b * 128 + sp + 1)) * D + tid];
        c2 += Sxx16[((size_t)(b * 128 + sp + 2)) * D + tid];
        c3 += Sxx16[((size_t)(b * 128 + sp + 3)) * D + tid];
    }
    for (; sp < s; sp++) {
        a0 += Sx16[((size_t)(b * 128 + sp)) * D + tid];
        c0 += Sxx16[((size_t)(b * 128 + sp)) * D + tid];
    }
    float runx = (a0 + a1) + (a2 + a3), runxx = (c0 + c1) + (c2 + c3);
    for (int k = 0; k < 16; k++) {
        int tg = s * 16 + k;
        float xv = x[((size_t)(b * L + tg)) * D + tid];
        runx += xv; runxx += xv * xv;
        float n = (float)(tg + 1);
        float rm = runx / n;
        float rv = runxx / n - rm * rm;
        xs[k][tid] = xv; rms[k][tid] = rm;
        rss[k][tid] = sqrtf(fmaxf(rv, 1e-8f));
    }
    __syncthreads();
    int tl = tid >> 4, p = tid & 15;
    const float* Wp = W + p;
    float u0 = 0.f, u1 = 0.f, u2 = 0.f;
#pragma unroll 4
    for (int j = 0; j < 256; j++) {
        u0 += xs[tl][j] * Wp[j * LTMP];
        u1 += rms[tl][j] * Wp[(256 + j) * LTMP];
        u2 += rss[tl][j] * Wp[(512 + j) * LTMP];
    }
    float z = tanhf(u0 + u1 + u2) * PI_F;
    float si, co; sincosf(z, &si, &co);
    int tg = s * 16 + tl;
    czsz[((size_t)(b * L + tg)) * 32 + p] = co;
    czsz[((size_t)(b * L + tg)) * 32 + 16 + p] = si;
}

// ---------------- per-chunk outer-product sums S[b,c,f,d] -----------------------
__global__ __launch_bounds__(256) void outer_sums_kernel(
    const float* __restrict__ V, const float* __restrict__ fk,
    const float* __restrict__ posc, const float* __restrict__ poss,
    float* __restrict__ S) {
    int g = blockIdx.x;   // 2 feature groups of 36
    int c = blockIdx.y;   // 32
    int b = blockIdx.z;   // 4
    int tid = threadIdx.x;
    __shared__ float Fk[T][40];
    int F0 = g * 36;
    {
        int t = tid >> 2, q = tid & 3;
        int tg = c * T + t;
        for (int e = 0; e < 9; e++) {
            int fl = q * 9 + e;
            int Fi = F0 + fl;
            float v;
            if (Fi < 40) v = fk[((size_t)(b * L + tg)) * 40 + Fi];
            else {
                int pf = Fi - 40;
                v = (pf & 1) ? poss[tg * POSP + (pf >> 1)] : posc[tg * POSP + (pf >> 1)];
            }
            Fk[t][fl] = v;
        }
    }
    __syncthreads();
    float acc[36];
#pragma unroll
    for (int f = 0; f < 36; f++) acc[f] = 0.f;
    for (int t = 0; t < T; t++) {
        float v = V[((size_t)(b * L + c * T + t)) * D + tid];
#pragma unroll
        for (int f = 0; f < 36; f++) acc[f] += Fk[t][f] * v;
    }
    for (int f = 0; f < 36; f++)
        S[(((size_t)(b * C + c)) * F + F0 + f) * D + tid] = acc[f];
}

// ---------------- in-place exclusive prefix of S over chunks --------------------
__global__ __launch_bounds__(256) void prefix_kernel(float* __restrict__ S) {
    int bf = blockIdx.x;
    int b = bf / F, f = bf % F;
    int d = threadIdx.x;
    float run = 0.f;
    for (int c = 0; c < C; c++) {
        size_t idx = (((size_t)(b * C + c)) * F + f) * D + d;
        float v = S[idx];
        S[idx] = run;
        run += v;
    }
}

// ---------------- intra (fused score): ret = Fq·M + A·V -------------------------
// grid (8 = 4 tg x 2 dh, 32 c, B); 256 threads; A computed in-LDS.
__global__ __launch_bounds__(256) void intra_kernel(
    const float* __restrict__ V, float* __restrict__ ret,
    const float* __restrict__ fk, const float* __restrict__ fq,
    const float* __restrict__ posc, const float* __restrict__ poss,
    const float* __restrict__ Mexc, const float* __restrict__ pos_weight) {
    int tg = blockIdx.x >> 1, dh = blockIdx.x & 1;
    int c = blockIdx.y, b = blockIdx.z;
    int tid = threadIdx.x;
    int t0 = tg * 16;
    __shared__ float Fk[64][76];
    __shared__ float Fq[16][76];
    __shared__ float As[16][68];
    float posq = 0.5f / (1.0f + expf(-pos_weight[0]));
    // stage Fk: full chunk (64 rows x 72 feats)
#pragma unroll
    for (int e = 0; e < 18; e++) {
        int idx = e * 256 + tid;
        int r = idx / 72, f = idx - r * 72;
        int tgl = c * T + r;
        float v;
        if (f < 40) v = fk[((size_t)(b * L + tgl)) * 40 + f];
        else { int pf = f - 40; v = (pf & 1) ? poss[tgl * POSP + (pf >> 1)] : posc[tgl * POSP + (pf >> 1)]; }
        Fk[r][f] = v;
    }
    // stage Fq: this block's 16 rows
#pragma unroll
    for (int e = 0; e < 5; e++) {
        int idx = e * 256 + tid;
        if (idx < 1152) {
            int r = idx / 72, f = idx - r * 72;
            int tgl = c * T + t0 + r;
            float v;
            if (f < 40) v = fq[((size_t)(b * L + tgl)) * 40 + f];
            else { int pf = f - 40; v = posq * ((pf & 1) ? poss[tgl * POSP + (pf >> 1)] : posc[tgl * POSP + (pf >> 1)]); }
            Fq[r][f] = v;
        }
    }
    __syncthreads();
    // A[r][k] = (k <= t0+r) ? Fq[r]·Fk[k] : 0     (16 x 64, 4 k's per thread)
    {
        int r = tid >> 4, k0 = (tid & 15) * 4;
        int tglob = t0 + r;
#pragma unroll
        for (int j = 0; j < 4; j++) {
            int k = k0 + j;
            float a = 0.f;
            if (k <= tglob) {
#pragma unroll
                for (int f = 0; f < F; f++) a += Fq[r][f] * Fk[k][f];
            }
            As[r][k] = a;
        }
    }
    __syncthreads();
    // main: thread owns column d, 8 rows; stream M then V from global
    int dl = tid & 127, rowg = tid >> 7;
    int d = dh * 128 + dl;
    int r0 = rowg * 8;
    float acc[8];
#pragma unroll
    for (int i = 0; i < 8; i++) acc[i] = 0.f;
    const float* Mp = Mexc + (((size_t)(b * C + c)) * F) * D + d;
#pragma unroll 8
    for (int f = 0; f < F; f++) {
        float m = Mp[(size_t)f * D];
#pragma unroll
        for (int i = 0; i < 8; i++) acc[i] += Fq[r0 + i][f] * m;
    }
    const float* Vp = V + ((size_t)(b * L + c * T)) * D + d;
    int kmax = t0 + 16;
#pragma unroll 8
    for (int k = 0; k < kmax; k++) {
        float v = Vp[(size_t)k * D];
#pragma unroll
        for (int i = 0; i < 8; i++) acc[i] += As[r0 + i][k] * v;
    }
    float* Rp = ret + ((size_t)(b * L + c * T + t0 + r0)) * D + d;
#pragma unroll
    for (int i = 0; i < 8; i++) Rp[(size_t)i * D] = acc[i];
}

// ---------------- final: +LTM, /nrm, LayerNorm, @w_out (64-col groups), +x ------
// grid (4 col-groups, 64 row-chunks, B)
__global__ __launch_bounds__(256) void final_kernel(
    const float* __restrict__ retp, const float* __restrict__ czsz,
    const float* __restrict__ ltm_mem, const float* __restrict__ ltm_count,
    const float* __restrict__ ltm_weight, const float* __restrict__ ln_gamma,
    const float* __restrict__ ln_beta, const float* __restrict__ w_out,
    const float* __restrict__ b_out, const float* __restrict__ x,
    float* __restrict__ out) {
    int cg = blockIdx.x;
    int rc = blockIdx.y;
    int b  = blockIdx.z;
    int row0 = rc * 32;
    int tid = threadIdx.x;
    __shared__ float hb[32][257];
    __shared__ float ws2[16][68];
    __shared__ float cs[32][33];
    __shared__ float part1[32][8], part2[32][8];
    __shared__ float mu[32], rsig[32];
    float lsig = 1.f / (1.f + expf(-ltm_weight[0]));
    float pnorm = sqrtf(fmaxf(ltm_count[0], 1.f) * (float)LTMP);
    float lcoef = lsig / pnorm;
    float Mre[16], Mim[16];
#pragma unroll
    for (int p = 0; p < 16; p++) {
        Mre[p] = ltm_mem[(p * D + tid) * 2];
        Mim[p] = ltm_mem[(p * D + tid) * 2 + 1];
    }
    float gam = ln_gamma[tid], bet = ln_beta[tid];
    {
        int t = tid >> 3, q = tid & 7;
        int tg = row0 + t;
        for (int e = 0; e < 4; e++)
            cs[t][q * 4 + e] = czsz[((size_t)(b * L + tg)) * 32 + q * 4 + e];
    }
    __syncthreads();
    for (int t = 0; t < 32; t++) {
        int tg = row0 + t;
        float pers = 0.f;
#pragma unroll
        for (int p = 0; p < 16; p++) pers += Mre[p] * cs[t][p] + Mim[p] * cs[t][16 + p];
        float rv = retp[((size_t)(b * L + tg)) * D + tid];
        hb[t][tid] = (rv + lcoef * pers) / (2.0f * sqrtf((float)(tg + 1)));
    }
    __syncthreads();
    {
        int t = tid >> 3, q = tid & 7;
        float s1 = 0.f, s2 = 0.f;
        for (int k = 0; k < 32; k++) {
            float v = hb[t][q * 32 + k];
            s1 += v; s2 += v * v;
        }
        part1[t][q] = s1; part2[t][q] = s2;
    }
    __syncthreads();
    if (tid < 32) {
        float s1 = 0.f, s2 = 0.f;
        for (int q = 0; q < 8; q++) { s1 += part1[tid][q]; s2 += part2[tid][q]; }
        float m = s1 / 256.f;
        mu[tid] = m;
        rsig[tid] = rsqrtf(fmaxf(s2 / 256.f - m * m, 0.f) + 1e-5f);
    }
    __syncthreads();
    for (int t = 0; t < 32; t++)
        hb[t][tid] = (hb[t][tid] - mu[t]) * rsig[t] * gam + bet;
    __syncthreads();
    // GEMM: hb[32][256] @ w_out[:, cg*64 .. cg*64+63]
    int rr = tid >> 3, c8 = tid & 7;
    float acc[8];
#pragma unroll
    for (int e = 0; e < 8; e++) acc[e] = 0.f;
    for (int kc = 0; kc < 16; kc++) {
        int kb = kc * 16;
        {
            int r = tid >> 4, c4 = tid & 15;
            *(float4*)&ws2[r][c4 * 4] =
                *(const float4*)(w_out + (size_t)(kb + r) * D + cg * 64 + c4 * 4);
        }
        __syncthreads();
#pragma unroll 4
        for (int j = 0; j < 16; j++) {
            float xv = hb[rr][kb + j];
            float4 w0 = *(float4*)&ws2[j][c8 * 8];
            float4 w1 = *(float4*)&ws2[j][c8 * 8 + 4];
            acc[0] += xv * w0.x; acc[1] += xv * w0.y; acc[2] += xv * w0.z; acc[3] += xv * w0.w;
            acc[4] += xv * w1.x; acc[5] += xv * w1.y; acc[6] += xv * w1.z; acc[7] += xv * w1.w;
        }
        __syncthreads();
    }
    {
        int d0 = cg * 64 + c8 * 8;
        float4 bo0 = *(const float4*)(b_out + d0);
        float4 bo1 = *(const float4*)(b_out + d0 + 4);
        size_t o = ((size_t)(b * L + row0 + rr)) * D + d0;
        float4 xa = *(const float4*)(x + o);
        float4 xb = *(const float4*)(x + o + 4);
        *(float4*)(out + o)     = make_float4(xa.x + acc[0] + bo0.x, xa.y + acc[1] + bo0.y,
                                              xa.z + acc[2] + bo0.z, xa.w + acc[3] + bo0.w);
        *(float4*)(out + o + 4) = make_float4(xb.x + acc[4] + bo1.x, xb.y + acc[5] + bo1.y,
                                              xb.z + acc[6] + bo1.z, xb.w + acc[7] + bo1.w);
    }
}

extern "C" void kernel_launch(void* const* d_in, const int* in_sizes, int n_in,
                              void* d_out, int out_size, void* d_ws, size_t ws_size,
                              hipStream_t stream) {
    (void)in_sizes; (void)n_in; (void)out_size; (void)ws_size;
    const float* x            = (const float*)d_in[0];
    const float* key_proj     = (const float*)d_in[1];
    const float* query_proj   = (const float*)d_in[2];
    const float* ltm_key_proj = (const float*)d_in[3];
    const float* pos_freqs    = (const float*)d_in[4];
    const float* w_value      = (const float*)d_in[5];
    const float* b_value      = (const float*)d_in[6];
    const float* ln_gamma     = (const float*)d_in[9];
    const float* ln_beta      = (const float*)d_in[10];
    const float* w_out        = (const float*)d_in[11];
    const float* b_out        = (const float*)d_in[12];
    const float* set_weights  = (const float*)d_in[13];
    const float* pos_weight   = (const float*)d_in[14];
    const float* surprise_scale      = (const float*)d_in[15];
    const float* surprise_bias       = (const float*)d_in[16];
    const float* resonance_scale     = (const float*)d_in[17];
    const float* resonance_threshold = (const float*)d_in[18];
    const float* ltm_weight   = (const float*)d_in[19];
    const float* ltm_mem      = (const float*)d_in[20];
    const float* ltm_count    = (const float*)d_in[21];
    float* out = (float*)d_out;

    float* ws = (float*)d_ws;
    size_t off = 0;
    float* V     = ws + off; off += (size_t)B * L * D;
    float* ret   = ws + off; off += (size_t)B * L * D;
    float* fk    = ws + off; off += (size_t)B * L * 40;
    float* fq    = ws + off; off += (size_t)B * L * 40;
    float* posc  = ws + off; off += (size_t)L * POSP;
    float* poss  = ws + off; off += (size_t)L * POSP;
    float* Sx16  = ws + off; off += (size_t)B * 128 * D;
    float* Sxx16 = ws + off; off += (size_t)B * 128 * D;
    float* czsz  = ws + off; off += (size_t)B * L * 32;
    float* S     = ws + off; off += (size_t)B * C * F * D;   // becomes exclusive prefix
    float* partial  = ws + off; off += (size_t)B * 64 * 8;
    float* chunkoff = ws + off; off += (size_t)B * 64 * 8;

    pos_kernel<<<dim3(128), 256, 0, stream>>>(pos_freqs, posc, poss);
    featurize_kernel<<<dim3(4, 64, B), 256, 0, stream>>>(x, key_proj, query_proj, w_value,
                                                         b_value, set_weights, V, fk, fq, partial);
    gs_scan_kernel<<<dim3(B), 512, 0, stream>>>(partial, chunkoff);
    gs_apply_kernel<<<dim3(64, B), 256, 0, stream>>>(fk, chunkoff, surprise_scale, surprise_bias,
                                                     resonance_scale, resonance_threshold);
    stats16_kernel<<<dim3(128, B), 256, 0, stream>>>(x, Sx16, Sxx16);
    ltm_z_kernel<<<dim3(128, B), 256, 0, stream>>>(x, Sx16, Sxx16, ltm_key_proj, czsz);
    outer_sums_kernel<<<dim3(2, C, B), 256, 0, stream>>>(V, fk, posc, poss, S);
    prefix_kernel<<<dim3(B * F), 256, 0, stream>>>(S);
    intra_kernel<<<dim3(8, C, B), 256, 0, stream>>>(V, ret, fk, fq, posc, poss, S, pos_weight);
    final_kernel<<<dim3(4, 64, B), 256, 0, stream>>>(ret, czsz, ltm_mem, ltm_count, ltm_weight,
                                                     ln_gamma, ln_beta, w_out, b_out, x, out);
}

// Round 5
// 271.606 us; speedup vs baseline: 2.4873x; 1.1044x over previous
//
#include <hip/hip_runtime.h>
#include <math.h>

#define B 4
#define L 2048
#define D 256
#define POSP 16
#define LTMP 16
#define T 64
#define C 32
#define F 72
#define PI_F 3.14159274101257324f
#define TWO_PI_D 6.283185307179586476925286766559

// ---------------- positional phasors (exact fp32 angle, double reduction) --------
__global__ __launch_bounds__(256) void pos_kernel(const float* __restrict__ pos_freqs,
                                                  float* __restrict__ posc,
                                                  float* __restrict__ poss) {
    int idx = blockIdx.x * 256 + threadIdx.x;
    if (idx >= L * POSP) return;
    int t = idx >> 4, p = idx & 15;
    float a = (float)t * pos_freqs[p];   // replicate numpy op order in fp32
    float th = (a * 2.0f) * PI_F;
    double r = fmod((double)th, TWO_PI_D);
    posc[idx] = (float)cos(r);
    poss[idx] = (float)sin(r);
}

// ---------------- featurize: fused GEMM x @ [w_value | key_proj | query_proj] ---
// grid (4 col-groups of 64, 64 row-chunks of 32, B); cg0 also does key_proj->fk,
// cg1 also does query_proj->fq. 8 indep FMA chains / thread.
__global__ __launch_bounds__(256) void featurize_kernel(
    const float* __restrict__ x, const float* __restrict__ key_proj,
    const float* __restrict__ query_proj, const float* __restrict__ w_value,
    const float* __restrict__ b_value, const float* __restrict__ set_weights,
    float* __restrict__ V, float* __restrict__ fk, float* __restrict__ fq,
    float* __restrict__ partial) {
    int cg = blockIdx.x;
    int rc = blockIdx.y;
    int b  = blockIdx.z;
    int row0 = rc * 32;
    int tid = threadIdx.x;
    __shared__ float xs[32][36];
    __shared__ float ws[32][84];    // 64 V-cols + 16 proj cols + pad
    __shared__ float zbuf[32][18];
    __shared__ float jkv[32][9];
    const bool has_proj = (cg < 2);
    const float* proj = (cg == 0) ? key_proj : query_proj;
    int rr = tid >> 3, c8 = tid & 7;   // row rr (0..31), cols c8*8..+7
    float acc[8], accp[2];
#pragma unroll
    for (int e = 0; e < 8; e++) acc[e] = 0.f;
    accp[0] = 0.f; accp[1] = 0.f;

    for (int kc = 0; kc < 8; kc++) {
        int kb = kc * 32;
        *(float4*)&xs[tid >> 3][(tid & 7) * 4] =
            *(const float4*)(x + ((size_t)(b * L + row0 + (tid >> 3))) * D + kb + (tid & 7) * 4);
#pragma unroll
        for (int e = 0; e < 3; e++) {
            int idx = e * 256 + tid;
            if (idx < 640) {
                int j = idx / 20, c4 = idx - j * 20;
                if (c4 < 16)
                    *(float4*)&ws[j][c4 * 4] =
                        *(const float4*)(w_value + (size_t)(kb + j) * D + cg * 64 + c4 * 4);
                else if (has_proj)
                    *(float4*)&ws[j][64 + (c4 - 16) * 4] =
                        *(const float4*)(proj + (size_t)(kb + j) * 16 + (c4 - 16) * 4);
            }
        }
        __syncthreads();
#pragma unroll 4
        for (int j = 0; j < 32; j++) {
            float xv = xs[rr][j];
            float4 w0 = *(float4*)&ws[j][c8 * 8];
            float4 w1 = *(float4*)&ws[j][c8 * 8 + 4];
            acc[0] += xv * w0.x; acc[1] += xv * w0.y; acc[2] += xv * w0.z; acc[3] += xv * w0.w;
            acc[4] += xv * w1.x; acc[5] += xv * w1.y; acc[6] += xv * w1.z; acc[7] += xv * w1.w;
            if (has_proj) {
                float2 wp = *(float2*)&ws[j][64 + c8 * 2];
                accp[0] += xv * wp.x; accp[1] += xv * wp.y;
            }
        }
        __syncthreads();
    }
    // V epilogue
    {
        int d0 = cg * 64 + c8 * 8;
        float4 bv0 = *(const float4*)(b_value + d0);
        float4 bv1 = *(const float4*)(b_value + d0 + 4);
        size_t o = ((size_t)(b * L + row0 + rr)) * D + d0;
        *(float4*)(V + o)     = make_float4(acc[0] + bv0.x, acc[1] + bv0.y, acc[2] + bv0.z, acc[3] + bv0.w);
        *(float4*)(V + o + 4) = make_float4(acc[4] + bv1.x, acc[5] + bv1.y, acc[6] + bv1.z, acc[7] + bv1.w);
    }
    if (!has_proj) return;
    zbuf[rr][c8 * 2]     = tanhf(accp[0]) * PI_F;
    zbuf[rr][c8 * 2 + 1] = tanhf(accp[1]) * PI_F;
    __syncthreads();
    // phasor epilogue
    {
        int tt = tid >> 3, c2 = tid & 7;
        size_t bt = (size_t)(b * L + row0 + tt);
        if (cg == 0) {
            float* fp = fk + bt * 40;
#pragma unroll
            for (int e = 0; e < 2; e++) {
                int col = c2 * 2 + e;
                float si, co; sincosf(zbuf[tt][col], &si, &co);
                fp[2 * col] = co; fp[2 * col + 1] = si;
            }
            if (c2 < 4) {
                int p = c2;
                float zs = zbuf[tt][p] + zbuf[tt][4 + p] + zbuf[tt][8 + p] + zbuf[tt][12 + p];
                float si, co; sincosf(zs, &si, &co);
                fp[32 + 2 * p] = co; fp[33 + 2 * p] = si;
                jkv[tt][2 * p] = co; jkv[tt][2 * p + 1] = si;
            }
        } else {
            float sw0 = set_weights[0], sw1 = set_weights[1], sw2 = set_weights[2], sw3 = set_weights[3];
            float mx = fmaxf(fmaxf(sw0, sw1), fmaxf(sw2, sw3));
            float e0 = expf(sw0 - mx), e1 = expf(sw1 - mx), e2 = expf(sw2 - mx), e3 = expf(sw3 - mx);
            float esum = e0 + e1 + e2 + e3;
            float wsoft[4] = {e0 / esum, e1 / esum, e2 / esum, e3 / esum};
            float* fp = fq + bt * 40;
#pragma unroll
            for (int e = 0; e < 2; e++) {
                int col = c2 * 2 + e;
                float si, co; sincosf(zbuf[tt][col], &si, &co);
                float sc = 0.1f * wsoft[col >> 2];   // 0.5 * w_s / (NSETS+1)
                fp[2 * col] = sc * co; fp[2 * col + 1] = sc * si;
            }
            if (c2 < 4) {
                int p = c2;
                float zs = zbuf[tt][p] + zbuf[tt][4 + p] + zbuf[tt][8 + p] + zbuf[tt][12 + p];
                float si, co; sincosf(zs, &si, &co);
                fp[32 + 2 * p] = 0.1f * co; fp[33 + 2 * p] = 0.1f * si;
            }
        }
    }
    __syncthreads();
    if (cg == 0) {   // reduce ungated jk over the 32 rows -> chunk partial
        int r2 = tid >> 3, ch = tid & 7;
#pragma unroll
        for (int s2 = 16; s2 >= 1; s2 >>= 1) {
            if (r2 < s2) jkv[r2][ch] += jkv[r2 + s2][ch];
            __syncthreads();
        }
        if (r2 == 0) partial[((size_t)(b * 64 + rc)) * 8 + ch] = jkv[0][ch];
    }
}

// ---------------- gate scan phase 2: exclusive scan of 64 chunk partials --------
__global__ __launch_bounds__(512) void gs_scan_kernel(const float* __restrict__ partial,
                                                      float* __restrict__ chunkoff) {
    int b = blockIdx.x;
    int tid = threadIdx.x;   // 512 = 64 chunks x 8 ch
    int c = tid >> 3, ch = tid & 7;
    __shared__ float sc_[64][9];
    float own = partial[((size_t)(b * 64 + c)) * 8 + ch];
    sc_[c][ch] = own;
    __syncthreads();
    for (int off = 1; off < 64; off <<= 1) {
        float v = 0.f;
        if (c >= off) v = sc_[c - off][ch];
        __syncthreads();
        if (c >= off) sc_[c][ch] += v;
        __syncthreads();
    }
    chunkoff[((size_t)(b * 64 + c)) * 8 + ch] = sc_[c][ch] - own;
}

// ---------------- gate scan phase 3: local scan, gate, scale fk -----------------
__global__ __launch_bounds__(256) void gs_apply_kernel(
    float* __restrict__ fk, const float* __restrict__ chunkoff,
    const float* __restrict__ surprise_scale, const float* __restrict__ surprise_bias,
    const float* __restrict__ resonance_scale, const float* __restrict__ resonance_threshold) {
    int rc = blockIdx.x, b = blockIdx.y;
    int tid = threadIdx.x;
    int t = tid >> 3, ch = tid & 7;
    __shared__ float sc_[32][9];
    __shared__ float gbuf[32];
    float* fp = fk + ((size_t)(b * L + rc * 32 + t)) * 40;
    float own = fp[32 + ch];
    sc_[t][ch] = own;
    __syncthreads();
    for (int off = 1; off < 32; off <<= 1) {
        float v = 0.f;
        if (t >= off) v = sc_[t - off][ch];
        __syncthreads();
        if (t >= off) sc_[t][ch] += v;
        __syncthreads();
    }
    float run = chunkoff[((size_t)(b * 64 + rc)) * 8 + ch] + sc_[t][ch] - own;
    __syncthreads();
    sc_[t][ch] = run;
    __syncthreads();
    if (tid < 32) {
        int tg = rc * 32 + tid;
        float r0 = sc_[tid][0], r1 = sc_[tid][1], r2 = sc_[tid][2], r3 = sc_[tid][3];
        float r4 = sc_[tid][4], r5 = sc_[tid][5], r6 = sc_[tid][6], r7 = sc_[tid][7];
        float rmag = 0.25f * (sqrtf(r0 * r0 + r1 * r1) + sqrtf(r2 * r2 + r3 * r3) +
                              sqrtf(r4 * r4 + r5 * r5) + sqrtf(r6 * r6 + r7 * r7));
        float scv = fminf(fmaxf(resonance_scale[0], 1.f), 20.f);
        float thv = fminf(fmaxf(resonance_threshold[0], 0.1f), 0.9f);
        float nres = rmag / sqrtf(fmaxf((float)tg, 1.0f));
        float surprise = 0.5f * (1.0f - tanhf(scv * (nres - thv)));
        gbuf[tid] = 1.0f / (1.0f + expf(-(surprise_scale[0] * (surprise - 0.5f) + surprise_bias[0])));
    }
    __syncthreads();
    float gv = gbuf[t];
#pragma unroll
    for (int e = 0; e < 5; e++) fp[ch * 5 + e] *= gv;
}

// ---------------- 16-row sub-chunk sums of x, x^2 (LTM stats) -------------------
__global__ __launch_bounds__(256) void stats16_kernel(const float* __restrict__ x,
                                                      float* __restrict__ Sx16,
                                                      float* __restrict__ Sxx16) {
    int s = blockIdx.x, b = blockIdx.y;
    int d = threadIdx.x;
    float sx = 0.f, sxx = 0.f;
#pragma unroll
    for (int k = 0; k < 16; k++) {
        float v = x[((size_t)(b * L + s * 16 + k)) * D + d];
        sx += v; sxx += v * v;
    }
    Sx16[((size_t)(b * 128 + s)) * D + d] = sx;
    Sxx16[((size_t)(b * 128 + s)) * D + d] = sxx;
}

// ---------------- LTM phasor angles, 16 rows per block --------------------------
__global__ __launch_bounds__(256) void ltm_z_kernel(
    const float* __restrict__ x, const float* __restrict__ Sx16,
    const float* __restrict__ Sxx16, const float* __restrict__ W,
    float* __restrict__ czsz) {
    int s = blockIdx.x, b = blockIdx.y;
    int tid = threadIdx.x;
    __shared__ float xs[16][257], rms[16][257], rss[16][257];
    float a0 = 0.f, a1 = 0.f, a2 = 0.f, a3 = 0.f;
    float c0 = 0.f, c1 = 0.f, c2 = 0.f, c3 = 0.f;
    int sp = 0;
    for (; sp + 4 <= s; sp += 4) {
        a0 += Sx16[((size_t)(b * 128 + sp)) * D + tid];
        a1 += Sx16[((size_t)(b * 128 + sp + 1)) * D + tid];
        a2 += Sx16[((size_t)(b * 128 + sp + 2)) * D + tid];
        a3 += Sx16[((size_t)(b * 128 + sp + 3)) * D + tid];
        c0 += Sxx16[((size_t)(b * 128 + sp)) * D + tid];
        c1 += Sxx16[((size_t)(b * 128 + sp + 1)) * D + tid];
        c2 += Sxx16[((size_t)(b * 128 + sp + 2)) * D + tid];
        c3 += Sxx16[((size_t)(b * 128 + sp + 3)) * D + tid];
    }
    for (; sp < s; sp++) {
        a0 += Sx16[((size_t)(b * 128 + sp)) * D + tid];
        c0 += Sxx16[((size_t)(b * 128 + sp)) * D + tid];
    }
    float runx = (a0 + a1) + (a2 + a3), runxx = (c0 + c1) + (c2 + c3);
    for (int k = 0; k < 16; k++) {
        int tg = s * 16 + k;
        float xv = x[((size_t)(b * L + tg)) * D + tid];
        runx += xv; runxx += xv * xv;
        float n = (float)(tg + 1);
        float rm = runx / n;
        float rv = runxx / n - rm * rm;
        xs[k][tid] = xv; rms[k][tid] = rm;
        rss[k][tid] = sqrtf(fmaxf(rv, 1e-8f));
    }
    __syncthreads();
    int tl = tid >> 4, p = tid & 15;
    const float* Wp = W + p;
    float u0 = 0.f, u1 = 0.f, u2 = 0.f;
#pragma unroll 4
    for (int j = 0; j < 256; j++) {
        u0 += xs[tl][j] * Wp[j * LTMP];
        u1 += rms[tl][j] * Wp[(256 + j) * LTMP];
        u2 += rss[tl][j] * Wp[(512 + j) * LTMP];
    }
    float z = tanhf(u0 + u1 + u2) * PI_F;
    float si, co; sincosf(z, &si, &co);
    int tg = s * 16 + tl;
    czsz[((size_t)(b * L + tg)) * 32 + p] = co;
    czsz[((size_t)(b * L + tg)) * 32 + 16 + p] = si;
}

// ---------------- per-chunk outer-product sums S[b,c,f,d] -----------------------
__global__ __launch_bounds__(256) void outer_sums_kernel(
    const float* __restrict__ V, const float* __restrict__ fk,
    const float* __restrict__ posc, const float* __restrict__ poss,
    float* __restrict__ S) {
    int g = blockIdx.x;   // 2 feature groups of 36
    int c = blockIdx.y;   // 32
    int b = blockIdx.z;   // 4
    int tid = threadIdx.x;
    __shared__ float Fk[T][40];
    int F0 = g * 36;
    {
        int t = tid >> 2, q = tid & 3;
        int tg = c * T + t;
        for (int e = 0; e < 9; e++) {
            int fl = q * 9 + e;
            int Fi = F0 + fl;
            float v;
            if (Fi < 40) v = fk[((size_t)(b * L + tg)) * 40 + Fi];
            else {
                int pf = Fi - 40;
                v = (pf & 1) ? poss[tg * POSP + (pf >> 1)] : posc[tg * POSP + (pf >> 1)];
            }
            Fk[t][fl] = v;
        }
    }
    __syncthreads();
    float acc[36];
#pragma unroll
    for (int f = 0; f < 36; f++) acc[f] = 0.f;
    for (int t = 0; t < T; t++) {
        float v = V[((size_t)(b * L + c * T + t)) * D + tid];
#pragma unroll
        for (int f = 0; f < 36; f++) acc[f] += Fk[t][f] * v;
    }
    for (int f = 0; f < 36; f++)
        S[(((size_t)(b * C + c)) * F + F0 + f) * D + tid] = acc[f];
}

// ---------------- exclusive prefix of S over chunks (register-pipelined) --------
__global__ __launch_bounds__(256) void prefix_kernel(float* __restrict__ S) {
    int bf = blockIdx.x;
    int b = bf / F, f = bf % F;
    int d = threadIdx.x;
    size_t base = (((size_t)(b * C)) * F + f) * D + d;
    const size_t stride = (size_t)F * D;
    float v[C];
#pragma unroll
    for (int c = 0; c < C; c++) v[c] = S[base + (size_t)c * stride];   // 32 outstanding
    float run = 0.f;
#pragma unroll
    for (int c = 0; c < C; c++) {
        float t = v[c];
        S[base + (size_t)c * stride] = run;
        run += t;
    }
}

// ---------------- intra (fused score): ret = Fq·M + A·V -------------------------
// grid (8 = 4 tg x 2 dh, 32 c, B); 256 threads; A computed in-LDS.
__global__ __launch_bounds__(256) void intra_kernel(
    const float* __restrict__ V, float* __restrict__ ret,
    const float* __restrict__ fk, const float* __restrict__ fq,
    const float* __restrict__ posc, const float* __restrict__ poss,
    const float* __restrict__ Mexc, const float* __restrict__ pos_weight) {
    int tg = blockIdx.x >> 1, dh = blockIdx.x & 1;
    int c = blockIdx.y, b = blockIdx.z;
    int tid = threadIdx.x;
    int t0 = tg * 16;
    __shared__ float Fk[64][76];
    __shared__ float Fq[16][76];
    __shared__ float As[16][68];
    float posq = 0.5f / (1.0f + expf(-pos_weight[0]));
    // stage Fk: full chunk (64 rows x 72 feats)
#pragma unroll
    for (int e = 0; e < 18; e++) {
        int idx = e * 256 + tid;
        int r = idx / 72, f = idx - r * 72;
        int tgl = c * T + r;
        float v;
        if (f < 40) v = fk[((size_t)(b * L + tgl)) * 40 + f];
        else { int pf = f - 40; v = (pf & 1) ? poss[tgl * POSP + (pf >> 1)] : posc[tgl * POSP + (pf >> 1)]; }
        Fk[r][f] = v;
    }
    // stage Fq: this block's 16 rows
#pragma unroll
    for (int e = 0; e < 5; e++) {
        int idx = e * 256 + tid;
        if (idx < 1152) {
            int r = idx / 72, f = idx - r * 72;
            int tgl = c * T + t0 + r;
            float v;
            if (f < 40) v = fq[((size_t)(b * L + tgl)) * 40 + f];
            else { int pf = f - 40; v = posq * ((pf & 1) ? poss[tgl * POSP + (pf >> 1)] : posc[tgl * POSP + (pf >> 1)]); }
            Fq[r][f] = v;
        }
    }
    __syncthreads();
    // A[r][k] = (k <= t0+r) ? Fq[r]·Fk[k] : 0     (16 x 64, 4 k's per thread)
    {
        int r = tid >> 4, k0 = (tid & 15) * 4;
        int tglob = t0 + r;
#pragma unroll
        for (int j = 0; j < 4; j++) {
            int k = k0 + j;
            float a = 0.f;
            if (k <= tglob) {
#pragma unroll
                for (int f = 0; f < F; f++) a += Fq[r][f] * Fk[k][f];
            }
            As[r][k] = a;
        }
    }
    __syncthreads();
    // main: thread owns column d, 8 rows; stream M then V from global
    int dl = tid & 127, rowg = tid >> 7;
    int d = dh * 128 + dl;
    int r0 = rowg * 8;
    float acc[8];
#pragma unroll
    for (int i = 0; i < 8; i++) acc[i] = 0.f;
    const float* Mp = Mexc + (((size_t)(b * C + c)) * F) * D + d;
#pragma unroll 8
    for (int f = 0; f < F; f++) {
        float m = Mp[(size_t)f * D];
#pragma unroll
        for (int i = 0; i < 8; i++) acc[i] += Fq[r0 + i][f] * m;
    }
    const float* Vp = V + ((size_t)(b * L + c * T)) * D + d;
    int kmax = t0 + 16;
#pragma unroll 8
    for (int k = 0; k < kmax; k++) {
        float v = Vp[(size_t)k * D];
#pragma unroll
        for (int i = 0; i < 8; i++) acc[i] += As[r0 + i][k] * v;
    }
    float* Rp = ret + ((size_t)(b * L + c * T + t0 + r0)) * D + d;
#pragma unroll
    for (int i = 0; i < 8; i++) Rp[(size_t)i * D] = acc[i];
}

// ---------------- hprep: hn = LN((ret + lcoef*pers)/nrm)*gamma + beta -----------
// grid (128 row-chunks of 16, B); 256 threads; conflict-free LN stats.
__global__ __launch_bounds__(256) void hprep_kernel(
    const float* __restrict__ retp, const float* __restrict__ czsz,
    const float* __restrict__ ltm_mem, const float* __restrict__ ltm_count,
    const float* __restrict__ ltm_weight, const float* __restrict__ ln_gamma,
    const float* __restrict__ ln_beta, float* __restrict__ hn) {
    int rc = blockIdx.x;
    int b  = blockIdx.y;
    int row0 = rc * 16;
    int tid = threadIdx.x;
    __shared__ float hb[16][260];    // 260%32==4 -> stats stride-16 is 2-way (free)
    __shared__ float cs[16][33];
    __shared__ float part1[16][17], part2[16][17];
    __shared__ float mu[16], rsig[16];
    float lsig = 1.f / (1.f + expf(-ltm_weight[0]));
    float pnorm = sqrtf(fmaxf(ltm_count[0], 1.f) * (float)LTMP);
    float lcoef = lsig / pnorm;
    float Mre[16], Mim[16];
#pragma unroll
    for (int p = 0; p < 16; p++) {
        Mre[p] = ltm_mem[(p * D + tid) * 2];
        Mim[p] = ltm_mem[(p * D + tid) * 2 + 1];
    }
    float gam = ln_gamma[tid], bet = ln_beta[tid];
#pragma unroll
    for (int e = 0; e < 2; e++) {
        int idx = e * 256 + tid;     // 512 = 16 rows x 32
        int t = idx >> 5, q = idx & 31;
        cs[t][q] = czsz[((size_t)(b * L + row0 + t)) * 32 + q];
    }
    __syncthreads();
    // h (pre-LN) into hb; thread owns column tid
#pragma unroll 4
    for (int t = 0; t < 16; t++) {
        int tg = row0 + t;
        float pers = 0.f;
#pragma unroll
        for (int p = 0; p < 16; p++) pers += Mre[p] * cs[t][p] + Mim[p] * cs[t][16 + p];
        float rv = retp[((size_t)(b * L + tg)) * D + tid];
        hb[t][tid] = (rv + lcoef * pers) / (2.0f * sqrtf((float)(tg + 1)));
    }
    __syncthreads();
    // LN stats: row = tid&15, e = tid>>4; cols e+16k -> 2-way banks only
    {
        int row = tid & 15, e = tid >> 4;
        float s1 = 0.f, s2 = 0.f;
#pragma unroll
        for (int k = 0; k < 16; k++) {
            float v = hb[row][e + 16 * k];
            s1 += v; s2 += v * v;
        }
        part1[row][e] = s1; part2[row][e] = s2;
    }
    __syncthreads();
    if (tid < 16) {
        float s1 = 0.f, s2 = 0.f;
#pragma unroll
        for (int e = 0; e < 16; e++) { s1 += part1[tid][e]; s2 += part2[tid][e]; }
        float m = s1 / 256.f;
        mu[tid] = m;
        rsig[tid] = rsqrtf(fmaxf(s2 / 256.f - m * m, 0.f) + 1e-5f);
    }
    __syncthreads();
#pragma unroll 4
    for (int t = 0; t < 16; t++)
        hn[((size_t)(b * L + row0 + t)) * D + tid] =
            (hb[t][tid] - mu[t]) * rsig[t] * gam + bet;
}

// ---------------- gemm_out: out = x + hn @ w_out + b_out ------------------------
// grid (4 col-groups of 64, 64 row-chunks of 32, B); 256 threads.
__global__ __launch_bounds__(256) void gemm_out_kernel(
    const float* __restrict__ hn, const float* __restrict__ w_out,
    const float* __restrict__ b_out, const float* __restrict__ x,
    float* __restrict__ out) {
    int cg = blockIdx.x;
    int rc = blockIdx.y;
    int b  = blockIdx.z;
    int row0 = rc * 32;
    int tid = threadIdx.x;
    __shared__ float hs[32][36];
    __shared__ float wo[32][68];
    int rr = tid >> 3, c8 = tid & 7;
    float acc[8];
#pragma unroll
    for (int e = 0; e < 8; e++) acc[e] = 0.f;
    for (int kc = 0; kc < 8; kc++) {
        int kb = kc * 32;
        *(float4*)&hs[tid >> 3][(tid & 7) * 4] =
            *(const float4*)(hn + ((size_t)(b * L + row0 + (tid >> 3))) * D + kb + (tid & 7) * 4);
#pragma unroll
        for (int e = 0; e < 2; e++) {
            int idx = e * 256 + tid;      // 512 float4s: 32 rows x 16 f4
            int r = idx >> 4, c4 = idx & 15;
            *(float4*)&wo[r][c4 * 4] =
                *(const float4*)(w_out + (size_t)(kb + r) * D + cg * 64 + c4 * 4);
        }
        __syncthreads();
#pragma unroll 4
        for (int j = 0; j < 32; j++) {
            float xv = hs[rr][j];
            float4 w0 = *(float4*)&wo[j][c8 * 8];
            float4 w1 = *(float4*)&wo[j][c8 * 8 + 4];
            acc[0] += xv * w0.x; acc[1] += xv * w0.y; acc[2] += xv * w0.z; acc[3] += xv * w0.w;
            acc[4] += xv * w1.x; acc[5] += xv * w1.y; acc[6] += xv * w1.z; acc[7] += xv * w1.w;
        }
        __syncthreads();
    }
    {
        int d0 = cg * 64 + c8 * 8;
        float4 bo0 = *(const float4*)(b_out + d0);
        float4 bo1 = *(const float4*)(b_out + d0 + 4);
        size_t o = ((size_t)(b * L + row0 + rr)) * D + d0;
        float4 xa = *(const float4*)(x + o);
        float4 xb = *(const float4*)(x + o + 4);
        *(float4*)(out + o)     = make_float4(xa.x + acc[0] + bo0.x, xa.y + acc[1] + bo0.y,
                                              xa.z + acc[2] + bo0.z, xa.w + acc[3] + bo0.w);
        *(float4*)(out + o + 4) = make_float4(xb.x + acc[4] + bo1.x, xb.y + acc[5] + bo1.y,
                                              xb.z + acc[6] + bo1.z, xb.w + acc[7] + bo1.w);
    }
}

extern "C" void kernel_launch(void* const* d_in, const int* in_sizes, int n_in,
                              void* d_out, int out_size, void* d_ws, size_t ws_size,
                              hipStream_t stream) {
    (void)in_sizes; (void)n_in; (void)out_size; (void)ws_size;
    const float* x            = (const float*)d_in[0];
    const float* key_proj     = (const float*)d_in[1];
    const float* query_proj   = (const float*)d_in[2];
    const float* ltm_key_proj = (const float*)d_in[3];
    const float* pos_freqs    = (const float*)d_in[4];
    const float* w_value      = (const float*)d_in[5];
    const float* b_value      = (const float*)d_in[6];
    const float* ln_gamma     = (const float*)d_in[9];
    const float* ln_beta      = (const float*)d_in[10];
    const float* w_out        = (const float*)d_in[11];
    const float* b_out        = (const float*)d_in[12];
    const float* set_weights  = (const float*)d_in[13];
    const float* pos_weight   = (const float*)d_in[14];
    const float* surprise_scale      = (const float*)d_in[15];
    const float* surprise_bias       = (const float*)d_in[16];
    const float* resonance_scale     = (const float*)d_in[17];
    const float* resonance_threshold = (const float*)d_in[18];
    const float* ltm_weight   = (const float*)d_in[19];
    const float* ltm_mem      = (const float*)d_in[20];
    const float* ltm_count    = (const float*)d_in[21];
    float* out = (float*)d_out;

    float* ws = (float*)d_ws;
    size_t off = 0;
    float* V     = ws + off; off += (size_t)B * L * D;       // V; reused as hn after intra
    float* ret   = ws + off; off += (size_t)B * L * D;
    float* fk    = ws + off; off += (size_t)B * L * 40;
    float* fq    = ws + off; off += (size_t)B * L * 40;
    float* posc  = ws + off; off += (size_t)L * POSP;
    float* poss  = ws + off; off += (size_t)L * POSP;
    float* Sx16  = ws + off; off += (size_t)B * 128 * D;
    float* Sxx16 = ws + off; off += (size_t)B * 128 * D;
    float* czsz  = ws + off; off += (size_t)B * L * 32;
    float* S     = ws + off; off += (size_t)B * C * F * D;   // becomes exclusive prefix
    float* partial  = ws + off; off += (size_t)B * 64 * 8;
    float* chunkoff = ws + off; off += (size_t)B * 64 * 8;
    float* hn = V;   // V retired after intra reads it

    pos_kernel<<<dim3(128), 256, 0, stream>>>(pos_freqs, posc, poss);
    featurize_kernel<<<dim3(4, 64, B), 256, 0, stream>>>(x, key_proj, query_proj, w_value,
                                                         b_value, set_weights, V, fk, fq, partial);
    gs_scan_kernel<<<dim3(B), 512, 0, stream>>>(partial, chunkoff);
    gs_apply_kernel<<<dim3(64, B), 256, 0, stream>>>(fk, chunkoff, surprise_scale, surprise_bias,
                                                     resonance_scale, resonance_threshold);
    stats16_kernel<<<dim3(128, B), 256, 0, stream>>>(x, Sx16, Sxx16);
    ltm_z_kernel<<<dim3(128, B), 256, 0, stream>>>(x, Sx16, Sxx16, ltm_key_proj, czsz);
    outer_sums_kernel<<<dim3(2, C, B), 256, 0, stream>>>(V, fk, posc, poss, S);
    prefix_kernel<<<dim3(B * F), 256, 0, stream>>>(S);
    intra_kernel<<<dim3(8, C, B), 256, 0, stream>>>(V, ret, fk, fq, posc, poss, S, pos_weight);
    hprep_kernel<<<dim3(128, B), 256, 0, stream>>>(ret, czsz, ltm_mem, ltm_count, ltm_weight,
                                                   ln_gamma, ln_beta, hn);
    gemm_out_kernel<<<dim3(4, 64, B), 256, 0, stream>>>(hn, w_out, b_out, x, out);
}

// Round 6
// 257.229 us; speedup vs baseline: 2.6264x; 1.0559x over previous
//
#include <hip/hip_runtime.h>
#include <math.h>

#define B 4
#define L 2048
#define D 256
#define POSP 16
#define LTMP 16
#define T 64
#define C 32
#define F 72
#define PI_F 3.14159274101257324f
#define TWO_PI_D 6.283185307179586476925286766559

// ---------------- positional phasors (exact fp32 angle, double reduction) --------
__global__ __launch_bounds__(256) void pos_kernel(const float* __restrict__ pos_freqs,
                                                  float* __restrict__ posc,
                                                  float* __restrict__ poss) {
    int idx = blockIdx.x * 256 + threadIdx.x;
    if (idx >= L * POSP) return;
    int t = idx >> 4, p = idx & 15;
    float a = (float)t * pos_freqs[p];   // replicate numpy op order in fp32
    float th = (a * 2.0f) * PI_F;
    double r = fmod((double)th, TWO_PI_D);
    posc[idx] = (float)cos(r);
    poss[idx] = (float)sin(r);
}

// ---------------- featurize: fused GEMM x @ [w_value | key_proj | query_proj] ---
// grid (4 col-groups of 64, 32 row-chunks of 64, B); 256 thr; 4x4 micro-tile;
// x staged TRANSPOSED (xs[j][r]) so x-fragment is one ds_read_b128; double-buffered.
// 1.0 LDS-bytes/FLOP (was 2.25 -> LDS-BW-bound at 53us).
__global__ __launch_bounds__(256) void featurize_kernel(
    const float* __restrict__ x, const float* __restrict__ key_proj,
    const float* __restrict__ query_proj, const float* __restrict__ w_value,
    const float* __restrict__ b_value, const float* __restrict__ set_weights,
    float* __restrict__ V, float* __restrict__ fk, float* __restrict__ fq,
    float* __restrict__ partial) {
    int cg = blockIdx.x;
    int rc = blockIdx.y;
    int b  = blockIdx.z;
    int row0 = rc * 64;
    int tid = threadIdx.x;
    __shared__ float xs[2][32][72];   // [buf][k][row] transposed x
    __shared__ float ws[2][32][84];   // [buf][k][64 V-cols + 16 proj cols]
    __shared__ float zbuf[64][20];
    __shared__ float jkv[64][9];
    const bool has_proj = (cg < 2);
    const float* proj = (cg == 0) ? key_proj : query_proj;
    int rg = tid >> 4, cgi = tid & 15;
    int r0 = rg * 4, c0 = cgi * 4;
    int prow = tid >> 2, pc4 = tid & 3;
    float acc[4][4], accp[4];
#pragma unroll
    for (int i = 0; i < 4; i++) {
#pragma unroll
        for (int e = 0; e < 4; e++) acc[i][e] = 0.f;
        accp[i] = 0.f;
    }
    int rrA = tid >> 3, k4A = tid & 7;     // x stage mapping
    int jA = tid >> 4, c4A = tid & 15;     // w stage mapping
    float4 xr0, xr1, wr0, wr1, prr;

#define ISSUE_LOADS(kb_)                                                            \
    {                                                                               \
        xr0 = *(const float4*)(x + ((size_t)(b * L + row0 + rrA)) * D + (kb_) + k4A * 4);      \
        xr1 = *(const float4*)(x + ((size_t)(b * L + row0 + 32 + rrA)) * D + (kb_) + k4A * 4); \
        wr0 = *(const float4*)(w_value + (size_t)((kb_) + jA) * D + cg * 64 + c4A * 4);        \
        wr1 = *(const float4*)(w_value + (size_t)((kb_) + 16 + jA) * D + cg * 64 + c4A * 4);   \
        if (has_proj && tid < 128)                                                  \
            prr = *(const float4*)(proj + (size_t)((kb_) + (tid >> 2)) * 16 + (tid & 3) * 4);  \
    }
#define WRITE_LDS(bi)                                                               \
    {                                                                               \
        const float* xp0 = (const float*)&xr0;                                      \
        const float* xp1 = (const float*)&xr1;                                      \
        _Pragma("unroll")                                                           \
        for (int u = 0; u < 4; u++) {                                               \
            xs[bi][k4A * 4 + u][rrA] = xp0[u];                                      \
            xs[bi][k4A * 4 + u][32 + rrA] = xp1[u];                                 \
        }                                                                           \
        *(float4*)&ws[bi][jA][c4A * 4] = wr0;                                       \
        *(float4*)&ws[bi][16 + jA][c4A * 4] = wr1;                                  \
        if (has_proj && tid < 128)                                                  \
            *(float4*)&ws[bi][tid >> 2][64 + (tid & 3) * 4] = prr;                  \
    }

    ISSUE_LOADS(0);
    WRITE_LDS(0);
    __syncthreads();
    for (int kc = 0; kc < 8; kc++) {
        if (kc < 7) ISSUE_LOADS((kc + 1) * 32);
        int bi = kc & 1;
#pragma unroll 8
        for (int j = 0; j < 32; j++) {
            float4 xv = *(float4*)&xs[bi][j][r0];
            float4 wv = *(float4*)&ws[bi][j][c0];
            acc[0][0] += xv.x * wv.x; acc[0][1] += xv.x * wv.y; acc[0][2] += xv.x * wv.z; acc[0][3] += xv.x * wv.w;
            acc[1][0] += xv.y * wv.x; acc[1][1] += xv.y * wv.y; acc[1][2] += xv.y * wv.z; acc[1][3] += xv.y * wv.w;
            acc[2][0] += xv.z * wv.x; acc[2][1] += xv.z * wv.y; acc[2][2] += xv.z * wv.z; acc[2][3] += xv.z * wv.w;
            acc[3][0] += xv.w * wv.x; acc[3][1] += xv.w * wv.y; acc[3][2] += xv.w * wv.z; acc[3][3] += xv.w * wv.w;
            if (has_proj) {
                float xp = xs[bi][j][prow];
                float4 wp = *(float4*)&ws[bi][j][64 + pc4 * 4];
                accp[0] += xp * wp.x; accp[1] += xp * wp.y;
                accp[2] += xp * wp.z; accp[3] += xp * wp.w;
            }
        }
        if (kc < 7) WRITE_LDS((kc + 1) & 1);
        __syncthreads();
    }
#undef ISSUE_LOADS
#undef WRITE_LDS

    // V epilogue
    {
        int d0 = cg * 64 + c0;
        float4 bv = *(const float4*)(b_value + d0);
#pragma unroll
        for (int i = 0; i < 4; i++) {
            size_t o = ((size_t)(b * L + row0 + r0 + i)) * D + d0;
            *(float4*)(V + o) = make_float4(acc[i][0] + bv.x, acc[i][1] + bv.y,
                                            acc[i][2] + bv.z, acc[i][3] + bv.w);
        }
    }
    if (!has_proj) return;
#pragma unroll
    for (int e = 0; e < 4; e++) zbuf[prow][pc4 * 4 + e] = tanhf(accp[e]) * PI_F;
    __syncthreads();
    // phasor epilogue: 64 rows x 4 threads; thread handles 4 cols + joint plane q
    {
        int tt = tid >> 2, q = tid & 3;
        size_t bt = (size_t)(b * L + row0 + tt);
        if (cg == 0) {
            float* fp = fk + bt * 40;
#pragma unroll
            for (int e = 0; e < 4; e++) {
                int col = q * 4 + e;
                float si, co; sincosf(zbuf[tt][col], &si, &co);
                fp[2 * col] = co; fp[2 * col + 1] = si;
            }
            float zs = zbuf[tt][q] + zbuf[tt][4 + q] + zbuf[tt][8 + q] + zbuf[tt][12 + q];
            float si, co; sincosf(zs, &si, &co);
            fp[32 + 2 * q] = co; fp[33 + 2 * q] = si;
            jkv[tt][2 * q] = co; jkv[tt][2 * q + 1] = si;
        } else {
            float sw0 = set_weights[0], sw1 = set_weights[1], sw2 = set_weights[2], sw3 = set_weights[3];
            float mx = fmaxf(fmaxf(sw0, sw1), fmaxf(sw2, sw3));
            float e0 = expf(sw0 - mx), e1 = expf(sw1 - mx), e2 = expf(sw2 - mx), e3 = expf(sw3 - mx);
            float esum = e0 + e1 + e2 + e3;
            float wsoft[4] = {e0 / esum, e1 / esum, e2 / esum, e3 / esum};
            float* fp = fq + bt * 40;
#pragma unroll
            for (int e = 0; e < 4; e++) {
                int col = q * 4 + e;
                float si, co; sincosf(zbuf[tt][col], &si, &co);
                float sc = 0.1f * wsoft[col >> 2];   // 0.5 * w_s / (NSETS+1)
                fp[2 * col] = sc * co; fp[2 * col + 1] = sc * si;
            }
            float zs = zbuf[tt][q] + zbuf[tt][4 + q] + zbuf[tt][8 + q] + zbuf[tt][12 + q];
            float si, co; sincosf(zs, &si, &co);
            fp[32 + 2 * q] = 0.1f * co; fp[33 + 2 * q] = 0.1f * si;
        }
    }
    __syncthreads();
    if (cg == 0) {   // reduce ungated jk over two 32-row halves -> 2 chunk partials
        int h = tid >> 7, idxr = tid & 127;
        int rr2 = idxr >> 3, ch = idxr & 7;
#pragma unroll
        for (int s2 = 16; s2 >= 1; s2 >>= 1) {
            if (rr2 < s2) jkv[h * 32 + rr2][ch] += jkv[h * 32 + rr2 + s2][ch];
            __syncthreads();
        }
        if (rr2 == 0) partial[((size_t)(b * 64 + rc * 2 + h)) * 8 + ch] = jkv[h * 32][ch];
    }
}

// ---------------- gate scan phase 2: exclusive scan of 64 chunk partials --------
__global__ __launch_bounds__(512) void gs_scan_kernel(const float* __restrict__ partial,
                                                      float* __restrict__ chunkoff) {
    int b = blockIdx.x;
    int tid = threadIdx.x;   // 512 = 64 chunks x 8 ch
    int c = tid >> 3, ch = tid & 7;
    __shared__ float sc_[64][9];
    float own = partial[((size_t)(b * 64 + c)) * 8 + ch];
    sc_[c][ch] = own;
    __syncthreads();
    for (int off = 1; off < 64; off <<= 1) {
        float v = 0.f;
        if (c >= off) v = sc_[c - off][ch];
        __syncthreads();
        if (c >= off) sc_[c][ch] += v;
        __syncthreads();
    }
    chunkoff[((size_t)(b * 64 + c)) * 8 + ch] = sc_[c][ch] - own;
}

// ---------------- gate scan phase 3: local scan, gate, scale fk -----------------
__global__ __launch_bounds__(256) void gs_apply_kernel(
    float* __restrict__ fk, const float* __restrict__ chunkoff,
    const float* __restrict__ surprise_scale, const float* __restrict__ surprise_bias,
    const float* __restrict__ resonance_scale, const float* __restrict__ resonance_threshold) {
    int rc = blockIdx.x, b = blockIdx.y;
    int tid = threadIdx.x;
    int t = tid >> 3, ch = tid & 7;
    __shared__ float sc_[32][9];
    __shared__ float gbuf[32];
    float* fp = fk + ((size_t)(b * L + rc * 32 + t)) * 40;
    float own = fp[32 + ch];
    sc_[t][ch] = own;
    __syncthreads();
    for (int off = 1; off < 32; off <<= 1) {
        float v = 0.f;
        if (t >= off) v = sc_[t - off][ch];
        __syncthreads();
        if (t >= off) sc_[t][ch] += v;
        __syncthreads();
    }
    float run = chunkoff[((size_t)(b * 64 + rc)) * 8 + ch] + sc_[t][ch] - own;
    __syncthreads();
    sc_[t][ch] = run;
    __syncthreads();
    if (tid < 32) {
        int tg = rc * 32 + tid;
        float r0 = sc_[tid][0], r1 = sc_[tid][1], r2 = sc_[tid][2], r3 = sc_[tid][3];
        float r4 = sc_[tid][4], r5 = sc_[tid][5], r6 = sc_[tid][6], r7 = sc_[tid][7];
        float rmag = 0.25f * (sqrtf(r0 * r0 + r1 * r1) + sqrtf(r2 * r2 + r3 * r3) +
                              sqrtf(r4 * r4 + r5 * r5) + sqrtf(r6 * r6 + r7 * r7));
        float scv = fminf(fmaxf(resonance_scale[0], 1.f), 20.f);
        float thv = fminf(fmaxf(resonance_threshold[0], 0.1f), 0.9f);
        float nres = rmag / sqrtf(fmaxf((float)tg, 1.0f));
        float surprise = 0.5f * (1.0f - tanhf(scv * (nres - thv)));
        gbuf[tid] = 1.0f / (1.0f + expf(-(surprise_scale[0] * (surprise - 0.5f) + surprise_bias[0])));
    }
    __syncthreads();
    float gv = gbuf[t];
#pragma unroll
    for (int e = 0; e < 5; e++) fp[ch * 5 + e] *= gv;
}

// ---------------- 16-row sub-chunk sums of x, x^2 (LTM stats) -------------------
__global__ __launch_bounds__(256) void stats16_kernel(const float* __restrict__ x,
                                                      float* __restrict__ Sx16,
                                                      float* __restrict__ Sxx16) {
    int s = blockIdx.x, b = blockIdx.y;
    int d = threadIdx.x;
    float sx = 0.f, sxx = 0.f;
#pragma unroll
    for (int k = 0; k < 16; k++) {
        float v = x[((size_t)(b * L + s * 16 + k)) * D + d];
        sx += v; sxx += v * v;
    }
    Sx16[((size_t)(b * 128 + s)) * D + d] = sx;
    Sxx16[((size_t)(b * 128 + s)) * D + d] = sxx;
}

// ---------------- LTM phasor angles, 16 rows per block --------------------------
__global__ __launch_bounds__(256) void ltm_z_kernel(
    const float* __restrict__ x, const float* __restrict__ Sx16,
    const float* __restrict__ Sxx16, const float* __restrict__ W,
    float* __restrict__ czsz) {
    int s = blockIdx.x, b = blockIdx.y;
    int tid = threadIdx.x;
    __shared__ float xs[16][257], rms[16][257], rss[16][257];
    float a0 = 0.f, a1 = 0.f, a2 = 0.f, a3 = 0.f;
    float c0 = 0.f, c1 = 0.f, c2 = 0.f, c3 = 0.f;
    int sp = 0;
    for (; sp + 4 <= s; sp += 4) {
        a0 += Sx16[((size_t)(b * 128 + sp)) * D + tid];
        a1 += Sx16[((size_t)(b * 128 + sp + 1)) * D + tid];
        a2 += Sx16[((size_t)(b * 128 + sp + 2)) * D + tid];
        a3 += Sx16[((size_t)(b * 128 + sp + 3)) * D + tid];
        c0 += Sxx16[((size_t)(b * 128 + sp)) * D + tid];
        c1 += Sxx16[((size_t)(b * 128 + sp + 1)) * D + tid];
        c2 += Sxx16[((size_t)(b * 128 + sp + 2)) * D + tid];
        c3 += Sxx16[((size_t)(b * 128 + sp + 3)) * D + tid];
    }
    for (; sp < s; sp++) {
        a0 += Sx16[((size_t)(b * 128 + sp)) * D + tid];
        c0 += Sxx16[((size_t)(b * 128 + sp)) * D + tid];
    }
    float runx = (a0 + a1) + (a2 + a3), runxx = (c0 + c1) + (c2 + c3);
    for (int k = 0; k < 16; k++) {
        int tg = s * 16 + k;
        float xv = x[((size_t)(b * L + tg)) * D + tid];
        runx += xv; runxx += xv * xv;
        float n = (float)(tg + 1);
        float rm = runx / n;
        float rv = runxx / n - rm * rm;
        xs[k][tid] = xv; rms[k][tid] = rm;
        rss[k][tid] = sqrtf(fmaxf(rv, 1e-8f));
    }
    __syncthreads();
    int tl = tid >> 4, p = tid & 15;
    const float* Wp = W + p;
    float u0 = 0.f, u1 = 0.f, u2 = 0.f;
#pragma unroll 4
    for (int j = 0; j < 256; j++) {
        u0 += xs[tl][j] * Wp[j * LTMP];
        u1 += rms[tl][j] * Wp[(256 + j) * LTMP];
        u2 += rss[tl][j] * Wp[(512 + j) * LTMP];
    }
    float z = tanhf(u0 + u1 + u2) * PI_F;
    float si, co; sincosf(z, &si, &co);
    int tg = s * 16 + tl;
    czsz[((size_t)(b * L + tg)) * 32 + p] = co;
    czsz[((size_t)(b * L + tg)) * 32 + 16 + p] = si;
}

// ---------------- per-chunk outer-product sums S[b,c,f,d] -----------------------
__global__ __launch_bounds__(256) void outer_sums_kernel(
    const float* __restrict__ V, const float* __restrict__ fk,
    const float* __restrict__ posc, const float* __restrict__ poss,
    float* __restrict__ S) {
    int g = blockIdx.x;   // 2 feature groups of 36
    int c = blockIdx.y;   // 32
    int b = blockIdx.z;   // 4
    int tid = threadIdx.x;
    __shared__ float Fk[T][40];
    int F0 = g * 36;
    {
        int t = tid >> 2, q = tid & 3;
        int tg = c * T + t;
        for (int e = 0; e < 9; e++) {
            int fl = q * 9 + e;
            int Fi = F0 + fl;
            float v;
            if (Fi < 40) v = fk[((size_t)(b * L + tg)) * 40 + Fi];
            else {
                int pf = Fi - 40;
                v = (pf & 1) ? poss[tg * POSP + (pf >> 1)] : posc[tg * POSP + (pf >> 1)];
            }
            Fk[t][fl] = v;
        }
    }
    __syncthreads();
    float acc[36];
#pragma unroll
    for (int f = 0; f < 36; f++) acc[f] = 0.f;
    for (int t = 0; t < T; t++) {
        float v = V[((size_t)(b * L + c * T + t)) * D + tid];
#pragma unroll
        for (int f = 0; f < 36; f++) acc[f] += Fk[t][f] * v;
    }
    for (int f = 0; f < 36; f++)
        S[(((size_t)(b * C + c)) * F + F0 + f) * D + tid] = acc[f];
}

// ---------------- exclusive prefix of S over chunks (register-pipelined) --------
__global__ __launch_bounds__(256) void prefix_kernel(float* __restrict__ S) {
    int bf = blockIdx.x;
    int b = bf / F, f = bf % F;
    int d = threadIdx.x;
    size_t base = (((size_t)(b * C)) * F + f) * D + d;
    const size_t stride = (size_t)F * D;
    float v[C];
#pragma unroll
    for (int c = 0; c < C; c++) v[c] = S[base + (size_t)c * stride];   // 32 outstanding
    float run = 0.f;
#pragma unroll
    for (int c = 0; c < C; c++) {
        float t = v[c];
        S[base + (size_t)c * stride] = run;
        run += t;
    }
}

// ---------------- intra (fused score): ret = Fq·M + A·V -------------------------
// grid (8 = 4 tg x 2 dh, 32 c, B); 256 threads; A computed in-LDS.
__global__ __launch_bounds__(256) void intra_kernel(
    const float* __restrict__ V, float* __restrict__ ret,
    const float* __restrict__ fk, const float* __restrict__ fq,
    const float* __restrict__ posc, const float* __restrict__ poss,
    const float* __restrict__ Mexc, const float* __restrict__ pos_weight) {
    int tg = blockIdx.x >> 1, dh = blockIdx.x & 1;
    int c = blockIdx.y, b = blockIdx.z;
    int tid = threadIdx.x;
    int t0 = tg * 16;
    __shared__ float Fk[64][76];
    __shared__ float Fq[16][76];
    __shared__ float As[16][68];
    float posq = 0.5f / (1.0f + expf(-pos_weight[0]));
    // stage Fk: full chunk (64 rows x 72 feats)
#pragma unroll
    for (int e = 0; e < 18; e++) {
        int idx = e * 256 + tid;
        int r = idx / 72, f = idx - r * 72;
        int tgl = c * T + r;
        float v;
        if (f < 40) v = fk[((size_t)(b * L + tgl)) * 40 + f];
        else { int pf = f - 40; v = (pf & 1) ? poss[tgl * POSP + (pf >> 1)] : posc[tgl * POSP + (pf >> 1)]; }
        Fk[r][f] = v;
    }
    // stage Fq: this block's 16 rows
#pragma unroll
    for (int e = 0; e < 5; e++) {
        int idx = e * 256 + tid;
        if (idx < 1152) {
            int r = idx / 72, f = idx - r * 72;
            int tgl = c * T + t0 + r;
            float v;
            if (f < 40) v = fq[((size_t)(b * L + tgl)) * 40 + f];
            else { int pf = f - 40; v = posq * ((pf & 1) ? poss[tgl * POSP + (pf >> 1)] : posc[tgl * POSP + (pf >> 1)]); }
            Fq[r][f] = v;
        }
    }
    __syncthreads();
    // A[r][k] = (k <= t0+r) ? Fq[r]·Fk[k] : 0     (16 x 64, 4 k's per thread)
    {
        int r = tid >> 4, k0 = (tid & 15) * 4;
        int tglob = t0 + r;
#pragma unroll
        for (int j = 0; j < 4; j++) {
            int k = k0 + j;
            float a = 0.f;
            if (k <= tglob) {
#pragma unroll
                for (int f = 0; f < F; f++) a += Fq[r][f] * Fk[k][f];
            }
            As[r][k] = a;
        }
    }
    __syncthreads();
    // main: thread owns column d, 8 rows; stream M then V from global
    int dl = tid & 127, rowg = tid >> 7;
    int d = dh * 128 + dl;
    int r0 = rowg * 8;
    float acc[8];
#pragma unroll
    for (int i = 0; i < 8; i++) acc[i] = 0.f;
    const float* Mp = Mexc + (((size_t)(b * C + c)) * F) * D + d;
#pragma unroll 8
    for (int f = 0; f < F; f++) {
        float m = Mp[(size_t)f * D];
#pragma unroll
        for (int i = 0; i < 8; i++) acc[i] += Fq[r0 + i][f] * m;
    }
    const float* Vp = V + ((size_t)(b * L + c * T)) * D + d;
    int kmax = t0 + 16;
#pragma unroll 8
    for (int k = 0; k < kmax; k++) {
        float v = Vp[(size_t)k * D];
#pragma unroll
        for (int i = 0; i < 8; i++) acc[i] += As[r0 + i][k] * v;
    }
    float* Rp = ret + ((size_t)(b * L + c * T + t0 + r0)) * D + d;
#pragma unroll
    for (int i = 0; i < 8; i++) Rp[(size_t)i * D] = acc[i];
}

// ---------------- hprep: hn = LN((ret + lcoef*pers)/nrm)*gamma + beta -----------
// grid (128 row-chunks of 16, B); 256 threads; conflict-free LN stats.
__global__ __launch_bounds__(256) void hprep_kernel(
    const float* __restrict__ retp, const float* __restrict__ czsz,
    const float* __restrict__ ltm_mem, const float* __restrict__ ltm_count,
    const float* __restrict__ ltm_weight, const float* __restrict__ ln_gamma,
    const float* __restrict__ ln_beta, float* __restrict__ hn) {
    int rc = blockIdx.x;
    int b  = blockIdx.y;
    int row0 = rc * 16;
    int tid = threadIdx.x;
    __shared__ float hb[16][260];    // 260%32==4 -> stats stride-16 is 2-way (free)
    __shared__ float cs[16][33];
    __shared__ float part1[16][17], part2[16][17];
    __shared__ float mu[16], rsig[16];
    float lsig = 1.f / (1.f + expf(-ltm_weight[0]));
    float pnorm = sqrtf(fmaxf(ltm_count[0], 1.f) * (float)LTMP);
    float lcoef = lsig / pnorm;
    float Mre[16], Mim[16];
#pragma unroll
    for (int p = 0; p < 16; p++) {
        Mre[p] = ltm_mem[(p * D + tid) * 2];
        Mim[p] = ltm_mem[(p * D + tid) * 2 + 1];
    }
    float gam = ln_gamma[tid], bet = ln_beta[tid];
#pragma unroll
    for (int e = 0; e < 2; e++) {
        int idx = e * 256 + tid;     // 512 = 16 rows x 32
        int t = idx >> 5, q = idx & 31;
        cs[t][q] = czsz[((size_t)(b * L + row0 + t)) * 32 + q];
    }
    __syncthreads();
    // h (pre-LN) into hb; thread owns column tid
#pragma unroll 4
    for (int t = 0; t < 16; t++) {
        int tg = row0 + t;
        float pers = 0.f;
#pragma unroll
        for (int p = 0; p < 16; p++) pers += Mre[p] * cs[t][p] + Mim[p] * cs[t][16 + p];
        float rv = retp[((size_t)(b * L + tg)) * D + tid];
        hb[t][tid] = (rv + lcoef * pers) / (2.0f * sqrtf((float)(tg + 1)));
    }
    __syncthreads();
    // LN stats: row = tid&15, e = tid>>4; cols e+16k -> 2-way banks only
    {
        int row = tid & 15, e = tid >> 4;
        float s1 = 0.f, s2 = 0.f;
#pragma unroll
        for (int k = 0; k < 16; k++) {
            float v = hb[row][e + 16 * k];
            s1 += v; s2 += v * v;
        }
        part1[row][e] = s1; part2[row][e] = s2;
    }
    __syncthreads();
    if (tid < 16) {
        float s1 = 0.f, s2 = 0.f;
#pragma unroll
        for (int e = 0; e < 16; e++) { s1 += part1[tid][e]; s2 += part2[tid][e]; }
        float m = s1 / 256.f;
        mu[tid] = m;
        rsig[tid] = rsqrtf(fmaxf(s2 / 256.f - m * m, 0.f) + 1e-5f);
    }
    __syncthreads();
#pragma unroll 4
    for (int t = 0; t < 16; t++)
        hn[((size_t)(b * L + row0 + t)) * D + tid] =
            (hb[t][tid] - mu[t]) * rsig[t] * gam + bet;
}

// ---------------- gemm_out: out = x + hn @ w_out + b_out ------------------------
// grid (4 col-groups of 64, 32 row-chunks of 64, B); 4x4 micro-tile, transposed hs,
// double-buffered (same structure as featurize).
__global__ __launch_bounds__(256) void gemm_out_kernel(
    const float* __restrict__ hn, const float* __restrict__ w_out,
    const float* __restrict__ b_out, const float* __restrict__ x,
    float* __restrict__ out) {
    int cg = blockIdx.x;
    int rc = blockIdx.y;
    int b  = blockIdx.z;
    int row0 = rc * 64;
    int tid = threadIdx.x;
    __shared__ float hs[2][32][72];
    __shared__ float wo[2][32][68];
    int rg = tid >> 4, cgi = tid & 15;
    int r0 = rg * 4, c0 = cgi * 4;
    float acc[4][4];
#pragma unroll
    for (int i = 0; i < 4; i++)
#pragma unroll
        for (int e = 0; e < 4; e++) acc[i][e] = 0.f;
    int rrA = tid >> 3, k4A = tid & 7;
    int jA = tid >> 4, c4A = tid & 15;
    float4 hr0, hr1, wr0, wr1;

#define ISSUE_LOADS(kb_)                                                            \
    {                                                                               \
        hr0 = *(const float4*)(hn + ((size_t)(b * L + row0 + rrA)) * D + (kb_) + k4A * 4);      \
        hr1 = *(const float4*)(hn + ((size_t)(b * L + row0 + 32 + rrA)) * D + (kb_) + k4A * 4); \
        wr0 = *(const float4*)(w_out + (size_t)((kb_) + jA) * D + cg * 64 + c4A * 4);           \
        wr1 = *(const float4*)(w_out + (size_t)((kb_) + 16 + jA) * D + cg * 64 + c4A * 4);      \
    }
#define WRITE_LDS(bi)                                                               \
    {                                                                               \
        const float* hp0 = (const float*)&hr0;                                      \
        const float* hp1 = (const float*)&hr1;                                      \
        _Pragma("unroll")                                                           \
        for (int u = 0; u < 4; u++) {                                               \
            hs[bi][k4A * 4 + u][rrA] = hp0[u];                                      \
            hs[bi][k4A * 4 + u][32 + rrA] = hp1[u];                                 \
        }                                                                           \
        *(float4*)&wo[bi][jA][c4A * 4] = wr0;                                       \
        *(float4*)&wo[bi][16 + jA][c4A * 4] = wr1;                                  \
    }

    ISSUE_LOADS(0);
    WRITE_LDS(0);
    __syncthreads();
    for (int kc = 0; kc < 8; kc++) {
        if (kc < 7) ISSUE_LOADS((kc + 1) * 32);
        int bi = kc & 1;
#pragma unroll 8
        for (int j = 0; j < 32; j++) {
            float4 xv = *(float4*)&hs[bi][j][r0];
            float4 wv = *(float4*)&wo[bi][j][c0];
            acc[0][0] += xv.x * wv.x; acc[0][1] += xv.x * wv.y; acc[0][2] += xv.x * wv.z; acc[0][3] += xv.x * wv.w;
            acc[1][0] += xv.y * wv.x; acc[1][1] += xv.y * wv.y; acc[1][2] += xv.y * wv.z; acc[1][3] += xv.y * wv.w;
            acc[2][0] += xv.z * wv.x; acc[2][1] += xv.z * wv.y; acc[2][2] += xv.z * wv.z; acc[2][3] += xv.z * wv.w;
            acc[3][0] += xv.w * wv.x; acc[3][1] += xv.w * wv.y; acc[3][2] += xv.w * wv.z; acc[3][3] += xv.w * wv.w;
        }
        if (kc < 7) WRITE_LDS((kc + 1) & 1);
        __syncthreads();
    }
#undef ISSUE_LOADS
#undef WRITE_LDS
    {
        int d0 = cg * 64 + c0;
        float4 bo = *(const float4*)(b_out + d0);
#pragma unroll
        for (int i = 0; i < 4; i++) {
            size_t o = ((size_t)(b * L + row0 + r0 + i)) * D + d0;
            float4 xa = *(const float4*)(x + o);
            *(float4*)(out + o) = make_float4(xa.x + acc[i][0] + bo.x, xa.y + acc[i][1] + bo.y,
                                              xa.z + acc[i][2] + bo.z, xa.w + acc[i][3] + bo.w);
        }
    }
}

extern "C" void kernel_launch(void* const* d_in, const int* in_sizes, int n_in,
                              void* d_out, int out_size, void* d_ws, size_t ws_size,
                              hipStream_t stream) {
    (void)in_sizes; (void)n_in; (void)out_size; (void)ws_size;
    const float* x            = (const float*)d_in[0];
    const float* key_proj     = (const float*)d_in[1];
    const float* query_proj   = (const float*)d_in[2];
    const float* ltm_key_proj = (const float*)d_in[3];
    const float* pos_freqs    = (const float*)d_in[4];
    const float* w_value      = (const float*)d_in[5];
    const float* b_value      = (const float*)d_in[6];
    const float* ln_gamma     = (const float*)d_in[9];
    const float* ln_beta      = (const float*)d_in[10];
    const float* w_out        = (const float*)d_in[11];
    const float* b_out        = (const float*)d_in[12];
    const float* set_weights  = (const float*)d_in[13];
    const float* pos_weight   = (const float*)d_in[14];
    const float* surprise_scale      = (const float*)d_in[15];
    const float* surprise_bias       = (const float*)d_in[16];
    const float* resonance_scale     = (const float*)d_in[17];
    const float* resonance_threshold = (const float*)d_in[18];
    const float* ltm_weight   = (const float*)d_in[19];
    const float* ltm_mem      = (const float*)d_in[20];
    const float* ltm_count    = (const float*)d_in[21];
    float* out = (float*)d_out;

    float* ws = (float*)d_ws;
    size_t off = 0;
    float* V     = ws + off; off += (size_t)B * L * D;       // V; reused as hn after intra
    float* ret   = ws + off; off += (size_t)B * L * D;
    float* fk    = ws + off; off += (size_t)B * L * 40;
    float* fq    = ws + off; off += (size_t)B * L * 40;
    float* posc  = ws + off; off += (size_t)L * POSP;
    float* poss  = ws + off; off += (size_t)L * POSP;
    float* Sx16  = ws + off; off += (size_t)B * 128 * D;
    float* Sxx16 = ws + off; off += (size_t)B * 128 * D;
    float* czsz  = ws + off; off += (size_t)B * L * 32;
    float* S     = ws + off; off += (size_t)B * C * F * D;   // becomes exclusive prefix
    float* partial  = ws + off; off += (size_t)B * 64 * 8;
    float* chunkoff = ws + off; off += (size_t)B * 64 * 8;
    float* hn = V;   // V retired after intra reads it

    pos_kernel<<<dim3(128), 256, 0, stream>>>(pos_freqs, posc, poss);
    featurize_kernel<<<dim3(4, 32, B), 256, 0, stream>>>(x, key_proj, query_proj, w_value,
                                                         b_value, set_weights, V, fk, fq, partial);
    gs_scan_kernel<<<dim3(B), 512, 0, stream>>>(partial, chunkoff);
    gs_apply_kernel<<<dim3(64, B), 256, 0, stream>>>(fk, chunkoff, surprise_scale, surprise_bias,
                                                     resonance_scale, resonance_threshold);
    stats16_kernel<<<dim3(128, B), 256, 0, stream>>>(x, Sx16, Sxx16);
    ltm_z_kernel<<<dim3(128, B), 256, 0, stream>>>(x, Sx16, Sxx16, ltm_key_proj, czsz);
    outer_sums_kernel<<<dim3(2, C, B), 256, 0, stream>>>(V, fk, posc, poss, S);
    prefix_kernel<<<dim3(B * F), 256, 0, stream>>>(S);
    intra_kernel<<<dim3(8, C, B), 256, 0, stream>>>(V, ret, fk, fq, posc, poss, S, pos_weight);
    hprep_kernel<<<dim3(128, B), 256, 0, stream>>>(ret, czsz, ltm_mem, ltm_count, ltm_weight,
                                                   ln_gamma, ln_beta, hn);
    gemm_out_kernel<<<dim3(4, 32, B), 256, 0, stream>>>(hn, w_out, b_out, x, out);
}

// Round 7
// 253.890 us; speedup vs baseline: 2.6609x; 1.0132x over previous
//
#include <hip/hip_runtime.h>
#include <math.h>

#define B 4
#define L 2048
#define D 256
#define POSP 16
#define LTMP 16
#define T 64
#define C 32
#define F 72
#define PI_F 3.14159274101257324f
#define TWO_PI_D 6.283185307179586476925286766559

// ---------------- positional phasors (exact fp32 angle, double reduction) --------
__global__ __launch_bounds__(256) void pos_kernel(const float* __restrict__ pos_freqs,
                                                  float* __restrict__ posc,
                                                  float* __restrict__ poss) {
    int idx = blockIdx.x * 256 + threadIdx.x;
    if (idx >= L * POSP) return;
    int t = idx >> 4, p = idx & 15;
    float a = (float)t * pos_freqs[p];   // replicate numpy op order in fp32
    float th = (a * 2.0f) * PI_F;
    double r = fmod((double)th, TWO_PI_D);
    posc[idx] = (float)cos(r);
    poss[idx] = (float)sin(r);
}

// ---------------- featurize: fused GEMM x @ [w_value | key_proj | query_proj] ---
// grid (4 col-groups of 64, 32 row-chunks of 64, B); 256 thr; 4x4 micro-tile;
// x staged TRANSPOSED with row stride 74 -> staging stores are 2-way (free),
// x-fragment reads are 2x ds_read_b64 broadcast (free). Double-buffered.
__global__ __launch_bounds__(256) void featurize_kernel(
    const float* __restrict__ x, const float* __restrict__ key_proj,
    const float* __restrict__ query_proj, const float* __restrict__ w_value,
    const float* __restrict__ b_value, const float* __restrict__ set_weights,
    float* __restrict__ V, float* __restrict__ fk, float* __restrict__ fq,
    float* __restrict__ partial) {
    int cg = blockIdx.x;
    int rc = blockIdx.y;
    int b  = blockIdx.z;
    int row0 = rc * 64;
    int tid = threadIdx.x;
    __shared__ float xs[2][32][74];   // [buf][k][row] transposed x, stride 74
    __shared__ float ws[2][32][84];   // [buf][k][64 V-cols + 16 proj cols]
    __shared__ float zbuf[64][20];
    __shared__ float jkv[64][9];
    const bool has_proj = (cg < 2);
    const float* proj = (cg == 0) ? key_proj : query_proj;
    int rg = tid >> 4, cgi = tid & 15;
    int r0 = rg * 4, c0 = cgi * 4;
    int prow = tid >> 2, pc4 = tid & 3;
    float acc[4][4], accp[4];
#pragma unroll
    for (int i = 0; i < 4; i++) {
#pragma unroll
        for (int e = 0; e < 4; e++) acc[i][e] = 0.f;
        accp[i] = 0.f;
    }
    int rrA = tid >> 3, k4A = tid & 7;     // x stage mapping
    int jA = tid >> 4, c4A = tid & 15;     // w stage mapping
    float4 xr0, xr1, wr0, wr1, prr;

#define ISSUE_LOADS(kb_)                                                            \
    {                                                                               \
        xr0 = *(const float4*)(x + ((size_t)(b * L + row0 + rrA)) * D + (kb_) + k4A * 4);      \
        xr1 = *(const float4*)(x + ((size_t)(b * L + row0 + 32 + rrA)) * D + (kb_) + k4A * 4); \
        wr0 = *(const float4*)(w_value + (size_t)((kb_) + jA) * D + cg * 64 + c4A * 4);        \
        wr1 = *(const float4*)(w_value + (size_t)((kb_) + 16 + jA) * D + cg * 64 + c4A * 4);   \
        if (has_proj && tid < 128)                                                  \
            prr = *(const float4*)(proj + (size_t)((kb_) + (tid >> 2)) * 16 + (tid & 3) * 4);  \
    }
#define WRITE_LDS(bi)                                                               \
    {                                                                               \
        const float* xp0 = (const float*)&xr0;                                      \
        const float* xp1 = (const float*)&xr1;                                      \
        _Pragma("unroll")                                                           \
        for (int u = 0; u < 4; u++) {                                               \
            xs[bi][k4A * 4 + u][rrA] = xp0[u];                                      \
            xs[bi][k4A * 4 + u][32 + rrA] = xp1[u];                                 \
        }                                                                           \
        *(float4*)&ws[bi][jA][c4A * 4] = wr0;                                       \
        *(float4*)&ws[bi][16 + jA][c4A * 4] = wr1;                                  \
        if (has_proj && tid < 128)                                                  \
            *(float4*)&ws[bi][tid >> 2][64 + (tid & 3) * 4] = prr;                  \
    }

    ISSUE_LOADS(0);
    WRITE_LDS(0);
    __syncthreads();
    for (int kc = 0; kc < 8; kc++) {
        if (kc < 7) ISSUE_LOADS((kc + 1) * 32);
        int bi = kc & 1;
#pragma unroll 8
        for (int j = 0; j < 32; j++) {
            float2 xlo = *(float2*)&xs[bi][j][r0];
            float2 xhi = *(float2*)&xs[bi][j][r0 + 2];
            float4 wv = *(float4*)&ws[bi][j][c0];
            acc[0][0] += xlo.x * wv.x; acc[0][1] += xlo.x * wv.y; acc[0][2] += xlo.x * wv.z; acc[0][3] += xlo.x * wv.w;
            acc[1][0] += xlo.y * wv.x; acc[1][1] += xlo.y * wv.y; acc[1][2] += xlo.y * wv.z; acc[1][3] += xlo.y * wv.w;
            acc[2][0] += xhi.x * wv.x; acc[2][1] += xhi.x * wv.y; acc[2][2] += xhi.x * wv.z; acc[2][3] += xhi.x * wv.w;
            acc[3][0] += xhi.y * wv.x; acc[3][1] += xhi.y * wv.y; acc[3][2] += xhi.y * wv.z; acc[3][3] += xhi.y * wv.w;
            if (has_proj) {
                float xp = xs[bi][j][prow];
                float4 wp = *(float4*)&ws[bi][j][64 + pc4 * 4];
                accp[0] += xp * wp.x; accp[1] += xp * wp.y;
                accp[2] += xp * wp.z; accp[3] += xp * wp.w;
            }
        }
        if (kc < 7) WRITE_LDS((kc + 1) & 1);
        __syncthreads();
    }
#undef ISSUE_LOADS
#undef WRITE_LDS

    // V epilogue
    {
        int d0 = cg * 64 + c0;
        float4 bv = *(const float4*)(b_value + d0);
#pragma unroll
        for (int i = 0; i < 4; i++) {
            size_t o = ((size_t)(b * L + row0 + r0 + i)) * D + d0;
            *(float4*)(V + o) = make_float4(acc[i][0] + bv.x, acc[i][1] + bv.y,
                                            acc[i][2] + bv.z, acc[i][3] + bv.w);
        }
    }
    if (!has_proj) return;
#pragma unroll
    for (int e = 0; e < 4; e++) zbuf[prow][pc4 * 4 + e] = tanhf(accp[e]) * PI_F;
    __syncthreads();
    // phasor epilogue: 64 rows x 4 threads; thread handles 4 cols + joint plane q
    {
        int tt = tid >> 2, q = tid & 3;
        size_t bt = (size_t)(b * L + row0 + tt);
        if (cg == 0) {
            float* fp = fk + bt * 40;
#pragma unroll
            for (int e = 0; e < 4; e++) {
                int col = q * 4 + e;
                float si, co; sincosf(zbuf[tt][col], &si, &co);
                fp[2 * col] = co; fp[2 * col + 1] = si;
            }
            float zs = zbuf[tt][q] + zbuf[tt][4 + q] + zbuf[tt][8 + q] + zbuf[tt][12 + q];
            float si, co; sincosf(zs, &si, &co);
            fp[32 + 2 * q] = co; fp[33 + 2 * q] = si;
            jkv[tt][2 * q] = co; jkv[tt][2 * q + 1] = si;
        } else {
            float sw0 = set_weights[0], sw1 = set_weights[1], sw2 = set_weights[2], sw3 = set_weights[3];
            float mx = fmaxf(fmaxf(sw0, sw1), fmaxf(sw2, sw3));
            float e0 = expf(sw0 - mx), e1 = expf(sw1 - mx), e2 = expf(sw2 - mx), e3 = expf(sw3 - mx);
            float esum = e0 + e1 + e2 + e3;
            float wsoft[4] = {e0 / esum, e1 / esum, e2 / esum, e3 / esum};
            float* fp = fq + bt * 40;
#pragma unroll
            for (int e = 0; e < 4; e++) {
                int col = q * 4 + e;
                float si, co; sincosf(zbuf[tt][col], &si, &co);
                float sc = 0.1f * wsoft[col >> 2];   // 0.5 * w_s / (NSETS+1)
                fp[2 * col] = sc * co; fp[2 * col + 1] = sc * si;
            }
            float zs = zbuf[tt][q] + zbuf[tt][4 + q] + zbuf[tt][8 + q] + zbuf[tt][12 + q];
            float si, co; sincosf(zs, &si, &co);
            fp[32 + 2 * q] = 0.1f * co; fp[33 + 2 * q] = 0.1f * si;
        }
    }
    __syncthreads();
    if (cg == 0) {   // reduce ungated jk over two 32-row halves -> 2 chunk partials
        int h = tid >> 7, idxr = tid & 127;
        int rr2 = idxr >> 3, ch = idxr & 7;
#pragma unroll
        for (int s2 = 16; s2 >= 1; s2 >>= 1) {
            if (rr2 < s2) jkv[h * 32 + rr2][ch] += jkv[h * 32 + rr2 + s2][ch];
            __syncthreads();
        }
        if (rr2 == 0) partial[((size_t)(b * 64 + rc * 2 + h)) * 8 + ch] = jkv[h * 32][ch];
    }
}

// ---------------- gate scan phase 2: exclusive scan of 64 chunk partials --------
__global__ __launch_bounds__(512) void gs_scan_kernel(const float* __restrict__ partial,
                                                      float* __restrict__ chunkoff) {
    int b = blockIdx.x;
    int tid = threadIdx.x;   // 512 = 64 chunks x 8 ch
    int c = tid >> 3, ch = tid & 7;
    __shared__ float sc_[64][9];
    float own = partial[((size_t)(b * 64 + c)) * 8 + ch];
    sc_[c][ch] = own;
    __syncthreads();
    for (int off = 1; off < 64; off <<= 1) {
        float v = 0.f;
        if (c >= off) v = sc_[c - off][ch];
        __syncthreads();
        if (c >= off) sc_[c][ch] += v;
        __syncthreads();
    }
    chunkoff[((size_t)(b * 64 + c)) * 8 + ch] = sc_[c][ch] - own;
}

// ---------------- gate scan phase 3: local scan, gate, scale fk -----------------
__global__ __launch_bounds__(256) void gs_apply_kernel(
    float* __restrict__ fk, const float* __restrict__ chunkoff,
    const float* __restrict__ surprise_scale, const float* __restrict__ surprise_bias,
    const float* __restrict__ resonance_scale, const float* __restrict__ resonance_threshold) {
    int rc = blockIdx.x, b = blockIdx.y;
    int tid = threadIdx.x;
    int t = tid >> 3, ch = tid & 7;
    __shared__ float sc_[32][9];
    __shared__ float gbuf[32];
    float* fp = fk + ((size_t)(b * L + rc * 32 + t)) * 40;
    float own = fp[32 + ch];
    sc_[t][ch] = own;
    __syncthreads();
    for (int off = 1; off < 32; off <<= 1) {
        float v = 0.f;
        if (t >= off) v = sc_[t - off][ch];
        __syncthreads();
        if (t >= off) sc_[t][ch] += v;
        __syncthreads();
    }
    float run = chunkoff[((size_t)(b * 64 + rc)) * 8 + ch] + sc_[t][ch] - own;
    __syncthreads();
    sc_[t][ch] = run;
    __syncthreads();
    if (tid < 32) {
        int tg = rc * 32 + tid;
        float r0 = sc_[tid][0], r1 = sc_[tid][1], r2 = sc_[tid][2], r3 = sc_[tid][3];
        float r4 = sc_[tid][4], r5 = sc_[tid][5], r6 = sc_[tid][6], r7 = sc_[tid][7];
        float rmag = 0.25f * (sqrtf(r0 * r0 + r1 * r1) + sqrtf(r2 * r2 + r3 * r3) +
                              sqrtf(r4 * r4 + r5 * r5) + sqrtf(r6 * r6 + r7 * r7));
        float scv = fminf(fmaxf(resonance_scale[0], 1.f), 20.f);
        float thv = fminf(fmaxf(resonance_threshold[0], 0.1f), 0.9f);
        float nres = rmag / sqrtf(fmaxf((float)tg, 1.0f));
        float surprise = 0.5f * (1.0f - tanhf(scv * (nres - thv)));
        gbuf[tid] = 1.0f / (1.0f + expf(-(surprise_scale[0] * (surprise - 0.5f) + surprise_bias[0])));
    }
    __syncthreads();
    float gv = gbuf[t];
#pragma unroll
    for (int e = 0; e < 5; e++) fp[ch * 5 + e] *= gv;
}

// ---------------- 16-row sub-chunk sums of x, x^2 (LTM stats) -------------------
__global__ __launch_bounds__(256) void stats16_kernel(const float* __restrict__ x,
                                                      float* __restrict__ Sx16,
                                                      float* __restrict__ Sxx16) {
    int s = blockIdx.x, b = blockIdx.y;
    int d = threadIdx.x;
    float sx = 0.f, sxx = 0.f;
#pragma unroll
    for (int k = 0; k < 16; k++) {
        float v = x[((size_t)(b * L + s * 16 + k)) * D + d];
        sx += v; sxx += v * v;
    }
    Sx16[((size_t)(b * 128 + s)) * D + d] = sx;
    Sxx16[((size_t)(b * 128 + s)) * D + d] = sxx;
}

// ---------------- LTM phasor angles, 16 rows per block --------------------------
__global__ __launch_bounds__(256) void ltm_z_kernel(
    const float* __restrict__ x, const float* __restrict__ Sx16,
    const float* __restrict__ Sxx16, const float* __restrict__ W,
    float* __restrict__ czsz) {
    int s = blockIdx.x, b = blockIdx.y;
    int tid = threadIdx.x;
    __shared__ float xs[16][257], rms[16][257], rss[16][257];
    float a0 = 0.f, a1 = 0.f, a2 = 0.f, a3 = 0.f;
    float c0 = 0.f, c1 = 0.f, c2 = 0.f, c3 = 0.f;
    int sp = 0;
    for (; sp + 4 <= s; sp += 4) {
        a0 += Sx16[((size_t)(b * 128 + sp)) * D + tid];
        a1 += Sx16[((size_t)(b * 128 + sp + 1)) * D + tid];
        a2 += Sx16[((size_t)(b * 128 + sp + 2)) * D + tid];
        a3 += Sx16[((size_t)(b * 128 + sp + 3)) * D + tid];
        c0 += Sxx16[((size_t)(b * 128 + sp)) * D + tid];
        c1 += Sxx16[((size_t)(b * 128 + sp + 1)) * D + tid];
        c2 += Sxx16[((size_t)(b * 128 + sp + 2)) * D + tid];
        c3 += Sxx16[((size_t)(b * 128 + sp + 3)) * D + tid];
    }
    for (; sp < s; sp++) {
        a0 += Sx16[((size_t)(b * 128 + sp)) * D + tid];
        c0 += Sxx16[((size_t)(b * 128 + sp)) * D + tid];
    }
    float runx = (a0 + a1) + (a2 + a3), runxx = (c0 + c1) + (c2 + c3);
    for (int k = 0; k < 16; k++) {
        int tg = s * 16 + k;
        float xv = x[((size_t)(b * L + tg)) * D + tid];
        runx += xv; runxx += xv * xv;
        float n = (float)(tg + 1);
        float rm = runx / n;
        float rv = runxx / n - rm * rm;
        xs[k][tid] = xv; rms[k][tid] = rm;
        rss[k][tid] = sqrtf(fmaxf(rv, 1e-8f));
    }
    __syncthreads();
    int tl = tid >> 4, p = tid & 15;
    const float* Wp = W + p;
    float u0 = 0.f, u1 = 0.f, u2 = 0.f;
#pragma unroll 4
    for (int j = 0; j < 256; j++) {
        u0 += xs[tl][j] * Wp[j * LTMP];
        u1 += rms[tl][j] * Wp[(256 + j) * LTMP];
        u2 += rss[tl][j] * Wp[(512 + j) * LTMP];
    }
    float z = tanhf(u0 + u1 + u2) * PI_F;
    float si, co; sincosf(z, &si, &co);
    int tg = s * 16 + tl;
    czsz[((size_t)(b * L + tg)) * 32 + p] = co;
    czsz[((size_t)(b * L + tg)) * 32 + 16 + p] = si;
}

// ---------------- per-chunk outer-product sums S[b,c,f,d] -----------------------
__global__ __launch_bounds__(256) void outer_sums_kernel(
    const float* __restrict__ V, const float* __restrict__ fk,
    const float* __restrict__ posc, const float* __restrict__ poss,
    float* __restrict__ S) {
    int g = blockIdx.x;   // 2 feature groups of 36
    int c = blockIdx.y;   // 32
    int b = blockIdx.z;   // 4
    int tid = threadIdx.x;
    __shared__ float Fk[T][40];
    int F0 = g * 36;
    {
        int t = tid >> 2, q = tid & 3;
        int tg = c * T + t;
        for (int e = 0; e < 9; e++) {
            int fl = q * 9 + e;
            int Fi = F0 + fl;
            float v;
            if (Fi < 40) v = fk[((size_t)(b * L + tg)) * 40 + Fi];
            else {
                int pf = Fi - 40;
                v = (pf & 1) ? poss[tg * POSP + (pf >> 1)] : posc[tg * POSP + (pf >> 1)];
            }
            Fk[t][fl] = v;
        }
    }
    __syncthreads();
    float acc[36];
#pragma unroll
    for (int f = 0; f < 36; f++) acc[f] = 0.f;
    for (int t = 0; t < T; t++) {
        float v = V[((size_t)(b * L + c * T + t)) * D + tid];
#pragma unroll
        for (int f = 0; f < 36; f++) acc[f] += Fk[t][f] * v;
    }
    for (int f = 0; f < 36; f++)
        S[(((size_t)(b * C + c)) * F + F0 + f) * D + tid] = acc[f];
}

// ---------------- exclusive prefix of S over chunks (register-pipelined) --------
__global__ __launch_bounds__(256) void prefix_kernel(float* __restrict__ S) {
    int bf = blockIdx.x;
    int b = bf / F, f = bf % F;
    int d = threadIdx.x;
    size_t base = (((size_t)(b * C)) * F + f) * D + d;
    const size_t stride = (size_t)F * D;
    float v[C];
#pragma unroll
    for (int c = 0; c < C; c++) v[c] = S[base + (size_t)c * stride];   // 32 outstanding
    float run = 0.f;
#pragma unroll
    for (int c = 0; c < C; c++) {
        float t = v[c];
        S[base + (size_t)c * stride] = run;
        run += t;
    }
}

// ---------------- intra (fused score): ret = Fq·M + A·V -------------------------
// grid (8 = 4 tg x 2 dh, 32 c, B); 256 threads; A computed in-LDS.
__global__ __launch_bounds__(256) void intra_kernel(
    const float* __restrict__ V, float* __restrict__ ret,
    const float* __restrict__ fk, const float* __restrict__ fq,
    const float* __restrict__ posc, const float* __restrict__ poss,
    const float* __restrict__ Mexc, const float* __restrict__ pos_weight) {
    int tg = blockIdx.x >> 1, dh = blockIdx.x & 1;
    int c = blockIdx.y, b = blockIdx.z;
    int tid = threadIdx.x;
    int t0 = tg * 16;
    __shared__ float Fk[64][76];
    __shared__ float Fq[16][76];
    __shared__ float As[16][68];
    float posq = 0.5f / (1.0f + expf(-pos_weight[0]));
    // stage Fk: full chunk (64 rows x 72 feats)
#pragma unroll
    for (int e = 0; e < 18; e++) {
        int idx = e * 256 + tid;
        int r = idx / 72, f = idx - r * 72;
        int tgl = c * T + r;
        float v;
        if (f < 40) v = fk[((size_t)(b * L + tgl)) * 40 + f];
        else { int pf = f - 40; v = (pf & 1) ? poss[tgl * POSP + (pf >> 1)] : posc[tgl * POSP + (pf >> 1)]; }
        Fk[r][f] = v;
    }
    // stage Fq: this block's 16 rows
#pragma unroll
    for (int e = 0; e < 5; e++) {
        int idx = e * 256 + tid;
        if (idx < 1152) {
            int r = idx / 72, f = idx - r * 72;
            int tgl = c * T + t0 + r;
            float v;
            if (f < 40) v = fq[((size_t)(b * L + tgl)) * 40 + f];
            else { int pf = f - 40; v = posq * ((pf & 1) ? poss[tgl * POSP + (pf >> 1)] : posc[tgl * POSP + (pf >> 1)]); }
            Fq[r][f] = v;
        }
    }
    __syncthreads();
    // A[r][k] = (k <= t0+r) ? Fq[r]·Fk[k] : 0     (16 x 64, 4 k's per thread)
    {
        int r = tid >> 4, k0 = (tid & 15) * 4;
        int tglob = t0 + r;
#pragma unroll
        for (int j = 0; j < 4; j++) {
            int k = k0 + j;
            float a = 0.f;
            if (k <= tglob) {
#pragma unroll
                for (int f = 0; f < F; f++) a += Fq[r][f] * Fk[k][f];
            }
            As[r][k] = a;
        }
    }
    __syncthreads();
    // main: thread owns column d, 8 rows; stream M then V from global
    int dl = tid & 127, rowg = tid >> 7;
    int d = dh * 128 + dl;
    int r0 = rowg * 8;
    float acc[8];
#pragma unroll
    for (int i = 0; i < 8; i++) acc[i] = 0.f;
    const float* Mp = Mexc + (((size_t)(b * C + c)) * F) * D + d;
#pragma unroll 8
    for (int f = 0; f < F; f++) {
        float m = Mp[(size_t)f * D];
#pragma unroll
        for (int i = 0; i < 8; i++) acc[i] += Fq[r0 + i][f] * m;
    }
    const float* Vp = V + ((size_t)(b * L + c * T)) * D + d;
    int kmax = t0 + 16;
#pragma unroll 8
    for (int k = 0; k < kmax; k++) {
        float v = Vp[(size_t)k * D];
#pragma unroll
        for (int i = 0; i < 8; i++) acc[i] += As[r0 + i][k] * v;
    }
    float* Rp = ret + ((size_t)(b * L + c * T + t0 + r0)) * D + d;
#pragma unroll
    for (int i = 0; i < 8; i++) Rp[(size_t)i * D] = acc[i];
}

// ---------------- hprep: hn = LN((ret + lcoef*pers)/nrm)*gamma + beta -----------
// grid (128 row-chunks of 16, B); 256 threads; conflict-free LN stats.
__global__ __launch_bounds__(256) void hprep_kernel(
    const float* __restrict__ retp, const float* __restrict__ czsz,
    const float* __restrict__ ltm_mem, const float* __restrict__ ltm_count,
    const float* __restrict__ ltm_weight, const float* __restrict__ ln_gamma,
    const float* __restrict__ ln_beta, float* __restrict__ hn) {
    int rc = blockIdx.x;
    int b  = blockIdx.y;
    int row0 = rc * 16;
    int tid = threadIdx.x;
    __shared__ float hb[16][260];    // 260%32==4 -> stats stride-16 is 2-way (free)
    __shared__ float cs[16][33];
    __shared__ float part1[16][17], part2[16][17];
    __shared__ float mu[16], rsig[16];
    float lsig = 1.f / (1.f + expf(-ltm_weight[0]));
    float pnorm = sqrtf(fmaxf(ltm_count[0], 1.f) * (float)LTMP);
    float lcoef = lsig / pnorm;
    float Mre[16], Mim[16];
#pragma unroll
    for (int p = 0; p < 16; p++) {
        Mre[p] = ltm_mem[(p * D + tid) * 2];
        Mim[p] = ltm_mem[(p * D + tid) * 2 + 1];
    }
    float gam = ln_gamma[tid], bet = ln_beta[tid];
#pragma unroll
    for (int e = 0; e < 2; e++) {
        int idx = e * 256 + tid;     // 512 = 16 rows x 32
        int t = idx >> 5, q = idx & 31;
        cs[t][q] = czsz[((size_t)(b * L + row0 + t)) * 32 + q];
    }
    __syncthreads();
    // h (pre-LN) into hb; thread owns column tid
#pragma unroll 4
    for (int t = 0; t < 16; t++) {
        int tg = row0 + t;
        float pers = 0.f;
#pragma unroll
        for (int p = 0; p < 16; p++) pers += Mre[p] * cs[t][p] + Mim[p] * cs[t][16 + p];
        float rv = retp[((size_t)(b * L + tg)) * D + tid];
        hb[t][tid] = (rv + lcoef * pers) / (2.0f * sqrtf((float)(tg + 1)));
    }
    __syncthreads();
    // LN stats: row = tid&15, e = tid>>4; cols e+16k -> 2-way banks only
    {
        int row = tid & 15, e = tid >> 4;
        float s1 = 0.f, s2 = 0.f;
#pragma unroll
        for (int k = 0; k < 16; k++) {
            float v = hb[row][e + 16 * k];
            s1 += v; s2 += v * v;
        }
        part1[row][e] = s1; part2[row][e] = s2;
    }
    __syncthreads();
    if (tid < 16) {
        float s1 = 0.f, s2 = 0.f;
#pragma unroll
        for (int e = 0; e < 16; e++) { s1 += part1[tid][e]; s2 += part2[tid][e]; }
        float m = s1 / 256.f;
        mu[tid] = m;
        rsig[tid] = rsqrtf(fmaxf(s2 / 256.f - m * m, 0.f) + 1e-5f);
    }
    __syncthreads();
#pragma unroll 4
    for (int t = 0; t < 16; t++)
        hn[((size_t)(b * L + row0 + t)) * D + tid] =
            (hb[t][tid] - mu[t]) * rsig[t] * gam + bet;
}

// ---------------- gemm_out: out = x + hn @ w_out + b_out ------------------------
// grid (4 col-groups of 64, 32 row-chunks of 64, B); 4x4 micro-tile, transposed hs
// (stride 74, conflict-free), double-buffered.
__global__ __launch_bounds__(256) void gemm_out_kernel(
    const float* __restrict__ hn, const float* __restrict__ w_out,
    const float* __restrict__ b_out, const float* __restrict__ x,
    float* __restrict__ out) {
    int cg = blockIdx.x;
    int rc = blockIdx.y;
    int b  = blockIdx.z;
    int row0 = rc * 64;
    int tid = threadIdx.x;
    __shared__ float hs[2][32][74];
    __shared__ float wo[2][32][68];
    int rg = tid >> 4, cgi = tid & 15;
    int r0 = rg * 4, c0 = cgi * 4;
    float acc[4][4];
#pragma unroll
    for (int i = 0; i < 4; i++)
#pragma unroll
        for (int e = 0; e < 4; e++) acc[i][e] = 0.f;
    int rrA = tid >> 3, k4A = tid & 7;
    int jA = tid >> 4, c4A = tid & 15;
    float4 hr0, hr1, wr0, wr1;

#define ISSUE_LOADS(kb_)                                                            \
    {                                                                               \
        hr0 = *(const float4*)(hn + ((size_t)(b * L + row0 + rrA)) * D + (kb_) + k4A * 4);      \
        hr1 = *(const float4*)(hn + ((size_t)(b * L + row0 + 32 + rrA)) * D + (kb_) + k4A * 4); \
        wr0 = *(const float4*)(w_out + (size_t)((kb_) + jA) * D + cg * 64 + c4A * 4);           \
        wr1 = *(const float4*)(w_out + (size_t)((kb_) + 16 + jA) * D + cg * 64 + c4A * 4);      \
    }
#define WRITE_LDS(bi)                                                               \
    {                                                                               \
        const float* hp0 = (const float*)&hr0;                                      \
        const float* hp1 = (const float*)&hr1;                                      \
        _Pragma("unroll")                                                           \
        for (int u = 0; u < 4; u++) {                                               \
            hs[bi][k4A * 4 + u][rrA] = hp0[u];                                      \
            hs[bi][k4A * 4 + u][32 + rrA] = hp1[u];                                 \
        }                                                                           \
        *(float4*)&wo[bi][jA][c4A * 4] = wr0;                                       \
        *(float4*)&wo[bi][16 + jA][c4A * 4] = wr1;                                  \
    }

    ISSUE_LOADS(0);
    WRITE_LDS(0);
    __syncthreads();
    for (int kc = 0; kc < 8; kc++) {
        if (kc < 7) ISSUE_LOADS((kc + 1) * 32);
        int bi = kc & 1;
#pragma unroll 8
        for (int j = 0; j < 32; j++) {
            float2 xlo = *(float2*)&hs[bi][j][r0];
            float2 xhi = *(float2*)&hs[bi][j][r0 + 2];
            float4 wv = *(float4*)&wo[bi][j][c0];
            acc[0][0] += xlo.x * wv.x; acc[0][1] += xlo.x * wv.y; acc[0][2] += xlo.x * wv.z; acc[0][3] += xlo.x * wv.w;
            acc[1][0] += xlo.y * wv.x; acc[1][1] += xlo.y * wv.y; acc[1][2] += xlo.y * wv.z; acc[1][3] += xlo.y * wv.w;
            acc[2][0] += xhi.x * wv.x; acc[2][1] += xhi.x * wv.y; acc[2][2] += xhi.x * wv.z; acc[2][3] += xhi.x * wv.w;
            acc[3][0] += xhi.y * wv.x; acc[3][1] += xhi.y * wv.y; acc[3][2] += xhi.y * wv.z; acc[3][3] += xhi.y * wv.w;
        }
        if (kc < 7) WRITE_LDS((kc + 1) & 1);
        __syncthreads();
    }
#undef ISSUE_LOADS
#undef WRITE_LDS
    {
        int d0 = cg * 64 + c0;
        float4 bo = *(const float4*)(b_out + d0);
#pragma unroll
        for (int i = 0; i < 4; i++) {
            size_t o = ((size_t)(b * L + row0 + r0 + i)) * D + d0;
            float4 xa = *(const float4*)(x + o);
            *(float4*)(out + o) = make_float4(xa.x + acc[i][0] + bo.x, xa.y + acc[i][1] + bo.y,
                                              xa.z + acc[i][2] + bo.z, xa.w + acc[i][3] + bo.w);
        }
    }
}

extern "C" void kernel_launch(void* const* d_in, const int* in_sizes, int n_in,
                              void* d_out, int out_size, void* d_ws, size_t ws_size,
                              hipStream_t stream) {
    (void)in_sizes; (void)n_in; (void)out_size; (void)ws_size;
    const float* x            = (const float*)d_in[0];
    const float* key_proj     = (const float*)d_in[1];
    const float* query_proj   = (const float*)d_in[2];
    const float* ltm_key_proj = (const float*)d_in[3];
    const float* pos_freqs    = (const float*)d_in[4];
    const float* w_value      = (const float*)d_in[5];
    const float* b_value      = (const float*)d_in[6];
    const float* ln_gamma     = (const float*)d_in[9];
    const float* ln_beta      = (const float*)d_in[10];
    const float* w_out        = (const float*)d_in[11];
    const float* b_out        = (const float*)d_in[12];
    const float* set_weights  = (const float*)d_in[13];
    const float* pos_weight   = (const float*)d_in[14];
    const float* surprise_scale      = (const float*)d_in[15];
    const float* surprise_bias       = (const float*)d_in[16];
    const float* resonance_scale     = (const float*)d_in[17];
    const float* resonance_threshold = (const float*)d_in[18];
    const float* ltm_weight   = (const float*)d_in[19];
    const float* ltm_mem      = (const float*)d_in[20];
    const float* ltm_count    = (const float*)d_in[21];
    float* out = (float*)d_out;

    float* ws = (float*)d_ws;
    size_t off = 0;
    float* V     = ws + off; off += (size_t)B * L * D;       // V; reused as hn after intra
    float* ret   = ws + off; off += (size_t)B * L * D;
    float* fk    = ws + off; off += (size_t)B * L * 40;
    float* fq    = ws + off; off += (size_t)B * L * 40;
    float* posc  = ws + off; off += (size_t)L * POSP;
    float* poss  = ws + off; off += (size_t)L * POSP;
    float* Sx16  = ws + off; off += (size_t)B * 128 * D;
    float* Sxx16 = ws + off; off += (size_t)B * 128 * D;
    float* czsz  = ws + off; off += (size_t)B * L * 32;
    float* S     = ws + off; off += (size_t)B * C * F * D;   // becomes exclusive prefix
    float* partial  = ws + off; off += (size_t)B * 64 * 8;
    float* chunkoff = ws + off; off += (size_t)B * 64 * 8;
    float* hn = V;   // V retired after intra reads it

    pos_kernel<<<dim3(128), 256, 0, stream>>>(pos_freqs, posc, poss);
    featurize_kernel<<<dim3(4, 32, B), 256, 0, stream>>>(x, key_proj, query_proj, w_value,
                                                         b_value, set_weights, V, fk, fq, partial);
    gs_scan_kernel<<<dim3(B), 512, 0, stream>>>(partial, chunkoff);
    gs_apply_kernel<<<dim3(64, B), 256, 0, stream>>>(fk, chunkoff, surprise_scale, surprise_bias,
                                                     resonance_scale, resonance_threshold);
    stats16_kernel<<<dim3(128, B), 256, 0, stream>>>(x, Sx16, Sxx16);
    ltm_z_kernel<<<dim3(128, B), 256, 0, stream>>>(x, Sx16, Sxx16, ltm_key_proj, czsz);
    outer_sums_kernel<<<dim3(2, C, B), 256, 0, stream>>>(V, fk, posc, poss, S);
    prefix_kernel<<<dim3(B * F), 256, 0, stream>>>(S);
    intra_kernel<<<dim3(8, C, B), 256, 0, stream>>>(V, ret, fk, fq, posc, poss, S, pos_weight);
    hprep_kernel<<<dim3(128, B), 256, 0, stream>>>(ret, czsz, ltm_mem, ltm_count, ltm_weight,
                                                   ln_gamma, ln_beta, hn);
    gemm_out_kernel<<<dim3(4, 32, B), 256, 0, stream>>>(hn, w_out, b_out, x, out);
}